// Round 10
// baseline (246.229 us; speedup 1.0000x reference)
//
#include <hip/hip_runtime.h>
#include <math.h>

#define D_ 256
#define NS_ 64
#define KNB_ 8
#define SEQ_ 1024
#define B_ 4
#define MAXQ_ 1024
#define KA_ 384            // prescaled A row: [e'(64) | s'(64) | h'(256)]
#define NEG_ (-10000.0f)
#define BLKNEG_ (-50000.0f)

__device__ __forceinline__ float waveSum(float v) {
#pragma unroll
    for (int off = 32; off; off >>= 1) v += __shfl_xor(v, off, 64);
    return v;
}

__device__ __forceinline__ void waveSum2(float& a, float& b) {
#pragma unroll
    for (int off = 32; off; off >>= 1) {
        a += __shfl_xor(a, off, 64);
        b += __shfl_xor(b, off, 64);
    }
}

__device__ __forceinline__ float blockSum(float v, float* scr) {
    const int tid = threadIdx.x;
    const int wid = tid >> 6, lane = tid & 63;
    v = waveSum(v);
    __syncthreads();
    if (lane == 0) scr[wid] = v;
    __syncthreads();
    return scr[0] + scr[1] + scr[2] + scr[3];
}

// batched block-wide sum of 4 independent values (2 barriers total)
__device__ __forceinline__ void blockSum4(float v[4], float (*scr4)[4]) {
    const int tid = threadIdx.x;
    const int wid = tid >> 6, lane = tid & 63;
#pragma unroll
    for (int off = 32; off; off >>= 1) {
#pragma unroll
        for (int q = 0; q < 4; ++q) v[q] += __shfl_xor(v[q], off, 64);
    }
    __syncthreads();
    if (lane == 0) {
#pragma unroll
        for (int q = 0; q < 4; ++q) scr4[wid][q] = v[q];
    }
    __syncthreads();
#pragma unroll
    for (int q = 0; q < 4; ++q)
        v[q] = scr4[0][q] + scr4[1][q] + scr4[2][q] + scr4[3][q];
}

// exact sparsemax tau via support iteration (monotone, fixpoint = exact tau)
__device__ __forceinline__ float sparsemaxTauWave(const float* zr) {
    float mx = zr[0];
#pragma unroll
    for (int i = 1; i < 16; ++i) mx = fmaxf(mx, zr[i]);
#pragma unroll
    for (int off = 32; off; off >>= 1) mx = fmaxf(mx, __shfl_xor(mx, off, 64));
    float tau = mx - 1.0f;
    for (int it = 0; it < 32; ++it) {
        float ssum = 0.f, cnt = 0.f;
#pragma unroll
        for (int i = 0; i < 16; ++i) {
            if (zr[i] > tau) { ssum += zr[i]; cnt += 1.f; }
        }
        waveSum2(ssum, cnt);
        if (cnt < 0.5f) break;                 // safety
        const float nt = (ssum - 1.0f) / cnt;
        if (nt == tau) break;                  // support stable -> exact
        tau = nt;
    }
    return tau;
}

// Fused setup: msg/scn transposes + mask-dtype detect + per-row prep.
// blocks [0,1024): messages -> msgT; [1024,1280): scn -> scnT;
// 1280: mask detect + counter zero; [1281,1793): prep (8 rows each).
__global__ __launch_bounds__(256) void setup_kernel(
    const float* __restrict__ messages, const float* __restrict__ scn,
    const float* __restrict__ hidden, const float* __restrict__ gvel,
    const float* __restrict__ ctx, const float* __restrict__ ent,
    const float* __restrict__ W_probe, const float* __restrict__ W_vel,
    const float* __restrict__ W_gate, const float* __restrict__ b_gate,
    float* __restrict__ msgT, float* __restrict__ scnT,
    const unsigned int* __restrict__ maskW, int* __restrict__ flag,
    int* __restrict__ qMeta,
    float* __restrict__ wsA, float* __restrict__ wsProbe,
    int* __restrict__ wsMode, float* __restrict__ wsGw)
{
    const int bid = blockIdx.x;
    const int tid = threadIdx.x;

    if (bid == 1280) {
        __shared__ int notI, notF;
        if (tid == 0) { notI = 0; notF = 0; qMeta[0] = 0; qMeta[1] = 0; }
        __syncthreads();
        int ni = 0, nf = 0;
        for (int i = tid; i < 1024; i += 256) {
            const unsigned int w = maskW[i];
            if (w != 0u && w != 1u) ni = 1;
            if (w != 0u && w != 0x3f800000u) nf = 1;
        }
        if (ni) atomicOr(&notI, 1);
        if (nf) atomicOr(&notF, 1);
        __syncthreads();
        if (tid == 0) *flag = (!notI) ? 0 : ((!notF) ? 2 : 1);
        return;
    }

    if (bid < 1280) {
        __shared__ float tile[32][33];
        const int tx = tid & 31, ty = tid >> 5;
        const float* src; float* dst; int Cc, bz, cx, cy;
        if (bid < 1024) {
            bz = bid >> 8; const int rem = bid & 255;
            cy = rem >> 3; cx = rem & 7;
            src = messages; dst = msgT; Cc = D_;
        } else {
            const int i = bid - 1024; bz = i >> 6; const int rem = i & 63;
            cy = rem >> 1; cx = rem & 1;
            src = scn; dst = scnT; Cc = NS_;
        }
        const int c0 = cx << 5, r0 = cy << 5;
        const float* s = src + (size_t)bz * SEQ_ * Cc;
        float* d = dst + (size_t)bz * SEQ_ * Cc;
#pragma unroll
        for (int i = 0; i < 32; i += 8)
            tile[ty + i][tx] = s[(size_t)(r0 + ty + i) * Cc + c0 + tx];
        __syncthreads();
#pragma unroll
        for (int i = 0; i < 32; i += 8)
            d[(size_t)(c0 + ty + i) * SEQ_ + r0 + tx] = tile[tx][ty + i];
        return;
    }

    // ---- prep: 8 rows per block ----
    __shared__ float scr4[4][4];
    const int rowBase = (bid - 1281) << 3;
    const int wid = tid >> 6, lane = tid & 63;
    const float* h0 = hidden + (size_t)rowBase * D_;

    float vh[8] = {};
    for (int e = 0; e < NS_; e += 4) {
        const float4 wv4 = *(const float4*)(W_vel + (size_t)tid * NS_ + e);  // thread-own row
#pragma unroll
        for (int r = 0; r < 8; ++r) {
            const float4 g4 = *(const float4*)(gvel + (size_t)(rowBase + r) * NS_ + e); // uniform
            vh[r] = fmaf(g4.x, wv4.x, fmaf(g4.y, wv4.y, fmaf(g4.z, wv4.z, fmaf(g4.w, wv4.w, vh[r]))));
        }
    }
    float pr[8] = {};
    for (int e = 0; e < D_; e += 4) {
        const float4 wp4 = *(const float4*)(W_probe + (size_t)tid * D_ + e);  // thread-own row
#pragma unroll
        for (int r = 0; r < 8; ++r) {
            const float4 h4 = *(const float4*)(h0 + (size_t)r * D_ + e);      // uniform
            pr[r] = fmaf(h4.x, wp4.x, fmaf(h4.y, wp4.y, fmaf(h4.z, wp4.z, fmaf(h4.w, wp4.w, pr[r]))));
        }
    }

    // per-wave: wave w handles rows 2w, 2w+1 (endpoint, s', argmax, gate)
#pragma unroll
    for (int rr = 0; rr < 2; ++rr) {
        const int r = (wid << 1) + rr, row = rowBase + r;
        const float sv = scn[(size_t)row * NS_ + lane];
        const float gv = gvel[(size_t)row * NS_ + lane];
        const float Hn = ent[row] / 10.373491191781864f;   // log(32000)+1e-8
        const float e = sv + 0.4f * gv;
        const float ss = waveSum(e * e);
        wsA[(size_t)row * KA_ + lane] = (e / fmaxf(sqrtf(ss), 1e-12f)) * 5.0f * Hn;
        wsA[(size_t)row * KA_ + 64 + lane] = 5.0f * sv;
        float v = sv; int idx = lane;
#pragma unroll
        for (int off = 1; off < 64; off <<= 1) {
            const float ov = __shfl_xor(v, off, 64);
            const int   oi = __shfl_xor(idx, off, 64);
            if (ov > v || (ov == v && oi < idx)) { v = ov; idx = oi; }
        }
        float gd = 0.f;
#pragma unroll
        for (int j = 0; j < 4; ++j) {
            const int d = lane + (j << 6);
            gd = fmaf(h0[(size_t)r * D_ + d], W_gate[d], gd);
        }
        gd = waveSum(gd);
        if (lane == 0) {
            wsMode[row] = idx;
            const float raw = 1.f / (1.f + expf(-(gd + b_gate[0])));
            wsGw[row] = raw * ctx[row];
        }
    }

    // block-wide norms, 4 rows per batched reduction
#pragma unroll
    for (int g = 0; g < 2; ++g) {
        float ha4[4], va[4], vp[4];
#pragma unroll
        for (int q = 0; q < 4; ++q) {
            const int r = (g << 2) + q;
            ha4[q] = h0[(size_t)r * D_ + tid] + 0.3f * vh[r];
            va[q] = ha4[q] * ha4[q];
            vp[q] = pr[(g << 2) + q] * pr[(g << 2) + q];
        }
        blockSum4(va, scr4);
        blockSum4(vp, scr4);
#pragma unroll
        for (int q = 0; q < 4; ++q) {
            const int r = (g << 2) + q;
            wsA[(size_t)(rowBase + r) * KA_ + 128 + tid] =
                (ha4[q] / fmaxf(sqrtf(va[q]), 1e-12f)) * 2.5f;
            wsProbe[(size_t)(rowBase + r) * D_ + tid] = pr[r] / fmaxf(sqrtf(vp[q]), 1e-12f);
        }
    }
}

// Kernel A: all-pairs sims -> zg/zl.  512 blocks = b(4) x rowgroup(128),
// 8 rows/block (12KB A working set/block -> 2 blocks/CU fits L1), 512 threads,
// 2 cols/thread; B prefetched one group ahead (branch-free wrap).
// zl FINALIZED in-block (full-column blocks -> block-local hasNb).
__global__ __launch_bounds__(512) void sims_kernel(
    const float* __restrict__ msgT,     // [B][D][S]
    const float* __restrict__ scnT,     // [B][NS][S]
    const float* __restrict__ wsA,      // [4096][KA_]
    const int* __restrict__ wsMode,
    const void* __restrict__ maskP,
    const int* __restrict__ maskFlag,
    float* __restrict__ zgO,            // [4096][1024]
    float* __restrict__ zlO)            // [4096][1024]
{
    __shared__ int anySh[8];
    const int bid = blockIdx.x;          // 512 blocks
    const int b = bid >> 7;
    const int sg = bid & 127;
    const int sBase = sg << 3;           // 8 rows
    const int rowBase = (b << 10) + sBase;
    const int tid = threadIdx.x;         // 0..511
    const int lane = tid & 63;
    const int tcol = tid << 1;           // 2 cols

    if (tid < 8) anySh[tid] = 0;
    __syncthreads();

    const float* msgTb = msgT + (size_t)b * D_ * SEQ_;
    const float* scnTb = scnT + (size_t)b * NS_ * SEQ_;
    const float* A = wsA + (size_t)rowBase * KA_;

    float zg[8][2] = {};
    float zl[8][2] = {};
    float2 sv[4], svn[4];

    // ---- K-loop 1: e' (zg) and s' (zl) against scnT (K=64), prefetched ----
#pragma unroll
    for (int dj = 0; dj < 4; ++dj)
        sv[dj] = *(const float2*)(scnTb + (size_t)dj * SEQ_ + tcol);
#pragma unroll
    for (int dc = 0; dc < NS_; dc += 4) {
        const int dn = (dc + 4) & (NS_ - 1);     // wrap: last prefetch harmless
#pragma unroll
        for (int dj = 0; dj < 4; ++dj)
            svn[dj] = *(const float2*)(scnTb + (size_t)(dn + dj) * SEQ_ + tcol);
#pragma unroll
        for (int r = 0; r < 8; ++r) {
            const float4 e4 = *(const float4*)(A + r * KA_ + dc);        // uniform
            const float4 s4 = *(const float4*)(A + r * KA_ + 64 + dc);   // uniform
            zg[r][0] = fmaf(e4.x, sv[0].x, fmaf(e4.y, sv[1].x, fmaf(e4.z, sv[2].x, fmaf(e4.w, sv[3].x, zg[r][0]))));
            zg[r][1] = fmaf(e4.x, sv[0].y, fmaf(e4.y, sv[1].y, fmaf(e4.z, sv[2].y, fmaf(e4.w, sv[3].y, zg[r][1]))));
            zl[r][0] = fmaf(s4.x, sv[0].x, fmaf(s4.y, sv[1].x, fmaf(s4.z, sv[2].x, fmaf(s4.w, sv[3].x, zl[r][0]))));
            zl[r][1] = fmaf(s4.x, sv[0].y, fmaf(s4.y, sv[1].y, fmaf(s4.z, sv[2].y, fmaf(s4.w, sv[3].y, zl[r][1]))));
        }
#pragma unroll
        for (int dj = 0; dj < 4; ++dj) sv[dj] = svn[dj];
    }

    // ---- K-loop 2: h' (zg) against msgT (K=256), prefetched ----
#pragma unroll
    for (int dj = 0; dj < 4; ++dj)
        sv[dj] = *(const float2*)(msgTb + (size_t)dj * SEQ_ + tcol);
#pragma unroll 4
    for (int dc = 0; dc < D_; dc += 4) {
        const int dn = (dc + 4) & (D_ - 1);
#pragma unroll
        for (int dj = 0; dj < 4; ++dj)
            svn[dj] = *(const float2*)(msgTb + (size_t)(dn + dj) * SEQ_ + tcol);
#pragma unroll
        for (int r = 0; r < 8; ++r) {
            const float4 h4 = *(const float4*)(A + r * KA_ + 128 + dc);  // uniform
            zg[r][0] = fmaf(h4.x, sv[0].x, fmaf(h4.y, sv[1].x, fmaf(h4.z, sv[2].x, fmaf(h4.w, sv[3].x, zg[r][0]))));
            zg[r][1] = fmaf(h4.x, sv[0].y, fmaf(h4.y, sv[1].y, fmaf(h4.z, sv[2].y, fmaf(h4.w, sv[3].y, zg[r][1]))));
        }
#pragma unroll
        for (int dj = 0; dj < 4; ++dj) sv[dj] = svn[dj];
    }

    // ---- tail: mask + mode; write zg; finalize zl (block-local hasNb) ----
    const int mf = *maskFlag;
    const int2 md2 = *(const int2*)(wsMode + (b << 10) + tcol);
    float zlc[8][2];
    int any8 = 0;
#pragma unroll
    for (int r = 0; r < 8; ++r) {
        const int s_r = sBase + r;
        const int row = rowBase + r;
        const int mS = wsMode[row];                   // uniform
        int blk0, blk1;
        const size_t mb = (size_t)s_r * SEQ_ + tcol;
        if (mf == 1) {
            const unsigned char* m8 = (const unsigned char*)maskP;
            blk0 = m8[mb] != 0; blk1 = m8[mb + 1] != 0;
        } else if (mf == 2) {
            const float* mfl = (const float*)maskP;
            blk0 = mfl[mb] != 0.f; blk1 = mfl[mb + 1] != 0.f;
        } else {
            const int* m32 = (const int*)maskP;
            blk0 = m32[mb] != 0; blk1 = m32[mb + 1] != 0;
        }
        if (s_r == tcol) blk0 = 1;
        if (s_r == tcol + 1) blk1 = 1;
        *(float2*)(zgO + (size_t)row * SEQ_ + tcol) =
            make_float2(blk0 ? NEG_ : zg[r][0], blk1 ? NEG_ : zg[r][1]);
        const int sm0 = (!blk0) && (md2.x == mS);
        const int sm1 = (!blk1) && (md2.y == mS);
        any8 |= (sm0 | sm1) << r;
        zlc[r][0] = sm0 ? zl[r][0] : (blk0 ? BLKNEG_ : 0.0f);
        zlc[r][1] = sm1 ? zl[r][1] : (blk1 ? BLKNEG_ : 0.0f);
    }
#pragma unroll
    for (int r = 0; r < 8; ++r) {
        if (__any((any8 >> r) & 1) && lane == 0) atomicOr(&anySh[r], 1);
    }
    __syncthreads();
#pragma unroll
    for (int r = 0; r < 8; ++r) {
        const int s_r = sBase + r;
        const int row = rowBase + r;
        float zl0 = zlc[r][0], zl1 = zlc[r][1];
        if (!anySh[r]) {
            zl0 = (zl0 == BLKNEG_) ? BLKNEG_ : -0.05f * fabsf((float)(s_r - tcol));
            zl1 = (zl1 == BLKNEG_) ? BLKNEG_ : -0.05f * fabsf((float)(s_r - tcol - 1));
        }
        *(float2*)(zlO + (size_t)row * SEQ_ + tcol) = make_float2(zl0, zl1);
    }
}

// Kernel B: 4 waves per block, wave owns one row (mirror-balanced).
// Sparse combined gather; dense-support rows deferred to cleanup via queue.
__global__ __launch_bounds__(256) void route4_kernel(
    const float* __restrict__ messages,
    const float* __restrict__ scn,
    const int* __restrict__ x_ids,
    const int* __restrict__ static_nb,
    const float* __restrict__ W_e1,
    const float* __restrict__ b_e1,
    const float* __restrict__ W_e2,
    const float* __restrict__ b_e2,
    const float* __restrict__ wsProbe,
    const float* __restrict__ wsGw,
    const float* __restrict__ zgA,
    const float* __restrict__ zlA,
    float* __restrict__ wq,          // [MAXQ][1024] dense weights
    int* __restrict__ qRows,
    int* __restrict__ qMeta,         // [0]=tail, [1]=consume
    float* __restrict__ out)
{
    __shared__ uint2 lst[4][256];        // combined (t, weight) entries per wave
    __shared__ float ewLds[4][8];
    __shared__ int   mlist[4][64];

    const int jb = blockIdx.x;               // 0..1023
    const int tid = threadIdx.x;
    const int wid = tid >> 6, lane = tid & 63;
    const int base = jb << 1;
    const int row = (wid == 0) ? base
                  : (wid == 1) ? base + 1
                  : (wid == 2) ? 4094 - base
                               : 4095 - base;
    const int b = row >> 10, s_r = row & 1023;
    const float* msgB = messages + (size_t)b * SEQ_ * D_;
    const float* scnB = scn + (size_t)b * SEQ_ * NS_;
    const unsigned long long ltmask = (1ull << lane) - 1ull;
    const int d4 = lane << 2;

    // ----- issue z loads up-front (latency hidden by static branch) -----
    float zrG[16], zrL[16];
    {
        const float4* zgp = (const float4*)(zgA + (size_t)row * SEQ_ + (lane << 4));
        const float4* zlp = (const float4*)(zlA + (size_t)row * SEQ_ + (lane << 4));
#pragma unroll
        for (int q = 0; q < 4; ++q) {
            const float4 g4 = zgp[q];
            zrG[q * 4 + 0] = g4.x; zrG[q * 4 + 1] = g4.y;
            zrG[q * 4 + 2] = g4.z; zrG[q * 4 + 3] = g4.w;
            const float4 l4 = zlp[q];
            zrL[q * 4 + 0] = l4.x; zrL[q * 4 + 1] = l4.y;
            zrL[q * 4 + 2] = l4.z; zrL[q * 4 + 3] = l4.w;
        }
    }

    // ----- static neighbor-vocab scan: ONE ballot per 64-block (kmask) -----
    const int q = x_ids[row];
    int nb[KNB_];
#pragma unroll
    for (int k = 0; k < KNB_; ++k) nb[k] = static_nb[(size_t)q * KNB_ + k];
    const float ss_l = scnB[(size_t)s_r * NS_ + lane];
    float simk[KNB_] = {};
    unsigned matchedMask = 0;
    int mcW = 0;
    const int* xb = x_ids + (b << 10);
    for (int pb = 0; pb <= s_r; pb += 64) {
        const int p = pb + lane;
        const int id = (p <= s_r) ? xb[p] : -2147483647;
        unsigned kmask = 0;
#pragma unroll
        for (int k = 0; k < KNB_; ++k) kmask |= (id == nb[k]) ? (1u << k) : 0u;
        unsigned long long mb = __ballot(kmask != 0u);
        while (mb) {
            const int src = __ffsll(mb) - 1; mb &= mb - 1;
            const unsigned kms = (unsigned)__shfl((int)kmask, src, 64);
            const int pp = pb + src;
            float pv = scnB[(size_t)pp * NS_ + lane] * ss_l;
            pv = waveSum(pv);
            matchedMask |= kms;
#pragma unroll
            for (int k = 0; k < KNB_; ++k) {
                if ((kms >> k) & 1u) {
                    simk[k] += pv;
                    if (mcW < 64) { if (lane == 0) mlist[wid][mcW] = (pp << 3) | k; ++mcW; }
                }
            }
        }
    }
    // edge MLP: lane = k*8 + j computes one gelu term
    const int kk = lane >> 3, jjn = lane & 7;
    float sv = simk[0];
#pragma unroll
    for (int k = 1; k < KNB_; ++k) sv = (kk == k) ? simk[k] : sv;
    const float xx = sv * W_e1[jjn] + b_e1[jjn];
    float eo = 0.5f * xx * (1.f + erff(xx * 0.70710678118654752f)) * W_e2[jjn];
    eo += __shfl_xor(eo, 1, 64); eo += __shfl_xor(eo, 2, 64); eo += __shfl_xor(eo, 4, 64);
    eo += b_e2[0];
    float m2 = eo;
    m2 = fmaxf(m2, __shfl_xor(m2, 8, 64));
    m2 = fmaxf(m2, __shfl_xor(m2, 16, 64));
    m2 = fmaxf(m2, __shfl_xor(m2, 32, 64));
    const float exv = expf(eo - m2);
    float smv = exv;
    smv += __shfl_xor(smv, 8, 64); smv += __shfl_xor(smv, 16, 64); smv += __shfl_xor(smv, 32, 64);
    if ((lane & 7) == 0) ewLds[wid][kk] = exv / smv;

    const float cov = (float)__popc(matchedMask) * 0.125f;
    const float gw = wsGw[row];
    const float coefG = gw;
    const float coefL = (1.f - gw) * (1.f - cov);
    const float coefS = (1.f - gw) * cov;

    // ----- sparsemax taus + support sizes -----
    const float tauG = sparsemaxTauWave(zrG);
    int supG = 0;
#pragma unroll
    for (int j = 0; j < 16; ++j) supG += __popcll(__ballot(zrG[j] > tauG));
    const float tauL = sparsemaxTauWave(zrL);
    int supL = 0;
#pragma unroll
    for (int j = 0; j < 16; ++j) supL += __popcll(__ballot(zrL[j] > tauL));
    const bool gDense = supG > 96;
    const bool lDense = supL > 96;

    // ----- sparse list build (only for non-dense branches) -----
    int cnt = 0;
    if (!gDense) {
#pragma unroll
        for (int j = 0; j < 16; ++j) {
            const float wv = zrG[j] - tauG;
            const bool take = wv > 0.f;
            const unsigned long long m = __ballot(take);
            if (take) {
                const int pos = cnt + __popcll(m & ltmask);
                lst[wid][pos] = make_uint2((unsigned)((lane << 4) + j),
                                           __float_as_uint(coefG * wv));
            }
            cnt += __popcll(m);
        }
    }
    if (!lDense) {
#pragma unroll
        for (int j = 0; j < 16; ++j) {
            const float wv = zrL[j] - tauL;
            const bool take = wv > 0.f;
            const unsigned long long m = __ballot(take);
            if (take) {
                const int pos = cnt + __popcll(m & ltmask);
                lst[wid][pos] = make_uint2((unsigned)((lane << 4) + j),
                                           __float_as_uint(coefL * wv));
            }
            cnt += __popcll(m);
        }
    }
    // static entries appended (lane-parallel)
    const int nm = (mcW < 64) ? mcW : 64;
    for (int i = lane; i < nm; i += 64) {
        const int ee = mlist[wid][i];
        lst[wid][cnt + i] = make_uint2((unsigned)(ee >> 3),
                                       __float_as_uint(coefS * ewLds[wid][ee & 7]));
    }
    cnt += nm;

    // ----- combined sparse gather, shfl-free, unroll x4 -----
    float ox = 0.f, oy = 0.f, oz2 = 0.f, ow = 0.f;
    int i = 0;
    for (; i + 4 <= cnt; i += 4) {
        const uint2 e0 = lst[wid][i + 0];
        const uint2 e1 = lst[wid][i + 1];
        const uint2 e2 = lst[wid][i + 2];
        const uint2 e3 = lst[wid][i + 3];
        const float4 m0 = *(const float4*)(msgB + (size_t)e0.x * D_ + d4);
        const float4 m1 = *(const float4*)(msgB + (size_t)e1.x * D_ + d4);
        const float4 m2b = *(const float4*)(msgB + (size_t)e2.x * D_ + d4);
        const float4 m3 = *(const float4*)(msgB + (size_t)e3.x * D_ + d4);
        const float w0 = __uint_as_float(e0.y), w1 = __uint_as_float(e1.y);
        const float w2 = __uint_as_float(e2.y), w3 = __uint_as_float(e3.y);
        ox = fmaf(w0, m0.x, fmaf(w1, m1.x, fmaf(w2, m2b.x, fmaf(w3, m3.x, ox))));
        oy = fmaf(w0, m0.y, fmaf(w1, m1.y, fmaf(w2, m2b.y, fmaf(w3, m3.y, oy))));
        oz2 = fmaf(w0, m0.z, fmaf(w1, m1.z, fmaf(w2, m2b.z, fmaf(w3, m3.z, oz2))));
        ow = fmaf(w0, m0.w, fmaf(w1, m1.w, fmaf(w2, m2b.w, fmaf(w3, m3.w, ow))));
    }
    for (; i < cnt; ++i) {
        const uint2 e0 = lst[wid][i];
        const float w0 = __uint_as_float(e0.y);
        const float4 m0 = *(const float4*)(msgB + (size_t)e0.x * D_ + d4);
        ox = fmaf(w0, m0.x, ox); oy = fmaf(w0, m0.y, oy);
        oz2 = fmaf(w0, m0.z, oz2); ow = fmaf(w0, m0.w, ow);
    }

    // ----- dense branches: enqueue for cleanup (or rare overflow fallback) -----
    int slot = -1;
    if (gDense || lDense) {
        int s0 = 0;
        if (lane == 0) s0 = atomicAdd(&qMeta[0], 1);
        slot = __shfl(s0, 0, 64);
    }
    if (slot >= 0 && slot < MAXQ_) {
        // write combined dense weights; raw partial to out; skip epilogue
#pragma unroll
        for (int qd = 0; qd < 4; ++qd) {
            float4 w4;
            float* wv4 = &w4.x;
#pragma unroll
            for (int u = 0; u < 4; ++u) {
                const int j = qd * 4 + u;
                float w = 0.f;
                if (gDense) w += coefG * fmaxf(zrG[j] - tauG, 0.f);
                if (lDense) w += coefL * fmaxf(zrL[j] - tauL, 0.f);
                wv4[u] = w;
            }
            *(float4*)(wq + (size_t)slot * SEQ_ + (lane << 4) + qd * 4) = w4;
        }
        if (lane == 0) qRows[slot] = row;
        *(float4*)(out + (size_t)row * D_ + d4) = make_float4(ox, oy, oz2, ow);
        return;   // wave done (other waves unaffected; no block barriers used)
    }
    if (slot >= MAXQ_) {
        // overflow fallback (effectively never): shfl-walk dense accumulate
#pragma unroll
        for (int j = 0; j < 16; ++j) {
            float wv = 0.f;
            if (gDense) wv += coefG * fmaxf(zrG[j] - tauG, 0.f);
            if (lDense) wv += coefL * fmaxf(zrL[j] - tauL, 0.f);
            unsigned long long m = __ballot(wv > 0.f);
            while (m) {
                const int s0 = __ffsll(m) - 1; m &= m - 1;
                const float w0 = __shfl(wv, s0, 64);
                const float4 m4 = *(const float4*)(msgB + (size_t)((s0 << 4) + j) * D_ + d4);
                ox = fmaf(w0, m4.x, ox); oy = fmaf(w0, m4.y, oy);
                oz2 = fmaf(w0, m4.z, oz2); ow = fmaf(w0, m4.w, ow);
            }
        }
    }

    // ----- epilogue: normalize, probe, rel -----
    float ssq = ox * ox + oy * oy + oz2 * oz2 + ow * ow;
    ssq = waveSum(ssq);
    const float nrm = fmaxf(sqrtf(ssq), 1e-12f);
    const float4 pr = *(const float4*)(wsProbe + (size_t)row * D_ + d4);
    float dp = (ox * pr.x + oy * pr.y + oz2 * pr.z + ow * pr.w) / nrm;
    dp = waveSum(dp);
    const float rel = 1.f / (1.f + expf(-dp));
    *(float4*)(out + (size_t)row * D_ + d4) =
        make_float4(ox * rel, oy * rel, oz2 * rel, ow * rel);
}

// Kernel C: drain dense-row queue. One block per row: branch-free coalesced
// 1024-step GEMV + partial add + epilogue.
__global__ __launch_bounds__(256) void cleanup_kernel(
    const float* __restrict__ messages,
    const float* __restrict__ wsProbe,
    const float* __restrict__ wq,
    const int* __restrict__ qRows,
    int* __restrict__ qMeta,
    float* __restrict__ out)
{
    __shared__ float wsh[SEQ_];
    __shared__ float scr[4];
    __shared__ int idxSh;
    const int tid = threadIdx.x;
    const int nq = (qMeta[0] < MAXQ_) ? qMeta[0] : MAXQ_;
    for (;;) {
        __syncthreads();
        if (tid == 0) idxSh = atomicAdd(&qMeta[1], 1);
        __syncthreads();
        const int idx = idxSh;
        if (idx >= nq) break;
        const int row = qRows[idx];
        const int b = row >> 10;
        const float* msgB = messages + (size_t)b * SEQ_ * D_;
        for (int i = tid; i < SEQ_; i += 256)
            wsh[i] = wq[(size_t)idx * SEQ_ + i];
        __syncthreads();
        float acc = out[(size_t)row * D_ + tid];   // sparse partial from route4
        for (int t = 0; t < SEQ_; t += 4) {
            acc = fmaf(wsh[t + 0], msgB[(size_t)(t + 0) * D_ + tid],
                  fmaf(wsh[t + 1], msgB[(size_t)(t + 1) * D_ + tid],
                  fmaf(wsh[t + 2], msgB[(size_t)(t + 2) * D_ + tid],
                  fmaf(wsh[t + 3], msgB[(size_t)(t + 3) * D_ + tid], acc))));
        }
        const float ssq = blockSum(acc * acc, scr);
        const float nrm = fmaxf(sqrtf(ssq), 1e-12f);
        const float dp = blockSum((acc / nrm) * wsProbe[(size_t)row * D_ + tid], scr);
        const float rel = 1.f / (1.f + expf(-dp));
        out[(size_t)row * D_ + tid] = acc * rel;
    }
}

extern "C" void kernel_launch(void* const* d_in, const int* in_sizes, int n_in,
                              void* d_out, int out_size, void* d_ws, size_t ws_size,
                              hipStream_t stream) {
    const float* messages  = (const float*)d_in[0];
    const float* hidden    = (const float*)d_in[1];
    const int*   x_ids     = (const int*)d_in[2];
    const float* scn       = (const float*)d_in[3];
    const void*  mask      = d_in[4];
    const int*   static_nb = (const int*)d_in[5];
    const float* gvel      = (const float*)d_in[6];
    const float* ctx       = (const float*)d_in[7];
    const float* ent       = (const float*)d_in[8];
    const float* W_vel     = (const float*)d_in[9];
    const float* W_e1      = (const float*)d_in[10];
    const float* b_e1      = (const float*)d_in[11];
    const float* W_e2      = (const float*)d_in[12];
    const float* b_e2      = (const float*)d_in[13];
    const float* W_probe   = (const float*)d_in[14];
    const float* W_gate    = (const float*)d_in[15];
    const float* b_gate    = (const float*)d_in[16];
    float* out = (float*)d_out;
    (void)in_sizes; (void)n_in; (void)out_size; (void)ws_size;

    char* ws = (char*)d_ws;
    size_t o = 0;
    int* flag      = (int*)(ws + o);   o += 256;
    float* wsA     = (float*)(ws + o); o += (size_t)B_ * SEQ_ * KA_ * 4;   // 6.3 MB
    float* wsProbe = (float*)(ws + o); o += (size_t)B_ * SEQ_ * D_ * 4;
    int* wsMode    = (int*)(ws + o);   o += (size_t)B_ * SEQ_ * 4;
    float* wsGw    = (float*)(ws + o); o += (size_t)B_ * SEQ_ * 4;
    float* msgT    = (float*)(ws + o); o += (size_t)B_ * D_ * SEQ_ * 4;    // 4 MB
    float* scnT    = (float*)(ws + o); o += (size_t)B_ * NS_ * SEQ_ * 4;
    float* zgW     = (float*)(ws + o); o += (size_t)B_ * SEQ_ * SEQ_ * 4;
    float* zlW     = (float*)(ws + o); o += (size_t)B_ * SEQ_ * SEQ_ * 4;
    int* qMeta     = (int*)(ws + o);   o += 256;
    int* qRows     = (int*)(ws + o);   o += (size_t)MAXQ_ * 4;
    // dense-weight buffer overlays msgT (msgT is dead after sims_kernel)
    float* wq      = msgT;             // MAXQ * 1024 * 4 = 4 MB = sizeof(msgT)

    setup_kernel<<<dim3(1793), dim3(256), 0, stream>>>(
        messages, scn, hidden, gvel, ctx, ent, W_probe, W_vel, W_gate, b_gate,
        msgT, scnT, (const unsigned int*)mask, flag, qMeta,
        wsA, wsProbe, wsMode, wsGw);
    sims_kernel<<<dim3(512), dim3(512), 0, stream>>>(
        msgT, scnT, wsA, wsMode, mask, flag, zgW, zlW);
    route4_kernel<<<dim3(B_ * SEQ_ / 4), dim3(256), 0, stream>>>(
        messages, scn, x_ids, static_nb, W_e1, b_e1, W_e2, b_e2,
        wsProbe, wsGw, zgW, zlW, wq, qRows, qMeta, out);
    cleanup_kernel<<<dim3(64), dim3(256), 0, stream>>>(
        messages, wsProbe, wq, qRows, qMeta, out);
}

// Round 11
// 145.610 us; speedup vs baseline: 1.6910x; 1.6910x over previous
//
#include <hip/hip_runtime.h>
#include <math.h>

#define D_ 256
#define NS_ 64
#define KNB_ 8
#define SEQ_ 1024
#define B_ 4
#define MAXQ_ 1024
#define KA_ 384            // prescaled A row: [e'(64) | s'(64) | h'(256)]
#define NEG_ (-10000.0f)
#define BLKNEG_ (-50000.0f)

typedef short bf16x8 __attribute__((ext_vector_type(8)));
typedef float f32x4 __attribute__((ext_vector_type(4)));

__device__ __forceinline__ float waveSum(float v) {
#pragma unroll
    for (int off = 32; off; off >>= 1) v += __shfl_xor(v, off, 64);
    return v;
}

__device__ __forceinline__ void waveSum2(float& a, float& b) {
#pragma unroll
    for (int off = 32; off; off >>= 1) {
        a += __shfl_xor(a, off, 64);
        b += __shfl_xor(b, off, 64);
    }
}

__device__ __forceinline__ float blockSum(float v, float* scr) {
    const int tid = threadIdx.x;
    const int wid = tid >> 6, lane = tid & 63;
    v = waveSum(v);
    __syncthreads();
    if (lane == 0) scr[wid] = v;
    __syncthreads();
    return scr[0] + scr[1] + scr[2] + scr[3];
}

__device__ __forceinline__ void blockSum4(float v[4], float (*scr4)[4]) {
    const int tid = threadIdx.x;
    const int wid = tid >> 6, lane = tid & 63;
#pragma unroll
    for (int off = 32; off; off >>= 1) {
#pragma unroll
        for (int q = 0; q < 4; ++q) v[q] += __shfl_xor(v[q], off, 64);
    }
    __syncthreads();
    if (lane == 0) {
#pragma unroll
        for (int q = 0; q < 4; ++q) scr4[wid][q] = v[q];
    }
    __syncthreads();
#pragma unroll
    for (int q = 0; q < 4; ++q)
        v[q] = scr4[0][q] + scr4[1][q] + scr4[2][q] + scr4[3][q];
}

// exact sparsemax tau via support iteration (monotone, fixpoint = exact tau)
__device__ __forceinline__ float sparsemaxTauWave(const float* zr) {
    float mx = zr[0];
#pragma unroll
    for (int i = 1; i < 16; ++i) mx = fmaxf(mx, zr[i]);
#pragma unroll
    for (int off = 32; off; off >>= 1) mx = fmaxf(mx, __shfl_xor(mx, off, 64));
    float tau = mx - 1.0f;
    for (int it = 0; it < 32; ++it) {
        float ssum = 0.f, cnt = 0.f;
#pragma unroll
        for (int i = 0; i < 16; ++i) {
            if (zr[i] > tau) { ssum += zr[i]; cnt += 1.f; }
        }
        waveSum2(ssum, cnt);
        if (cnt < 0.5f) break;
        const float nt = (ssum - 1.0f) / cnt;
        if (nt == tau) break;
        tau = nt;
    }
    return tau;
}

// split fp32 -> bf16 hi + bf16 lo (truncation; a ~= hi + lo, err ~2^-16 rel)
__device__ __forceinline__ void cvtSplit(float a, short& h, short& l) {
    const unsigned ab = __float_as_uint(a);
    h = (short)(ab >> 16);
    const float hf = __uint_as_float(ab & 0xFFFF0000u);
    l = (short)(__float_as_uint(a - hf) >> 16);
}

// Fused setup: bf16-split conversions + mask detect + per-row prep.
// blocks [0,256): messages -> msgH/msgL; [256,320): scn -> scnH/scnL;
// 320: mask detect + counter zero; [321,833): prep (8 rows each).
__global__ __launch_bounds__(256) void setup_kernel(
    const float* __restrict__ messages, const float* __restrict__ scn,
    const float* __restrict__ hidden, const float* __restrict__ gvel,
    const float* __restrict__ ctx, const float* __restrict__ ent,
    const float* __restrict__ W_probe, const float* __restrict__ W_vel,
    const float* __restrict__ W_gate, const float* __restrict__ b_gate,
    short* __restrict__ msgH, short* __restrict__ msgL,
    short* __restrict__ scnH, short* __restrict__ scnL,
    const unsigned int* __restrict__ maskW, int* __restrict__ flag,
    int* __restrict__ qMeta,
    short* __restrict__ wsAh, short* __restrict__ wsAl,
    float* __restrict__ wsProbe,
    int* __restrict__ wsMode, float* __restrict__ wsGw)
{
    const int bid = blockIdx.x;
    const int tid = threadIdx.x;

    if (bid < 320) {   // conversions
        const float* src; short* dh; short* dl; size_t base;
        if (bid < 256) { src = messages; dh = msgH; dl = msgL; base = (size_t)bid * 4096 + tid * 4; }
        else           { src = scn; dh = scnH; dl = scnL; base = (size_t)(bid - 256) * 4096 + tid * 4; }
#pragma unroll
        for (int i = 0; i < 4; ++i) {
            const size_t o = base + (size_t)i * 1024;
            const float4 v = *(const float4*)(src + o);
            short4 h4, l4;
            cvtSplit(v.x, h4.x, l4.x);
            cvtSplit(v.y, h4.y, l4.y);
            cvtSplit(v.z, h4.z, l4.z);
            cvtSplit(v.w, h4.w, l4.w);
            *(short4*)(dh + o) = h4;
            *(short4*)(dl + o) = l4;
        }
        return;
    }

    if (bid == 320) {
        __shared__ int notI, notF;
        if (tid == 0) { notI = 0; notF = 0; qMeta[0] = 0; qMeta[1] = 0; }
        __syncthreads();
        int ni = 0, nf = 0;
        for (int i = tid; i < 1024; i += 256) {
            const unsigned int w = maskW[i];
            if (w != 0u && w != 1u) ni = 1;
            if (w != 0u && w != 0x3f800000u) nf = 1;
        }
        if (ni) atomicOr(&notI, 1);
        if (nf) atomicOr(&notF, 1);
        __syncthreads();
        if (tid == 0) *flag = (!notI) ? 0 : ((!notF) ? 2 : 1);
        return;
    }

    // ---- prep: 8 rows per block ----
    __shared__ float scr4[4][4];
    const int rowBase = (bid - 321) << 3;
    const int wid = tid >> 6, lane = tid & 63;
    const float* h0 = hidden + (size_t)rowBase * D_;

    float vh[8] = {};
    for (int e = 0; e < NS_; e += 4) {
        const float4 wv4 = *(const float4*)(W_vel + (size_t)tid * NS_ + e);  // thread-own row
#pragma unroll
        for (int r = 0; r < 8; ++r) {
            const float4 g4 = *(const float4*)(gvel + (size_t)(rowBase + r) * NS_ + e); // uniform
            vh[r] = fmaf(g4.x, wv4.x, fmaf(g4.y, wv4.y, fmaf(g4.z, wv4.z, fmaf(g4.w, wv4.w, vh[r]))));
        }
    }
    float pr[8] = {};
    for (int e = 0; e < D_; e += 4) {
        const float4 wp4 = *(const float4*)(W_probe + (size_t)tid * D_ + e);  // thread-own row
#pragma unroll
        for (int r = 0; r < 8; ++r) {
            const float4 h4 = *(const float4*)(h0 + (size_t)r * D_ + e);      // uniform
            pr[r] = fmaf(h4.x, wp4.x, fmaf(h4.y, wp4.y, fmaf(h4.z, wp4.z, fmaf(h4.w, wp4.w, pr[r]))));
        }
    }

    // per-wave: wave w handles rows 2w, 2w+1 (endpoint, s', argmax, gate)
#pragma unroll
    for (int rr = 0; rr < 2; ++rr) {
        const int r = (wid << 1) + rr, row = rowBase + r;
        const float sv = scn[(size_t)row * NS_ + lane];
        const float gv = gvel[(size_t)row * NS_ + lane];
        const float Hn = ent[row] / 10.373491191781864f;   // log(32000)+1e-8
        const float e = sv + 0.4f * gv;
        const float ss = waveSum(e * e);
        short hh, ll;
        cvtSplit((e / fmaxf(sqrtf(ss), 1e-12f)) * 5.0f * Hn, hh, ll);
        wsAh[(size_t)row * KA_ + lane] = hh;
        wsAl[(size_t)row * KA_ + lane] = ll;
        cvtSplit(5.0f * sv, hh, ll);
        wsAh[(size_t)row * KA_ + 64 + lane] = hh;
        wsAl[(size_t)row * KA_ + 64 + lane] = ll;
        float v = sv; int idx = lane;
#pragma unroll
        for (int off = 1; off < 64; off <<= 1) {
            const float ov = __shfl_xor(v, off, 64);
            const int   oi = __shfl_xor(idx, off, 64);
            if (ov > v || (ov == v && oi < idx)) { v = ov; idx = oi; }
        }
        float gd = 0.f;
#pragma unroll
        for (int j = 0; j < 4; ++j) {
            const int d = lane + (j << 6);
            gd = fmaf(h0[(size_t)r * D_ + d], W_gate[d], gd);
        }
        gd = waveSum(gd);
        if (lane == 0) {
            wsMode[row] = idx;
            const float raw = 1.f / (1.f + expf(-(gd + b_gate[0])));
            wsGw[row] = raw * ctx[row];
        }
    }

    // block-wide norms, 4 rows per batched reduction
#pragma unroll
    for (int g = 0; g < 2; ++g) {
        float ha4[4], va[4], vp[4];
#pragma unroll
        for (int q = 0; q < 4; ++q) {
            const int r = (g << 2) + q;
            ha4[q] = h0[(size_t)r * D_ + tid] + 0.3f * vh[r];
            va[q] = ha4[q] * ha4[q];
            vp[q] = pr[(g << 2) + q] * pr[(g << 2) + q];
        }
        blockSum4(va, scr4);
        blockSum4(vp, scr4);
#pragma unroll
        for (int q = 0; q < 4; ++q) {
            const int r = (g << 2) + q;
            short hh, ll;
            cvtSplit((ha4[q] / fmaxf(sqrtf(va[q]), 1e-12f)) * 2.5f, hh, ll);
            wsAh[(size_t)(rowBase + r) * KA_ + 128 + tid] = hh;
            wsAl[(size_t)(rowBase + r) * KA_ + 128 + tid] = ll;
            wsProbe[(size_t)(rowBase + r) * D_ + tid] = pr[r] / fmaxf(sqrtf(vp[q]), 1e-12f);
        }
    }
}

// Kernel A: all-pairs sims via split-bf16 MFMA (3-pass: hh + hl + lh).
// 256 blocks (b x 64 rowgroups), 512 thr = 8 waves; BM=16 rows, BN=1024 cols.
// Wave w owns 8 col-tiles of 16. A frag: row=lane&15, k=(lane>>4)*8+j (wsA rows).
// B frag: col=lane&15, k=(lane>>4)*8+j -> contiguous k in ROW-MAJOR messages/scn.
// C frag: col=lane&15, row=(lane>>4)*4+reg [verified m89/m91].
__global__ __launch_bounds__(512) void sims_kernel(
    const short* __restrict__ msgH, const short* __restrict__ msgL,   // [B][S][D]
    const short* __restrict__ scnH, const short* __restrict__ scnL,   // [B][S][NS]
    const short* __restrict__ wsAh, const short* __restrict__ wsAl,   // [4096][KA_]
    const int* __restrict__ wsMode,
    const void* __restrict__ maskP,
    const int* __restrict__ maskFlag,
    float* __restrict__ zgO,            // [4096][1024]
    float* __restrict__ zlO)            // [4096][1024]
{
    __shared__ int anySh[16];
    const int bid = blockIdx.x;          // 256 blocks
    const int b = bid >> 6;
    const int sBase = (bid & 63) << 4;   // 16 rows
    const int rowBase = (b << 10) + sBase;
    const int tid = threadIdx.x;
    const int w = tid >> 6, l = tid & 63;
    const int m16 = l & 15, kq = l >> 4;
    const int kq8 = kq << 3;

    if (tid < 16) anySh[tid] = 0;
    __syncthreads();

    const short* mHb = msgH + (size_t)b * SEQ_ * D_;
    const short* mLb = msgL + (size_t)b * SEQ_ * D_;
    const short* sHb = scnH + (size_t)b * SEQ_ * NS_;
    const short* sLb = scnL + (size_t)b * SEQ_ * NS_;
    const short* Ah = wsAh + (size_t)rowBase * KA_ + (size_t)m16 * KA_;
    const short* Al = wsAl + (size_t)rowBase * KA_ + (size_t)m16 * KA_;

    f32x4 accG[8], accL8[8];
#pragma unroll
    for (int ct = 0; ct < 8; ++ct) {
        accG[ct] = (f32x4){0.f, 0.f, 0.f, 0.f};
        accL8[ct] = (f32x4){0.f, 0.f, 0.f, 0.f};
    }

    // ---- zg: 10 k-steps (e' x scn: 2 steps, h' x messages: 8 steps) ----
#pragma unroll
    for (int st = 0; st < 10; ++st) {
        const int koffA = (st < 2) ? (st << 5) : (128 + ((st - 2) << 5));
        const bf16x8 ah = *(const bf16x8*)(Ah + koffA + kq8);
        const bf16x8 al = *(const bf16x8*)(Al + koffA + kq8);
        const short* BH = (st < 2) ? sHb : mHb;
        const short* BL = (st < 2) ? sLb : mLb;
        const int ldb = (st < 2) ? NS_ : D_;
        const int koffB = ((st < 2) ? (st << 5) : ((st - 2) << 5)) + kq8;
#pragma unroll
        for (int ct = 0; ct < 8; ++ct) {
            const int t = (((w << 3) + ct) << 4) + m16;
            const bf16x8 bh = *(const bf16x8*)(BH + (size_t)t * ldb + koffB);
            const bf16x8 bl = *(const bf16x8*)(BL + (size_t)t * ldb + koffB);
            accG[ct] = __builtin_amdgcn_mfma_f32_16x16x32_bf16(ah, bh, accG[ct], 0, 0, 0);
            accG[ct] = __builtin_amdgcn_mfma_f32_16x16x32_bf16(ah, bl, accG[ct], 0, 0, 0);
            accG[ct] = __builtin_amdgcn_mfma_f32_16x16x32_bf16(al, bh, accG[ct], 0, 0, 0);
        }
    }
    // ---- zl: 2 k-steps (s' x scn) ----
#pragma unroll
    for (int st = 0; st < 2; ++st) {
        const int koffA = 64 + (st << 5);
        const bf16x8 ah = *(const bf16x8*)(Ah + koffA + kq8);
        const bf16x8 al = *(const bf16x8*)(Al + koffA + kq8);
        const int koffB = (st << 5) + kq8;
#pragma unroll
        for (int ct = 0; ct < 8; ++ct) {
            const int t = (((w << 3) + ct) << 4) + m16;
            const bf16x8 bh = *(const bf16x8*)(sHb + (size_t)t * NS_ + koffB);
            const bf16x8 bl = *(const bf16x8*)(sLb + (size_t)t * NS_ + koffB);
            accL8[ct] = __builtin_amdgcn_mfma_f32_16x16x32_bf16(ah, bh, accL8[ct], 0, 0, 0);
            accL8[ct] = __builtin_amdgcn_mfma_f32_16x16x32_bf16(ah, bl, accL8[ct], 0, 0, 0);
            accL8[ct] = __builtin_amdgcn_mfma_f32_16x16x32_bf16(al, bh, accL8[ct], 0, 0, 0);
        }
    }

    // ---- tail: mask + mode; write zg; collect hasNb; finalize zl ----
    const int mf = *maskFlag;
    const int4 mS4 = *(const int4*)(wsMode + rowBase + (kq << 2));   // this lane's 4 rows
    const int mSq[4] = {mS4.x, mS4.y, mS4.z, mS4.w};
    unsigned blkbits = 0, smbits = 0;
#pragma unroll
    for (int ct = 0; ct < 8; ++ct) {
        const int t = (((w << 3) + ct) << 4) + m16;
        const int mdt = wsMode[(b << 10) + t];
#pragma unroll
        for (int q = 0; q < 4; ++q) {
            const int r = (kq << 2) + q;
            const int s_r = sBase + r;
            const size_t mb = (size_t)s_r * SEQ_ + t;
            int blk;
            if (mf == 1)      blk = ((const unsigned char*)maskP)[mb] != 0;
            else if (mf == 2) blk = ((const float*)maskP)[mb] != 0.f;
            else              blk = ((const int*)maskP)[mb] != 0;
            if (s_r == t) blk = 1;
            zgO[(size_t)(rowBase + r) * SEQ_ + t] = blk ? NEG_ : accG[ct][q];
            const int sm = (!blk) && (mdt == mSq[q]);
            blkbits |= (unsigned)blk << ((ct << 2) + q);
            smbits |= (unsigned)sm << ((ct << 2) + q);
        }
    }
#pragma unroll
    for (int q = 0; q < 4; ++q) {
        int any_q = 0;
#pragma unroll
        for (int ct = 0; ct < 8; ++ct) any_q |= (smbits >> ((ct << 2) + q)) & 1;
        if (any_q) atomicOr(&anySh[(kq << 2) + q], 1);
    }
    __syncthreads();
#pragma unroll
    for (int ct = 0; ct < 8; ++ct) {
        const int t = (((w << 3) + ct) << 4) + m16;
#pragma unroll
        for (int q = 0; q < 4; ++q) {
            const int r = (kq << 2) + q;
            const int s_r = sBase + r;
            const int blk = (blkbits >> ((ct << 2) + q)) & 1;
            const int sm = (smbits >> ((ct << 2) + q)) & 1;
            float z;
            if (blk) z = BLKNEG_;
            else if (anySh[r]) z = sm ? accL8[ct][q] : 0.0f;
            else z = -0.05f * fabsf((float)(s_r - t));
            zlO[(size_t)(rowBase + r) * SEQ_ + t] = z;
        }
    }
}

// Kernel B: 4 waves per block, wave owns one row (mirror-balanced).
// Sparse combined gather; dense-support rows deferred to cleanup via queue.
__global__ __launch_bounds__(256) void route4_kernel(
    const float* __restrict__ messages,
    const float* __restrict__ scn,
    const int* __restrict__ x_ids,
    const int* __restrict__ static_nb,
    const float* __restrict__ W_e1,
    const float* __restrict__ b_e1,
    const float* __restrict__ W_e2,
    const float* __restrict__ b_e2,
    const float* __restrict__ wsProbe,
    const float* __restrict__ wsGw,
    const float* __restrict__ zgA,
    const float* __restrict__ zlA,
    float* __restrict__ wq,          // [MAXQ][1024] dense weights
    int* __restrict__ qRows,
    int* __restrict__ qMeta,         // [0]=tail, [1]=consume
    float* __restrict__ out)
{
    __shared__ uint2 lst[4][256];
    __shared__ float ewLds[4][8];
    __shared__ int   mlist[4][64];

    const int jb = blockIdx.x;               // 0..1023
    const int tid = threadIdx.x;
    const int wid = tid >> 6, lane = tid & 63;
    const int base = jb << 1;
    const int row = (wid == 0) ? base
                  : (wid == 1) ? base + 1
                  : (wid == 2) ? 4094 - base
                               : 4095 - base;
    const int b = row >> 10, s_r = row & 1023;
    const float* msgB = messages + (size_t)b * SEQ_ * D_;
    const float* scnB = scn + (size_t)b * SEQ_ * NS_;
    const unsigned long long ltmask = (1ull << lane) - 1ull;
    const int d4 = lane << 2;

    float zrG[16], zrL[16];
    {
        const float4* zgp = (const float4*)(zgA + (size_t)row * SEQ_ + (lane << 4));
        const float4* zlp = (const float4*)(zlA + (size_t)row * SEQ_ + (lane << 4));
#pragma unroll
        for (int q = 0; q < 4; ++q) {
            const float4 g4 = zgp[q];
            zrG[q * 4 + 0] = g4.x; zrG[q * 4 + 1] = g4.y;
            zrG[q * 4 + 2] = g4.z; zrG[q * 4 + 3] = g4.w;
            const float4 l4 = zlp[q];
            zrL[q * 4 + 0] = l4.x; zrL[q * 4 + 1] = l4.y;
            zrL[q * 4 + 2] = l4.z; zrL[q * 4 + 3] = l4.w;
        }
    }

    // ----- static neighbor-vocab scan: ONE ballot per 64-block (kmask) -----
    const int q = x_ids[row];
    int nb[KNB_];
#pragma unroll
    for (int k = 0; k < KNB_; ++k) nb[k] = static_nb[(size_t)q * KNB_ + k];
    const float ss_l = scnB[(size_t)s_r * NS_ + lane];
    float simk[KNB_] = {};
    unsigned matchedMask = 0;
    int mcW = 0;
    const int* xb = x_ids + (b << 10);
    for (int pb = 0; pb <= s_r; pb += 64) {
        const int p = pb + lane;
        const int id = (p <= s_r) ? xb[p] : -2147483647;
        unsigned kmask = 0;
#pragma unroll
        for (int k = 0; k < KNB_; ++k) kmask |= (id == nb[k]) ? (1u << k) : 0u;
        unsigned long long mb = __ballot(kmask != 0u);
        while (mb) {
            const int src = __ffsll(mb) - 1; mb &= mb - 1;
            const unsigned kms = (unsigned)__shfl((int)kmask, src, 64);
            const int pp = pb + src;
            float pv = scnB[(size_t)pp * NS_ + lane] * ss_l;
            pv = waveSum(pv);
            matchedMask |= kms;
#pragma unroll
            for (int k = 0; k < KNB_; ++k) {
                if ((kms >> k) & 1u) {
                    simk[k] += pv;
                    if (mcW < 64) { if (lane == 0) mlist[wid][mcW] = (pp << 3) | k; ++mcW; }
                }
            }
        }
    }
    const int kk = lane >> 3, jjn = lane & 7;
    float sv = simk[0];
#pragma unroll
    for (int k = 1; k < KNB_; ++k) sv = (kk == k) ? simk[k] : sv;
    const float xx = sv * W_e1[jjn] + b_e1[jjn];
    float eo = 0.5f * xx * (1.f + erff(xx * 0.70710678118654752f)) * W_e2[jjn];
    eo += __shfl_xor(eo, 1, 64); eo += __shfl_xor(eo, 2, 64); eo += __shfl_xor(eo, 4, 64);
    eo += b_e2[0];
    float m2 = eo;
    m2 = fmaxf(m2, __shfl_xor(m2, 8, 64));
    m2 = fmaxf(m2, __shfl_xor(m2, 16, 64));
    m2 = fmaxf(m2, __shfl_xor(m2, 32, 64));
    const float exv = expf(eo - m2);
    float smv = exv;
    smv += __shfl_xor(smv, 8, 64); smv += __shfl_xor(smv, 16, 64); smv += __shfl_xor(smv, 32, 64);
    if ((lane & 7) == 0) ewLds[wid][kk] = exv / smv;

    const float cov = (float)__popc(matchedMask) * 0.125f;
    const float gw = wsGw[row];
    const float coefG = gw;
    const float coefL = (1.f - gw) * (1.f - cov);
    const float coefS = (1.f - gw) * cov;

    const float tauG = sparsemaxTauWave(zrG);
    int supG = 0;
#pragma unroll
    for (int j = 0; j < 16; ++j) supG += __popcll(__ballot(zrG[j] > tauG));
    const float tauL = sparsemaxTauWave(zrL);
    int supL = 0;
#pragma unroll
    for (int j = 0; j < 16; ++j) supL += __popcll(__ballot(zrL[j] > tauL));
    const bool gDense = supG > 96;
    const bool lDense = supL > 96;

    int cnt = 0;
    if (!gDense) {
#pragma unroll
        for (int j = 0; j < 16; ++j) {
            const float wv = zrG[j] - tauG;
            const bool take = wv > 0.f;
            const unsigned long long m = __ballot(take);
            if (take) {
                const int pos = cnt + __popcll(m & ltmask);
                lst[wid][pos] = make_uint2((unsigned)((lane << 4) + j),
                                           __float_as_uint(coefG * wv));
            }
            cnt += __popcll(m);
        }
    }
    if (!lDense) {
#pragma unroll
        for (int j = 0; j < 16; ++j) {
            const float wv = zrL[j] - tauL;
            const bool take = wv > 0.f;
            const unsigned long long m = __ballot(take);
            if (take) {
                const int pos = cnt + __popcll(m & ltmask);
                lst[wid][pos] = make_uint2((unsigned)((lane << 4) + j),
                                           __float_as_uint(coefL * wv));
            }
            cnt += __popcll(m);
        }
    }
    const int nm = (mcW < 64) ? mcW : 64;
    for (int i = lane; i < nm; i += 64) {
        const int ee = mlist[wid][i];
        lst[wid][cnt + i] = make_uint2((unsigned)(ee >> 3),
                                       __float_as_uint(coefS * ewLds[wid][ee & 7]));
    }
    cnt += nm;

    float ox = 0.f, oy = 0.f, oz2 = 0.f, ow = 0.f;
    int i = 0;
    for (; i + 4 <= cnt; i += 4) {
        const uint2 e0 = lst[wid][i + 0];
        const uint2 e1 = lst[wid][i + 1];
        const uint2 e2 = lst[wid][i + 2];
        const uint2 e3 = lst[wid][i + 3];
        const float4 m0 = *(const float4*)(msgB + (size_t)e0.x * D_ + d4);
        const float4 m1 = *(const float4*)(msgB + (size_t)e1.x * D_ + d4);
        const float4 m2b = *(const float4*)(msgB + (size_t)e2.x * D_ + d4);
        const float4 m3 = *(const float4*)(msgB + (size_t)e3.x * D_ + d4);
        const float w0 = __uint_as_float(e0.y), w1 = __uint_as_float(e1.y);
        const float w2 = __uint_as_float(e2.y), w3 = __uint_as_float(e3.y);
        ox = fmaf(w0, m0.x, fmaf(w1, m1.x, fmaf(w2, m2b.x, fmaf(w3, m3.x, ox))));
        oy = fmaf(w0, m0.y, fmaf(w1, m1.y, fmaf(w2, m2b.y, fmaf(w3, m3.y, oy))));
        oz2 = fmaf(w0, m0.z, fmaf(w1, m1.z, fmaf(w2, m2b.z, fmaf(w3, m3.z, oz2))));
        ow = fmaf(w0, m0.w, fmaf(w1, m1.w, fmaf(w2, m2b.w, fmaf(w3, m3.w, ow))));
    }
    for (; i < cnt; ++i) {
        const uint2 e0 = lst[wid][i];
        const float w0 = __uint_as_float(e0.y);
        const float4 m0 = *(const float4*)(msgB + (size_t)e0.x * D_ + d4);
        ox = fmaf(w0, m0.x, ox); oy = fmaf(w0, m0.y, oy);
        oz2 = fmaf(w0, m0.z, oz2); ow = fmaf(w0, m0.w, ow);
    }

    int slot = -1;
    if (gDense || lDense) {
        int s0 = 0;
        if (lane == 0) s0 = atomicAdd(&qMeta[0], 1);
        slot = __shfl(s0, 0, 64);
    }
    if (slot >= 0 && slot < MAXQ_) {
#pragma unroll
        for (int qd = 0; qd < 4; ++qd) {
            float4 w4;
            float* wv4 = &w4.x;
#pragma unroll
            for (int u = 0; u < 4; ++u) {
                const int j = qd * 4 + u;
                float w = 0.f;
                if (gDense) w += coefG * fmaxf(zrG[j] - tauG, 0.f);
                if (lDense) w += coefL * fmaxf(zrL[j] - tauL, 0.f);
                wv4[u] = w;
            }
            *(float4*)(wq + (size_t)slot * SEQ_ + (lane << 4) + qd * 4) = w4;
        }
        if (lane == 0) qRows[slot] = row;
        *(float4*)(out + (size_t)row * D_ + d4) = make_float4(ox, oy, oz2, ow);
        return;
    }
    if (slot >= MAXQ_) {
#pragma unroll
        for (int j = 0; j < 16; ++j) {
            float wv = 0.f;
            if (gDense) wv += coefG * fmaxf(zrG[j] - tauG, 0.f);
            if (lDense) wv += coefL * fmaxf(zrL[j] - tauL, 0.f);
            unsigned long long m = __ballot(wv > 0.f);
            while (m) {
                const int s0 = __ffsll(m) - 1; m &= m - 1;
                const float w0 = __shfl(wv, s0, 64);
                const float4 m4 = *(const float4*)(msgB + (size_t)((s0 << 4) + j) * D_ + d4);
                ox = fmaf(w0, m4.x, ox); oy = fmaf(w0, m4.y, oy);
                oz2 = fmaf(w0, m4.z, oz2); ow = fmaf(w0, m4.w, ow);
            }
        }
    }

    float ssq = ox * ox + oy * oy + oz2 * oz2 + ow * ow;
    ssq = waveSum(ssq);
    const float nrm = fmaxf(sqrtf(ssq), 1e-12f);
    const float4 pr = *(const float4*)(wsProbe + (size_t)row * D_ + d4);
    float dp = (ox * pr.x + oy * pr.y + oz2 * pr.z + ow * pr.w) / nrm;
    dp = waveSum(dp);
    const float rel = 1.f / (1.f + expf(-dp));
    *(float4*)(out + (size_t)row * D_ + d4) =
        make_float4(ox * rel, oy * rel, oz2 * rel, ow * rel);
}

// Kernel C: drain dense-row queue.
__global__ __launch_bounds__(256) void cleanup_kernel(
    const float* __restrict__ messages,
    const float* __restrict__ wsProbe,
    const float* __restrict__ wq,
    const int* __restrict__ qRows,
    int* __restrict__ qMeta,
    float* __restrict__ out)
{
    __shared__ float wsh[SEQ_];
    __shared__ float scr[4];
    __shared__ int idxSh;
    const int tid = threadIdx.x;
    const int nq = (qMeta[0] < MAXQ_) ? qMeta[0] : MAXQ_;
    for (;;) {
        __syncthreads();
        if (tid == 0) idxSh = atomicAdd(&qMeta[1], 1);
        __syncthreads();
        const int idx = idxSh;
        if (idx >= nq) break;
        const int row = qRows[idx];
        const int b = row >> 10;
        const float* msgB = messages + (size_t)b * SEQ_ * D_;
        for (int i = tid; i < SEQ_; i += 256)
            wsh[i] = wq[(size_t)idx * SEQ_ + i];
        __syncthreads();
        float acc = out[(size_t)row * D_ + tid];
        for (int t = 0; t < SEQ_; t += 4) {
            acc = fmaf(wsh[t + 0], msgB[(size_t)(t + 0) * D_ + tid],
                  fmaf(wsh[t + 1], msgB[(size_t)(t + 1) * D_ + tid],
                  fmaf(wsh[t + 2], msgB[(size_t)(t + 2) * D_ + tid],
                  fmaf(wsh[t + 3], msgB[(size_t)(t + 3) * D_ + tid], acc))));
        }
        const float ssq = blockSum(acc * acc, scr);
        const float nrm = fmaxf(sqrtf(ssq), 1e-12f);
        const float dp = blockSum((acc / nrm) * wsProbe[(size_t)row * D_ + tid], scr);
        const float rel = 1.f / (1.f + expf(-dp));
        out[(size_t)row * D_ + tid] = acc * rel;
    }
}

extern "C" void kernel_launch(void* const* d_in, const int* in_sizes, int n_in,
                              void* d_out, int out_size, void* d_ws, size_t ws_size,
                              hipStream_t stream) {
    const float* messages  = (const float*)d_in[0];
    const float* hidden    = (const float*)d_in[1];
    const int*   x_ids     = (const int*)d_in[2];
    const float* scn       = (const float*)d_in[3];
    const void*  mask      = d_in[4];
    const int*   static_nb = (const int*)d_in[5];
    const float* gvel      = (const float*)d_in[6];
    const float* ctx       = (const float*)d_in[7];
    const float* ent       = (const float*)d_in[8];
    const float* W_vel     = (const float*)d_in[9];
    const float* W_e1      = (const float*)d_in[10];
    const float* b_e1      = (const float*)d_in[11];
    const float* W_e2      = (const float*)d_in[12];
    const float* b_e2      = (const float*)d_in[13];
    const float* W_probe   = (const float*)d_in[14];
    const float* W_gate    = (const float*)d_in[15];
    const float* b_gate    = (const float*)d_in[16];
    float* out = (float*)d_out;
    (void)in_sizes; (void)n_in; (void)out_size; (void)ws_size;

    char* ws = (char*)d_ws;
    size_t o = 0;
    int* flag      = (int*)(ws + o);   o += 256;
    short* wsAh    = (short*)(ws + o); o += (size_t)B_ * SEQ_ * KA_ * 2;   // 3.1 MB
    short* wsAl    = (short*)(ws + o); o += (size_t)B_ * SEQ_ * KA_ * 2;
    float* wsProbe = (float*)(ws + o); o += (size_t)B_ * SEQ_ * D_ * 4;
    int* wsMode    = (int*)(ws + o);   o += (size_t)B_ * SEQ_ * 4;
    float* wsGw    = (float*)(ws + o); o += (size_t)B_ * SEQ_ * 4;
    short* msgH    = (short*)(ws + o); o += (size_t)B_ * SEQ_ * D_ * 2;    // 2 MB
    short* msgL    = (short*)(ws + o); o += (size_t)B_ * SEQ_ * D_ * 2;    // 2 MB
    short* scnH    = (short*)(ws + o); o += (size_t)B_ * SEQ_ * NS_ * 2;
    short* scnL    = (short*)(ws + o); o += (size_t)B_ * SEQ_ * NS_ * 2;
    float* zgW     = (float*)(ws + o); o += (size_t)B_ * SEQ_ * SEQ_ * 4;
    float* zlW     = (float*)(ws + o); o += (size_t)B_ * SEQ_ * SEQ_ * 4;
    int* qMeta     = (int*)(ws + o);   o += 256;
    int* qRows     = (int*)(ws + o);   o += (size_t)MAXQ_ * 4;
    // dense-weight buffer overlays msgH+msgL (dead after sims): 4 MB
    float* wq      = (float*)msgH;

    setup_kernel<<<dim3(833), dim3(256), 0, stream>>>(
        messages, scn, hidden, gvel, ctx, ent, W_probe, W_vel, W_gate, b_gate,
        msgH, msgL, scnH, scnL, (const unsigned int*)mask, flag, qMeta,
        wsAh, wsAl, wsProbe, wsMode, wsGw);
    sims_kernel<<<dim3(256), dim3(512), 0, stream>>>(
        msgH, msgL, scnH, scnL, wsAh, wsAl, wsMode, mask, flag, zgW, zlW);
    route4_kernel<<<dim3(B_ * SEQ_ / 4), dim3(256), 0, stream>>>(
        messages, scn, x_ids, static_nb, W_e1, b_e1, W_e2, b_e2,
        wsProbe, wsGw, zgW, zlW, wq, qRows, qMeta, out);
    cleanup_kernel<<<dim3(64), dim3(256), 0, stream>>>(
        messages, wsProbe, wq, qRows, qMeta, out);
}

// Round 13
// 138.657 us; speedup vs baseline: 1.7758x; 1.0501x over previous
//
#include <hip/hip_runtime.h>
#include <math.h>

#define D_ 256
#define NS_ 64
#define KNB_ 8
#define SEQ_ 1024
#define B_ 4
#define MAXQ_ 1024
#define KA_ 384            // prescaled A row: [e'(64) | s'(64) | h'(256)]
#define NEG_ (-10000.0f)
#define BLKNEG_ (-50000.0f)

typedef short bf16x8 __attribute__((ext_vector_type(8)));
typedef float f32x4 __attribute__((ext_vector_type(4)));

__device__ __forceinline__ float waveSum(float v) {
#pragma unroll
    for (int off = 32; off; off >>= 1) v += __shfl_xor(v, off, 64);
    return v;
}

__device__ __forceinline__ void waveSum2(float& a, float& b) {
#pragma unroll
    for (int off = 32; off; off >>= 1) {
        a += __shfl_xor(a, off, 64);
        b += __shfl_xor(b, off, 64);
    }
}

__device__ __forceinline__ float blockSum(float v, float* scr) {
    const int tid = threadIdx.x;
    const int wid = tid >> 6, lane = tid & 63;
    v = waveSum(v);
    __syncthreads();
    if (lane == 0) scr[wid] = v;
    __syncthreads();
    return scr[0] + scr[1] + scr[2] + scr[3];
}

__device__ __forceinline__ void blockSum4(float v[4], float (*scr4)[4]) {
    const int tid = threadIdx.x;
    const int wid = tid >> 6, lane = tid & 63;
#pragma unroll
    for (int off = 32; off; off >>= 1) {
#pragma unroll
        for (int q = 0; q < 4; ++q) v[q] += __shfl_xor(v[q], off, 64);
    }
    __syncthreads();
    if (lane == 0) {
#pragma unroll
        for (int q = 0; q < 4; ++q) scr4[wid][q] = v[q];
    }
    __syncthreads();
#pragma unroll
    for (int q = 0; q < 4; ++q)
        v[q] = scr4[0][q] + scr4[1][q] + scr4[2][q] + scr4[3][q];
}

// exact sparsemax tau via support iteration (monotone, fixpoint = exact tau)
__device__ __forceinline__ float sparsemaxTauWave(const float* zr) {
    float mx = zr[0];
#pragma unroll
    for (int i = 1; i < 16; ++i) mx = fmaxf(mx, zr[i]);
#pragma unroll
    for (int off = 32; off; off >>= 1) mx = fmaxf(mx, __shfl_xor(mx, off, 64));
    float tau = mx - 1.0f;
    for (int it = 0; it < 32; ++it) {
        float ssum = 0.f, cnt = 0.f;
#pragma unroll
        for (int i = 0; i < 16; ++i) {
            if (zr[i] > tau) { ssum += zr[i]; cnt += 1.f; }
        }
        waveSum2(ssum, cnt);
        if (cnt < 0.5f) break;
        const float nt = (ssum - 1.0f) / cnt;
        if (nt == tau) break;
        tau = nt;
    }
    return tau;
}

// split fp32 -> bf16 hi + bf16 lo (truncation; a ~= hi + lo, err ~2^-16 rel)
__device__ __forceinline__ void cvtSplit(float a, short& h, short& l) {
    const unsigned ab = __float_as_uint(a);
    h = (short)(ab >> 16);
    const float hf = __uint_as_float(ab & 0xFFFF0000u);
    l = (short)(__float_as_uint(a - hf) >> 16);
}

// Fused setup: bf16-split conversions + mask detect + per-row prep.
// blocks [0,256): messages -> msgH/msgL; [256,320): scn -> scnH/scnL;
// 320: mask detect + counter zero; [321,833): prep (8 rows each).
__global__ __launch_bounds__(256) void setup_kernel(
    const float* __restrict__ messages, const float* __restrict__ scn,
    const float* __restrict__ hidden, const float* __restrict__ gvel,
    const float* __restrict__ ctx, const float* __restrict__ ent,
    const float* __restrict__ W_probe, const float* __restrict__ W_vel,
    const float* __restrict__ W_gate, const float* __restrict__ b_gate,
    short* __restrict__ msgH, short* __restrict__ msgL,
    short* __restrict__ scnH, short* __restrict__ scnL,
    const unsigned int* __restrict__ maskW, int* __restrict__ flag,
    int* __restrict__ qMeta,
    short* __restrict__ wsAh, short* __restrict__ wsAl,
    float* __restrict__ wsProbe,
    int* __restrict__ wsMode, float* __restrict__ wsGw)
{
    const int bid = blockIdx.x;
    const int tid = threadIdx.x;

    if (bid < 320) {   // conversions
        const float* src; short* dh; short* dl; size_t base;
        if (bid < 256) { src = messages; dh = msgH; dl = msgL; base = (size_t)bid * 4096 + tid * 4; }
        else           { src = scn; dh = scnH; dl = scnL; base = (size_t)(bid - 256) * 4096 + tid * 4; }
#pragma unroll
        for (int i = 0; i < 4; ++i) {
            const size_t o = base + (size_t)i * 1024;
            const float4 v = *(const float4*)(src + o);
            short4 h4, l4;
            cvtSplit(v.x, h4.x, l4.x);
            cvtSplit(v.y, h4.y, l4.y);
            cvtSplit(v.z, h4.z, l4.z);
            cvtSplit(v.w, h4.w, l4.w);
            *(short4*)(dh + o) = h4;
            *(short4*)(dl + o) = l4;
        }
        return;
    }

    if (bid == 320) {
        __shared__ int notI, notF;
        if (tid == 0) { notI = 0; notF = 0; qMeta[0] = 0; qMeta[1] = 0; }
        __syncthreads();
        int ni = 0, nf = 0;
        for (int i = tid; i < 1024; i += 256) {
            const unsigned int w = maskW[i];
            if (w != 0u && w != 1u) ni = 1;
            if (w != 0u && w != 0x3f800000u) nf = 1;
        }
        if (ni) atomicOr(&notI, 1);
        if (nf) atomicOr(&notF, 1);
        __syncthreads();
        if (tid == 0) *flag = (!notI) ? 0 : ((!notF) ? 2 : 1);
        return;
    }

    // ---- prep: 8 rows per block ----
    __shared__ float scr4[4][4];
    const int rowBase = (bid - 321) << 3;
    const int wid = tid >> 6, lane = tid & 63;
    const float* h0 = hidden + (size_t)rowBase * D_;

    float vh[8] = {};
    for (int e = 0; e < NS_; e += 4) {
        const float4 wv4 = *(const float4*)(W_vel + (size_t)tid * NS_ + e);  // thread-own row
#pragma unroll
        for (int r = 0; r < 8; ++r) {
            const float4 g4 = *(const float4*)(gvel + (size_t)(rowBase + r) * NS_ + e); // uniform
            vh[r] = fmaf(g4.x, wv4.x, fmaf(g4.y, wv4.y, fmaf(g4.z, wv4.z, fmaf(g4.w, wv4.w, vh[r]))));
        }
    }
    float pr[8] = {};
    for (int e = 0; e < D_; e += 4) {
        const float4 wp4 = *(const float4*)(W_probe + (size_t)tid * D_ + e);  // thread-own row
#pragma unroll
        for (int r = 0; r < 8; ++r) {
            const float4 h4 = *(const float4*)(h0 + (size_t)r * D_ + e);      // uniform
            pr[r] = fmaf(h4.x, wp4.x, fmaf(h4.y, wp4.y, fmaf(h4.z, wp4.z, fmaf(h4.w, wp4.w, pr[r]))));
        }
    }

    // per-wave: wave w handles rows 2w, 2w+1 (endpoint, s', argmax, gate)
#pragma unroll
    for (int rr = 0; rr < 2; ++rr) {
        const int r = (wid << 1) + rr, row = rowBase + r;
        const float sv = scn[(size_t)row * NS_ + lane];
        const float gv = gvel[(size_t)row * NS_ + lane];
        const float Hn = ent[row] / 10.373491191781864f;   // log(32000)+1e-8
        const float e = sv + 0.4f * gv;
        const float ss = waveSum(e * e);
        short hh, ll;
        cvtSplit((e / fmaxf(sqrtf(ss), 1e-12f)) * 5.0f * Hn, hh, ll);
        wsAh[(size_t)row * KA_ + lane] = hh;
        wsAl[(size_t)row * KA_ + lane] = ll;
        cvtSplit(5.0f * sv, hh, ll);
        wsAh[(size_t)row * KA_ + 64 + lane] = hh;
        wsAl[(size_t)row * KA_ + 64 + lane] = ll;
        float v = sv; int idx = lane;
#pragma unroll
        for (int off = 1; off < 64; off <<= 1) {
            const float ov = __shfl_xor(v, off, 64);
            const int   oi = __shfl_xor(idx, off, 64);
            if (ov > v || (ov == v && oi < idx)) { v = ov; idx = oi; }
        }
        float gd = 0.f;
#pragma unroll
        for (int j = 0; j < 4; ++j) {
            const int d = lane + (j << 6);
            gd = fmaf(h0[(size_t)r * D_ + d], W_gate[d], gd);
        }
        gd = waveSum(gd);
        if (lane == 0) {
            wsMode[row] = idx;
            const float raw = 1.f / (1.f + expf(-(gd + b_gate[0])));
            wsGw[row] = raw * ctx[row];
        }
    }

    // block-wide norms, 4 rows per batched reduction
#pragma unroll
    for (int g = 0; g < 2; ++g) {
        float ha4[4], va[4], vp[4];
#pragma unroll
        for (int q = 0; q < 4; ++q) {
            const int r = (g << 2) + q;
            ha4[q] = h0[(size_t)r * D_ + tid] + 0.3f * vh[r];
            va[q] = ha4[q] * ha4[q];
            vp[q] = pr[(g << 2) + q] * pr[(g << 2) + q];
        }
        blockSum4(va, scr4);
        blockSum4(vp, scr4);
#pragma unroll
        for (int q = 0; q < 4; ++q) {
            const int r = (g << 2) + q;
            short hh, ll;
            cvtSplit((ha4[q] / fmaxf(sqrtf(va[q]), 1e-12f)) * 2.5f, hh, ll);
            wsAh[(size_t)(rowBase + r) * KA_ + 128 + tid] = hh;
            wsAl[(size_t)(rowBase + r) * KA_ + 128 + tid] = ll;
            wsProbe[(size_t)(rowBase + r) * D_ + tid] = pr[r] / fmaxf(sqrtf(vp[q]), 1e-12f);
        }
    }
}

// Kernel A: all-pairs sims via split-bf16 MFMA (3-pass: hh + hl + lh).
// 512 blocks = b(4) x rowgroup(64) x colhalf(2); 8 waves x 4 col-tiles each
// -> 2 blocks/CU, 16 waves/CU.  scn k-steps feed zg AND zl from one B load.
// zl written RAW (BLKNEG / sim / 0); route4 derives hasNb from zl itself.
__global__ __launch_bounds__(512) void sims_kernel(
    const short* __restrict__ msgH, const short* __restrict__ msgL,   // [B][S][D]
    const short* __restrict__ scnH, const short* __restrict__ scnL,   // [B][S][NS]
    const short* __restrict__ wsAh, const short* __restrict__ wsAl,   // [4096][KA_]
    const int* __restrict__ wsMode,
    const void* __restrict__ maskP,
    const int* __restrict__ maskFlag,
    float* __restrict__ zgO,            // [4096][1024]
    float* __restrict__ zlO)            // [4096][1024]
{
    const int bid = blockIdx.x;          // 512 blocks
    const int half = bid & 1;
    const int sg = (bid >> 1) & 63;
    const int b = bid >> 7;
    const int sBase = sg << 4;           // 16 rows
    const int rowBase = (b << 10) + sBase;
    const int tid = threadIdx.x;
    const int w = tid >> 6, l = tid & 63;
    const int m16 = l & 15, kq = l >> 4;
    const int kq8 = kq << 3;

    const short* mHb = msgH + (size_t)b * SEQ_ * D_;
    const short* mLb = msgL + (size_t)b * SEQ_ * D_;
    const short* sHb = scnH + (size_t)b * SEQ_ * NS_;
    const short* sLb = scnL + (size_t)b * SEQ_ * NS_;
    const short* Ah = wsAh + (size_t)(rowBase + m16) * KA_;
    const short* Al = wsAl + (size_t)(rowBase + m16) * KA_;
    const int tBase = (half << 9) + (w << 6);   // this wave's 4 col-tiles start

    f32x4 accG[4], accL8[4];
#pragma unroll
    for (int ct = 0; ct < 4; ++ct) {
        accG[ct] = (f32x4){0.f, 0.f, 0.f, 0.f};
        accL8[ct] = (f32x4){0.f, 0.f, 0.f, 0.f};
    }

    // ---- scn k-steps (2): e' -> accG, s' -> accL, shared B loads ----
#pragma unroll
    for (int st = 0; st < 2; ++st) {
        const int ko = (st << 5) + kq8;
        const bf16x8 aeh = *(const bf16x8*)(Ah + ko);
        const bf16x8 ael = *(const bf16x8*)(Al + ko);
        const bf16x8 ash = *(const bf16x8*)(Ah + 64 + ko);
        const bf16x8 asl = *(const bf16x8*)(Al + 64 + ko);
#pragma unroll
        for (int ct = 0; ct < 4; ++ct) {
            const int t = tBase + (ct << 4) + m16;
            const bf16x8 bh = *(const bf16x8*)(sHb + (size_t)t * NS_ + ko);
            const bf16x8 bl = *(const bf16x8*)(sLb + (size_t)t * NS_ + ko);
            accG[ct] = __builtin_amdgcn_mfma_f32_16x16x32_bf16(aeh, bh, accG[ct], 0, 0, 0);
            accG[ct] = __builtin_amdgcn_mfma_f32_16x16x32_bf16(aeh, bl, accG[ct], 0, 0, 0);
            accG[ct] = __builtin_amdgcn_mfma_f32_16x16x32_bf16(ael, bh, accG[ct], 0, 0, 0);
            accL8[ct] = __builtin_amdgcn_mfma_f32_16x16x32_bf16(ash, bh, accL8[ct], 0, 0, 0);
            accL8[ct] = __builtin_amdgcn_mfma_f32_16x16x32_bf16(ash, bl, accL8[ct], 0, 0, 0);
            accL8[ct] = __builtin_amdgcn_mfma_f32_16x16x32_bf16(asl, bh, accL8[ct], 0, 0, 0);
        }
    }
    // ---- msg k-steps (8): h' -> accG ----
#pragma unroll
    for (int st = 0; st < 8; ++st) {
        const int koA = 128 + (st << 5) + kq8;
        const int koB = (st << 5) + kq8;
        const bf16x8 ah = *(const bf16x8*)(Ah + koA);
        const bf16x8 al = *(const bf16x8*)(Al + koA);
#pragma unroll
        for (int ct = 0; ct < 4; ++ct) {
            const int t = tBase + (ct << 4) + m16;
            const bf16x8 bh = *(const bf16x8*)(mHb + (size_t)t * D_ + koB);
            const bf16x8 bl = *(const bf16x8*)(mLb + (size_t)t * D_ + koB);
            accG[ct] = __builtin_amdgcn_mfma_f32_16x16x32_bf16(ah, bh, accG[ct], 0, 0, 0);
            accG[ct] = __builtin_amdgcn_mfma_f32_16x16x32_bf16(ah, bl, accG[ct], 0, 0, 0);
            accG[ct] = __builtin_amdgcn_mfma_f32_16x16x32_bf16(al, bh, accG[ct], 0, 0, 0);
        }
    }

    // ---- tail: mask + mode; write zg + raw zl ----
    const int mf = *maskFlag;
    const int4 mS4 = *(const int4*)(wsMode + rowBase + (kq << 2));   // this lane's 4 rows
    const int mSq[4] = {mS4.x, mS4.y, mS4.z, mS4.w};
#pragma unroll
    for (int ct = 0; ct < 4; ++ct) {
        const int t = tBase + (ct << 4) + m16;
        const int mdt = wsMode[(b << 10) + t];
#pragma unroll
        for (int q = 0; q < 4; ++q) {
            const int r = (kq << 2) + q;
            const int s_r = sBase + r;
            const size_t mb = (size_t)s_r * SEQ_ + t;
            int blk;
            if (mf == 1)      blk = ((const unsigned char*)maskP)[mb] != 0;
            else if (mf == 2) blk = ((const float*)maskP)[mb] != 0.f;
            else              blk = ((const int*)maskP)[mb] != 0;
            if (s_r == t) blk = 1;
            zgO[(size_t)(rowBase + r) * SEQ_ + t] = blk ? NEG_ : accG[ct][q];
            const int sm = (!blk) && (mdt == mSq[q]);
            zlO[(size_t)(rowBase + r) * SEQ_ + t] =
                blk ? BLKNEG_ : (sm ? accL8[ct][q] : 0.0f);
        }
    }
}

// Kernel B: 4 waves per block, wave owns one row (mirror-balanced).
// hasNb derived in-row from raw zl (round-7 protocol, no cross-kernel mask).
// Sparse combined gather; dense-support rows deferred to cleanup via queue.
__global__ __launch_bounds__(256) void route4_kernel(
    const float* __restrict__ messages,
    const float* __restrict__ scn,
    const int* __restrict__ x_ids,
    const int* __restrict__ static_nb,
    const float* __restrict__ W_e1,
    const float* __restrict__ b_e1,
    const float* __restrict__ W_e2,
    const float* __restrict__ b_e2,
    const float* __restrict__ wsProbe,
    const float* __restrict__ wsGw,
    const float* __restrict__ zgA,
    const float* __restrict__ zlA,
    float* __restrict__ wq,          // [MAXQ][1024] dense weights
    int* __restrict__ qRows,
    int* __restrict__ qMeta,         // [0]=tail, [1]=consume
    float* __restrict__ out)
{
    __shared__ uint2 lst[4][256];
    __shared__ float ewLds[4][8];
    __shared__ int   mlist[4][64];

    const int jb = blockIdx.x;               // 0..1023
    const int tid = threadIdx.x;
    const int wid = tid >> 6, lane = tid & 63;
    const int base = jb << 1;
    const int row = (wid == 0) ? base
                  : (wid == 1) ? base + 1
                  : (wid == 2) ? 4094 - base
                               : 4095 - base;
    const int b = row >> 10, s_r = row & 1023;
    const float* msgB = messages + (size_t)b * SEQ_ * D_;
    const float* scnB = scn + (size_t)b * SEQ_ * NS_;
    const unsigned long long ltmask = (1ull << lane) - 1ull;
    const int d4 = lane << 2;

    float zrG[16], zrL[16];
    {
        const float4* zgp = (const float4*)(zgA + (size_t)row * SEQ_ + (lane << 4));
        const float4* zlp = (const float4*)(zlA + (size_t)row * SEQ_ + (lane << 4));
#pragma unroll
        for (int q = 0; q < 4; ++q) {
            const float4 g4 = zgp[q];
            zrG[q * 4 + 0] = g4.x; zrG[q * 4 + 1] = g4.y;
            zrG[q * 4 + 2] = g4.z; zrG[q * 4 + 3] = g4.w;
            const float4 l4 = zlp[q];
            zrL[q * 4 + 0] = l4.x; zrL[q * 4 + 1] = l4.y;
            zrL[q * 4 + 2] = l4.z; zrL[q * 4 + 3] = l4.w;
        }
    }

    // ----- static neighbor-vocab scan: ONE ballot per 64-block (kmask) -----
    const int q = x_ids[row];
    int nb[KNB_];
#pragma unroll
    for (int k = 0; k < KNB_; ++k) nb[k] = static_nb[(size_t)q * KNB_ + k];
    const float ss_l = scnB[(size_t)s_r * NS_ + lane];
    float simk[KNB_] = {};
    unsigned matchedMask = 0;
    int mcW = 0;
    const int* xb = x_ids + (b << 10);
    for (int pb = 0; pb <= s_r; pb += 64) {
        const int p = pb + lane;
        const int id = (p <= s_r) ? xb[p] : -2147483647;
        unsigned kmask = 0;
#pragma unroll
        for (int k = 0; k < KNB_; ++k) kmask |= (id == nb[k]) ? (1u << k) : 0u;
        unsigned long long mb = __ballot(kmask != 0u);
        while (mb) {
            const int src = __ffsll(mb) - 1; mb &= mb - 1;
            const unsigned kms = (unsigned)__shfl((int)kmask, src, 64);
            const int pp = pb + src;
            float pv = scnB[(size_t)pp * NS_ + lane] * ss_l;
            pv = waveSum(pv);
            matchedMask |= kms;
#pragma unroll
            for (int k = 0; k < KNB_; ++k) {
                if ((kms >> k) & 1u) {
                    simk[k] += pv;
                    if (mcW < 64) { if (lane == 0) mlist[wid][mcW] = (pp << 3) | k; ++mcW; }
                }
            }
        }
    }
    const int kk = lane >> 3, jjn = lane & 7;
    float sv = simk[0];
#pragma unroll
    for (int k = 1; k < KNB_; ++k) sv = (kk == k) ? simk[k] : sv;
    const float xx = sv * W_e1[jjn] + b_e1[jjn];
    float eo = 0.5f * xx * (1.f + erff(xx * 0.70710678118654752f)) * W_e2[jjn];
    eo += __shfl_xor(eo, 1, 64); eo += __shfl_xor(eo, 2, 64); eo += __shfl_xor(eo, 4, 64);
    eo += b_e2[0];
    float m2 = eo;
    m2 = fmaxf(m2, __shfl_xor(m2, 8, 64));
    m2 = fmaxf(m2, __shfl_xor(m2, 16, 64));
    m2 = fmaxf(m2, __shfl_xor(m2, 32, 64));
    const float exv = expf(eo - m2);
    float smv = exv;
    smv += __shfl_xor(smv, 8, 64); smv += __shfl_xor(smv, 16, 64); smv += __shfl_xor(smv, 32, 64);
    if ((lane & 7) == 0) ewLds[wid][kk] = exv / smv;

    const float cov = (float)__popc(matchedMask) * 0.125f;
    const float gw = wsGw[row];
    const float coefG = gw;
    const float coefL = (1.f - gw) * (1.f - cov);
    const float coefS = (1.f - gw) * cov;

    // ----- local hasNb derived from raw zl (non-same-mode entries are 0.0f) -----
    int fl = 0;
#pragma unroll
    for (int j = 0; j < 16; ++j) fl |= (zrL[j] != 0.0f && zrL[j] > -40000.f);
    const int hasNb = __any(fl);
    if (!hasNb) {
#pragma unroll
        for (int j = 0; j < 16; ++j) {
            const int t = (lane << 4) + j;
            zrL[j] = (zrL[j] <= -40000.f) ? BLKNEG_ : -0.05f * fabsf((float)(s_r - t));
        }
    }

    const float tauG = sparsemaxTauWave(zrG);
    int supG = 0;
#pragma unroll
    for (int j = 0; j < 16; ++j) supG += __popcll(__ballot(zrG[j] > tauG));
    const float tauL = sparsemaxTauWave(zrL);
    int supL = 0;
#pragma unroll
    for (int j = 0; j < 16; ++j) supL += __popcll(__ballot(zrL[j] > tauL));
    const bool gDense = supG > 96;
    const bool lDense = supL > 96;

    int cnt = 0;
    if (!gDense) {
#pragma unroll
        for (int j = 0; j < 16; ++j) {
            const float wv = zrG[j] - tauG;
            const bool take = wv > 0.f;
            const unsigned long long m = __ballot(take);
            if (take) {
                const int pos = cnt + __popcll(m & ltmask);
                lst[wid][pos] = make_uint2((unsigned)((lane << 4) + j),
                                           __float_as_uint(coefG * wv));
            }
            cnt += __popcll(m);
        }
    }
    if (!lDense) {
#pragma unroll
        for (int j = 0; j < 16; ++j) {
            const float wv = zrL[j] - tauL;
            const bool take = wv > 0.f;
            const unsigned long long m = __ballot(take);
            if (take) {
                const int pos = cnt + __popcll(m & ltmask);
                lst[wid][pos] = make_uint2((unsigned)((lane << 4) + j),
                                           __float_as_uint(coefL * wv));
            }
            cnt += __popcll(m);
        }
    }
    const int nm = (mcW < 64) ? mcW : 64;
    for (int i = lane; i < nm; i += 64) {
        const int ee = mlist[wid][i];
        lst[wid][cnt + i] = make_uint2((unsigned)(ee >> 3),
                                       __float_as_uint(coefS * ewLds[wid][ee & 7]));
    }
    cnt += nm;

    float ox = 0.f, oy = 0.f, oz2 = 0.f, ow = 0.f;
    int i = 0;
    for (; i + 4 <= cnt; i += 4) {
        const uint2 e0 = lst[wid][i + 0];
        const uint2 e1 = lst[wid][i + 1];
        const uint2 e2 = lst[wid][i + 2];
        const uint2 e3 = lst[wid][i + 3];
        const float4 m0 = *(const float4*)(msgB + (size_t)e0.x * D_ + d4);
        const float4 m1 = *(const float4*)(msgB + (size_t)e1.x * D_ + d4);
        const float4 m2b = *(const float4*)(msgB + (size_t)e2.x * D_ + d4);
        const float4 m3 = *(const float4*)(msgB + (size_t)e3.x * D_ + d4);
        const float w0 = __uint_as_float(e0.y), w1 = __uint_as_float(e1.y);
        const float w2 = __uint_as_float(e2.y), w3 = __uint_as_float(e3.y);
        ox = fmaf(w0, m0.x, fmaf(w1, m1.x, fmaf(w2, m2b.x, fmaf(w3, m3.x, ox))));
        oy = fmaf(w0, m0.y, fmaf(w1, m1.y, fmaf(w2, m2b.y, fmaf(w3, m3.y, oy))));
        oz2 = fmaf(w0, m0.z, fmaf(w1, m1.z, fmaf(w2, m2b.z, fmaf(w3, m3.z, oz2))));
        ow = fmaf(w0, m0.w, fmaf(w1, m1.w, fmaf(w2, m2b.w, fmaf(w3, m3.w, ow))));
    }
    for (; i < cnt; ++i) {
        const uint2 e0 = lst[wid][i];
        const float w0 = __uint_as_float(e0.y);
        const float4 m0 = *(const float4*)(msgB + (size_t)e0.x * D_ + d4);
        ox = fmaf(w0, m0.x, ox); oy = fmaf(w0, m0.y, oy);
        oz2 = fmaf(w0, m0.z, oz2); ow = fmaf(w0, m0.w, ow);
    }

    int slot = -1;
    if (gDense || lDense) {
        int s0 = 0;
        if (lane == 0) s0 = atomicAdd(&qMeta[0], 1);
        slot = __shfl(s0, 0, 64);
    }
    if (slot >= 0 && slot < MAXQ_) {
#pragma unroll
        for (int qd = 0; qd < 4; ++qd) {
            float4 w4;
            float* wv4 = &w4.x;
#pragma unroll
            for (int u = 0; u < 4; ++u) {
                const int j = qd * 4 + u;
                float w = 0.f;
                if (gDense) w += coefG * fmaxf(zrG[j] - tauG, 0.f);
                if (lDense) w += coefL * fmaxf(zrL[j] - tauL, 0.f);
                wv4[u] = w;
            }
            *(float4*)(wq + (size_t)slot * SEQ_ + (lane << 4) + qd * 4) = w4;
        }
        if (lane == 0) qRows[slot] = row;
        *(float4*)(out + (size_t)row * D_ + d4) = make_float4(ox, oy, oz2, ow);
        return;
    }
    if (slot >= MAXQ_) {
#pragma unroll
        for (int j = 0; j < 16; ++j) {
            float wv = 0.f;
            if (gDense) wv += coefG * fmaxf(zrG[j] - tauG, 0.f);
            if (lDense) wv += coefL * fmaxf(zrL[j] - tauL, 0.f);
            unsigned long long m = __ballot(wv > 0.f);
            while (m) {
                const int s0 = __ffsll(m) - 1; m &= m - 1;
                const float w0 = __shfl(wv, s0, 64);
                const float4 m4 = *(const float4*)(msgB + (size_t)((s0 << 4) + j) * D_ + d4);
                ox = fmaf(w0, m4.x, ox); oy = fmaf(w0, m4.y, oy);
                oz2 = fmaf(w0, m4.z, oz2); ow = fmaf(w0, m4.w, ow);
            }
        }
    }

    float ssq = ox * ox + oy * oy + oz2 * oz2 + ow * ow;
    ssq = waveSum(ssq);
    const float nrm = fmaxf(sqrtf(ssq), 1e-12f);
    const float4 pr = *(const float4*)(wsProbe + (size_t)row * D_ + d4);
    float dp = (ox * pr.x + oy * pr.y + oz2 * pr.z + ow * pr.w) / nrm;
    dp = waveSum(dp);
    const float rel = 1.f / (1.f + expf(-dp));
    *(float4*)(out + (size_t)row * D_ + d4) =
        make_float4(ox * rel, oy * rel, oz2 * rel, ow * rel);
}

// Kernel C: drain dense-row queue.
__global__ __launch_bounds__(256) void cleanup_kernel(
    const float* __restrict__ messages,
    const float* __restrict__ wsProbe,
    const float* __restrict__ wq,
    const int* __restrict__ qRows,
    int* __restrict__ qMeta,
    float* __restrict__ out)
{
    __shared__ float wsh[SEQ_];
    __shared__ float scr[4];
    __shared__ int idxSh;
    const int tid = threadIdx.x;
    const int nq = (qMeta[0] < MAXQ_) ? qMeta[0] : MAXQ_;
    for (;;) {
        __syncthreads();
        if (tid == 0) idxSh = atomicAdd(&qMeta[1], 1);
        __syncthreads();
        const int idx = idxSh;
        if (idx >= nq) break;
        const int row = qRows[idx];
        const int b = row >> 10;
        const float* msgB = messages + (size_t)b * SEQ_ * D_;
        for (int i = tid; i < SEQ_; i += 256)
            wsh[i] = wq[(size_t)idx * SEQ_ + i];
        __syncthreads();
        float acc = out[(size_t)row * D_ + tid];
        for (int t = 0; t < SEQ_; t += 4) {
            acc = fmaf(wsh[t + 0], msgB[(size_t)(t + 0) * D_ + tid],
                  fmaf(wsh[t + 1], msgB[(size_t)(t + 1) * D_ + tid],
                  fmaf(wsh[t + 2], msgB[(size_t)(t + 2) * D_ + tid],
                  fmaf(wsh[t + 3], msgB[(size_t)(t + 3) * D_ + tid], acc))));
        }
        const float ssq = blockSum(acc * acc, scr);
        const float nrm = fmaxf(sqrtf(ssq), 1e-12f);
        const float dp = blockSum((acc / nrm) * wsProbe[(size_t)row * D_ + tid], scr);
        const float rel = 1.f / (1.f + expf(-dp));
        out[(size_t)row * D_ + tid] = acc * rel;
    }
}

extern "C" void kernel_launch(void* const* d_in, const int* in_sizes, int n_in,
                              void* d_out, int out_size, void* d_ws, size_t ws_size,
                              hipStream_t stream) {
    const float* messages  = (const float*)d_in[0];
    const float* hidden    = (const float*)d_in[1];
    const int*   x_ids     = (const int*)d_in[2];
    const float* scn       = (const float*)d_in[3];
    const void*  mask      = d_in[4];
    const int*   static_nb = (const int*)d_in[5];
    const float* gvel      = (const float*)d_in[6];
    const float* ctx       = (const float*)d_in[7];
    const float* ent       = (const float*)d_in[8];
    const float* W_vel     = (const float*)d_in[9];
    const float* W_e1      = (const float*)d_in[10];
    const float* b_e1      = (const float*)d_in[11];
    const float* W_e2      = (const float*)d_in[12];
    const float* b_e2      = (const float*)d_in[13];
    const float* W_probe   = (const float*)d_in[14];
    const float* W_gate    = (const float*)d_in[15];
    const float* b_gate    = (const float*)d_in[16];
    float* out = (float*)d_out;
    (void)in_sizes; (void)n_in; (void)out_size; (void)ws_size;

    char* ws = (char*)d_ws;
    size_t o = 0;
    int* flag      = (int*)(ws + o);   o += 256;
    short* wsAh    = (short*)(ws + o); o += (size_t)B_ * SEQ_ * KA_ * 2;   // 3.1 MB
    short* wsAl    = (short*)(ws + o); o += (size_t)B_ * SEQ_ * KA_ * 2;
    float* wsProbe = (float*)(ws + o); o += (size_t)B_ * SEQ_ * D_ * 4;
    int* wsMode    = (int*)(ws + o);   o += (size_t)B_ * SEQ_ * 4;
    float* wsGw    = (float*)(ws + o); o += (size_t)B_ * SEQ_ * 4;
    short* msgH    = (short*)(ws + o); o += (size_t)B_ * SEQ_ * D_ * 2;    // 2 MB
    short* msgL    = (short*)(ws + o); o += (size_t)B_ * SEQ_ * D_ * 2;    // 2 MB
    short* scnH    = (short*)(ws + o); o += (size_t)B_ * SEQ_ * NS_ * 2;
    short* scnL    = (short*)(ws + o); o += (size_t)B_ * SEQ_ * NS_ * 2;
    float* zgW     = (float*)(ws + o); o += (size_t)B_ * SEQ_ * SEQ_ * 4;
    float* zlW     = (float*)(ws + o); o += (size_t)B_ * SEQ_ * SEQ_ * 4;
    int* qMeta     = (int*)(ws + o);   o += 256;
    int* qRows     = (int*)(ws + o);   o += (size_t)MAXQ_ * 4;
    // dense-weight buffer overlays msgH+msgL (dead after sims): 4 MB
    float* wq      = (float*)msgH;

    setup_kernel<<<dim3(833), dim3(256), 0, stream>>>(
        messages, scn, hidden, gvel, ctx, ent, W_probe, W_vel, W_gate, b_gate,
        msgH, msgL, scnH, scnL, (const unsigned int*)mask, flag, qMeta,
        wsAh, wsAl, wsProbe, wsMode, wsGw);
    sims_kernel<<<dim3(512), dim3(512), 0, stream>>>(
        msgH, msgL, scnH, scnL, wsAh, wsAl, wsMode, mask, flag, zgW, zlW);
    route4_kernel<<<dim3(B_ * SEQ_ / 4), dim3(256), 0, stream>>>(
        messages, scn, x_ids, static_nb, W_e1, b_e1, W_e2, b_e2,
        wsProbe, wsGw, zgW, zlW, wq, qRows, qMeta, out);
    cleanup_kernel<<<dim3(64), dim3(256), 0, stream>>>(
        messages, wsProbe, wq, qRows, qMeta, out);
}

// Round 14
// 111.162 us; speedup vs baseline: 2.2150x; 1.2473x over previous
//
#include <hip/hip_runtime.h>
#include <math.h>

#define D_ 256
#define NS_ 64
#define KNB_ 8
#define SEQ_ 1024
#define B_ 4
#define MAXQ_ 1024
#define NEG_ (-10000.0f)
#define BLKNEG_ (-50000.0f)

// packed sizes (shorts)
#define MSGP_B 262144      // 64 tiles * 8 ksteps * 64 lanes * 8
#define SCNP_B 65536       // 64 tiles * 2 ksteps * 64 lanes * 8
#define ASTEPS 12          // e'(2) | s'(2) | h'(8)

typedef short bf16x8 __attribute__((ext_vector_type(8)));
typedef float f32x4 __attribute__((ext_vector_type(4)));

__device__ __forceinline__ float waveSum(float v) {
#pragma unroll
    for (int off = 32; off; off >>= 1) v += __shfl_xor(v, off, 64);
    return v;
}

__device__ __forceinline__ void waveSum2(float& a, float& b) {
#pragma unroll
    for (int off = 32; off; off >>= 1) {
        a += __shfl_xor(a, off, 64);
        b += __shfl_xor(b, off, 64);
    }
}

__device__ __forceinline__ float blockSum(float v, float* scr) {
    const int tid = threadIdx.x;
    const int wid = tid >> 6, lane = tid & 63;
    v = waveSum(v);
    __syncthreads();
    if (lane == 0) scr[wid] = v;
    __syncthreads();
    return scr[0] + scr[1] + scr[2] + scr[3];
}

__device__ __forceinline__ void blockSum4(float v[4], float (*scr4)[4]) {
    const int tid = threadIdx.x;
    const int wid = tid >> 6, lane = tid & 63;
#pragma unroll
    for (int off = 32; off; off >>= 1) {
#pragma unroll
        for (int q = 0; q < 4; ++q) v[q] += __shfl_xor(v[q], off, 64);
    }
    __syncthreads();
    if (lane == 0) {
#pragma unroll
        for (int q = 0; q < 4; ++q) scr4[wid][q] = v[q];
    }
    __syncthreads();
#pragma unroll
    for (int q = 0; q < 4; ++q)
        v[q] = scr4[0][q] + scr4[1][q] + scr4[2][q] + scr4[3][q];
}

// exact sparsemax tau via support iteration (monotone, fixpoint = exact tau)
__device__ __forceinline__ float sparsemaxTauWave(const float* zr) {
    float mx = zr[0];
#pragma unroll
    for (int i = 1; i < 16; ++i) mx = fmaxf(mx, zr[i]);
#pragma unroll
    for (int off = 32; off; off >>= 1) mx = fmaxf(mx, __shfl_xor(mx, off, 64));
    float tau = mx - 1.0f;
    for (int it = 0; it < 32; ++it) {
        float ssum = 0.f, cnt = 0.f;
#pragma unroll
        for (int i = 0; i < 16; ++i) {
            if (zr[i] > tau) { ssum += zr[i]; cnt += 1.f; }
        }
        waveSum2(ssum, cnt);
        if (cnt < 0.5f) break;
        const float nt = (ssum - 1.0f) / cnt;
        if (nt == tau) break;
        tau = nt;
    }
    return tau;
}

// split fp32 -> bf16 hi + bf16 lo (truncation; a ~= hi + lo, err ~2^-16 rel)
__device__ __forceinline__ void cvtSplit(float a, short& h, short& l) {
    const unsigned ab = __float_as_uint(a);
    h = (short)(ab >> 16);
    const float hf = __uint_as_float(ab & 0xFFFF0000u);
    l = (short)(__float_as_uint(a - hf) >> 16);
}

// A-pack index: ((sg*12 + st)*64 + kq*16 + m16)*8 + j
__device__ __forceinline__ size_t aIdx(int sg, int st, int kq, int m16, int j) {
    return ((((size_t)sg * ASTEPS + st) << 6) + (kq << 4) + m16) * 8 + j;
}

// Fused setup: fragment-major bf16-split packing + mask detect + prep.
// blocks [0,256): messages -> msgH/msgL packed (b=bid>>6, T=bid&63)
// [256,320): scn -> scnH/scnL packed (4 tiles per block)
// 320: mask detect + counter zero; [321,833): prep (8 rows each).
__global__ __launch_bounds__(256) void setup_kernel(
    const float* __restrict__ messages, const float* __restrict__ scn,
    const float* __restrict__ hidden, const float* __restrict__ gvel,
    const float* __restrict__ ctx, const float* __restrict__ ent,
    const float* __restrict__ W_probe, const float* __restrict__ W_vel,
    const float* __restrict__ W_gate, const float* __restrict__ b_gate,
    short* __restrict__ msgH, short* __restrict__ msgL,
    short* __restrict__ scnH, short* __restrict__ scnL,
    const unsigned int* __restrict__ maskW, int* __restrict__ flag,
    int* __restrict__ qMeta,
    short* __restrict__ wsAh, short* __restrict__ wsAl,
    float* __restrict__ wsProbe,
    int* __restrict__ wsMode, float* __restrict__ wsGw)
{
    const int bid = blockIdx.x;
    const int tid = threadIdx.x;

    if (bid < 256) {   // messages -> packed fragments
        const int b = bid >> 6, T = bid & 63;
        const float* src = messages + (size_t)b * SEQ_ * D_;
        short* dh = msgH + (size_t)b * MSGP_B;
        short* dl = msgL + (size_t)b * MSGP_B;
#pragma unroll
        for (int it = 0; it < 2; ++it) {
            const int g = (it << 8) + tid;         // 0..511
            const int st = g >> 6, kq = (g >> 4) & 3, m16 = g & 15;
            const int t = (T << 4) + m16;
            const int k0 = (st << 5) + (kq << 3);
            const float4 v0 = *(const float4*)(src + (size_t)t * D_ + k0);
            const float4 v1 = *(const float4*)(src + (size_t)t * D_ + k0 + 4);
            short h[8], l[8];
            cvtSplit(v0.x, h[0], l[0]); cvtSplit(v0.y, h[1], l[1]);
            cvtSplit(v0.z, h[2], l[2]); cvtSplit(v0.w, h[3], l[3]);
            cvtSplit(v1.x, h[4], l[4]); cvtSplit(v1.y, h[5], l[5]);
            cvtSplit(v1.z, h[6], l[6]); cvtSplit(v1.w, h[7], l[7]);
            const size_t o = (((size_t)T * 8 + st) << 9) + (size_t)((kq << 4) + m16) * 8;
            *(short4*)(dh + o) = make_short4(h[0], h[1], h[2], h[3]);
            *(short4*)(dh + o + 4) = make_short4(h[4], h[5], h[6], h[7]);
            *(short4*)(dl + o) = make_short4(l[0], l[1], l[2], l[3]);
            *(short4*)(dl + o + 4) = make_short4(l[4], l[5], l[6], l[7]);
        }
        return;
    }

    if (bid < 320) {   // scn -> packed fragments, 4 tiles per block
        const int i = bid - 256;
        const int b = i >> 4;
        const float* src = scn + (size_t)b * SEQ_ * NS_;
        short* dh = scnH + (size_t)b * SCNP_B;
        short* dl = scnL + (size_t)b * SCNP_B;
#pragma unroll
        for (int tt = 0; tt < 4; ++tt) {
            const int T = ((i & 15) << 2) + tt;
            if (tid < 128) {
                const int st = tid >> 6, kq = (tid >> 4) & 3, m16 = tid & 15;
                const int t = (T << 4) + m16;
                const int k0 = (st << 5) + (kq << 3);
                const float4 v0 = *(const float4*)(src + (size_t)t * NS_ + k0);
                const float4 v1 = *(const float4*)(src + (size_t)t * NS_ + k0 + 4);
                short h[8], l[8];
                cvtSplit(v0.x, h[0], l[0]); cvtSplit(v0.y, h[1], l[1]);
                cvtSplit(v0.z, h[2], l[2]); cvtSplit(v0.w, h[3], l[3]);
                cvtSplit(v1.x, h[4], l[4]); cvtSplit(v1.y, h[5], l[5]);
                cvtSplit(v1.z, h[6], l[6]); cvtSplit(v1.w, h[7], l[7]);
                const size_t o = (((size_t)T * 2 + st) << 9) + (size_t)((kq << 4) + m16) * 8;
                *(short4*)(dh + o) = make_short4(h[0], h[1], h[2], h[3]);
                *(short4*)(dh + o + 4) = make_short4(h[4], h[5], h[6], h[7]);
                *(short4*)(dl + o) = make_short4(l[0], l[1], l[2], l[3]);
                *(short4*)(dl + o + 4) = make_short4(l[4], l[5], l[6], l[7]);
            }
        }
        return;
    }

    if (bid == 320) {
        __shared__ int notI, notF;
        if (tid == 0) { notI = 0; notF = 0; qMeta[0] = 0; qMeta[1] = 0; }
        __syncthreads();
        int ni = 0, nf = 0;
        for (int i = tid; i < 1024; i += 256) {
            const unsigned int w = maskW[i];
            if (w != 0u && w != 1u) ni = 1;
            if (w != 0u && w != 0x3f800000u) nf = 1;
        }
        if (ni) atomicOr(&notI, 1);
        if (nf) atomicOr(&notF, 1);
        __syncthreads();
        if (tid == 0) *flag = (!notI) ? 0 : ((!notF) ? 2 : 1);
        return;
    }

    // ---- prep: 8 rows per block; A written in fragment-major pack ----
    __shared__ float scr4[4][4];
    const int rowBase = (bid - 321) << 3;
    const int wid = tid >> 6, lane = tid & 63;
    const float* h0 = hidden + (size_t)rowBase * D_;

    float vh[8] = {};
    for (int e = 0; e < NS_; e += 4) {
        const float4 wv4 = *(const float4*)(W_vel + (size_t)tid * NS_ + e);  // thread-own row
#pragma unroll
        for (int r = 0; r < 8; ++r) {
            const float4 g4 = *(const float4*)(gvel + (size_t)(rowBase + r) * NS_ + e); // uniform
            vh[r] = fmaf(g4.x, wv4.x, fmaf(g4.y, wv4.y, fmaf(g4.z, wv4.z, fmaf(g4.w, wv4.w, vh[r]))));
        }
    }
    float pr[8] = {};
    for (int e = 0; e < D_; e += 4) {
        const float4 wp4 = *(const float4*)(W_probe + (size_t)tid * D_ + e);  // thread-own row
#pragma unroll
        for (int r = 0; r < 8; ++r) {
            const float4 h4 = *(const float4*)(h0 + (size_t)r * D_ + e);      // uniform
            pr[r] = fmaf(h4.x, wp4.x, fmaf(h4.y, wp4.y, fmaf(h4.z, wp4.z, fmaf(h4.w, wp4.w, pr[r]))));
        }
    }

    // per-wave: wave w handles rows 2w, 2w+1 (endpoint e', s', argmax, gate)
#pragma unroll
    for (int rr = 0; rr < 2; ++rr) {
        const int r = (wid << 1) + rr, row = rowBase + r;
        const int sg = row >> 4, m16 = row & 15;
        const float sv = scn[(size_t)row * NS_ + lane];
        const float gv = gvel[(size_t)row * NS_ + lane];
        const float Hn = ent[row] / 10.373491191781864f;   // log(32000)+1e-8
        const float e = sv + 0.4f * gv;
        const float ss = waveSum(e * e);
        const int stE = lane >> 5, kqE = (lane & 31) >> 3, jE = lane & 7;
        short hh, ll;
        cvtSplit((e / fmaxf(sqrtf(ss), 1e-12f)) * 5.0f * Hn, hh, ll);
        wsAh[aIdx(sg, stE, kqE, m16, jE)] = hh;
        wsAl[aIdx(sg, stE, kqE, m16, jE)] = ll;
        cvtSplit(5.0f * sv, hh, ll);
        wsAh[aIdx(sg, 2 + stE, kqE, m16, jE)] = hh;
        wsAl[aIdx(sg, 2 + stE, kqE, m16, jE)] = ll;
        float v = sv; int idx = lane;
#pragma unroll
        for (int off = 1; off < 64; off <<= 1) {
            const float ov = __shfl_xor(v, off, 64);
            const int   oi = __shfl_xor(idx, off, 64);
            if (ov > v || (ov == v && oi < idx)) { v = ov; idx = oi; }
        }
        float gd = 0.f;
#pragma unroll
        for (int j = 0; j < 4; ++j) {
            const int d = lane + (j << 6);
            gd = fmaf(h0[(size_t)r * D_ + d], W_gate[d], gd);
        }
        gd = waveSum(gd);
        if (lane == 0) {
            wsMode[row] = idx;
            const float raw = 1.f / (1.f + expf(-(gd + b_gate[0])));
            wsGw[row] = raw * ctx[row];
        }
    }

    // block-wide norms; h' written packed
    const int stH = 4 + (tid >> 5), kqH = (tid & 31) >> 3, jH = tid & 7;
#pragma unroll
    for (int g = 0; g < 2; ++g) {
        float ha4[4], va[4], vp[4];
#pragma unroll
        for (int q = 0; q < 4; ++q) {
            const int r = (g << 2) + q;
            ha4[q] = h0[(size_t)r * D_ + tid] + 0.3f * vh[r];
            va[q] = ha4[q] * ha4[q];
            vp[q] = pr[(g << 2) + q] * pr[(g << 2) + q];
        }
        blockSum4(va, scr4);
        blockSum4(vp, scr4);
#pragma unroll
        for (int q = 0; q < 4; ++q) {
            const int r = (g << 2) + q;
            const int row = rowBase + r;
            const int sg = row >> 4, m16 = row & 15;
            short hh, ll;
            cvtSplit((ha4[q] / fmaxf(sqrtf(va[q]), 1e-12f)) * 2.5f, hh, ll);
            wsAh[aIdx(sg, stH, kqH, m16, jH)] = hh;
            wsAl[aIdx(sg, stH, kqH, m16, jH)] = ll;
            wsProbe[(size_t)row * D_ + tid] = pr[r] / fmaxf(sqrtf(vp[q]), 1e-12f);
        }
    }
}

// Kernel A: all-pairs sims via split-bf16 MFMA, fragment-packed operands:
// every A/B load is lane-contiguous (1 KB/wave-load).  512 blocks =
// b(4) x rowgroup(64) x colhalf(2); 8 waves x 4 col-tiles.
__global__ __launch_bounds__(512) void sims_kernel(
    const short* __restrict__ msgH, const short* __restrict__ msgL,   // packed
    const short* __restrict__ scnH, const short* __restrict__ scnL,   // packed
    const short* __restrict__ wsAh, const short* __restrict__ wsAl,   // packed
    const int* __restrict__ wsMode,
    const void* __restrict__ maskP,
    const int* __restrict__ maskFlag,
    float* __restrict__ zgO,            // [4096][1024]
    float* __restrict__ zlO)            // [4096][1024]
{
    const int bid = blockIdx.x;          // 512 blocks
    const int half = bid & 1;
    const int sg = (bid >> 1) & 63;
    const int b = bid >> 7;
    const int sBase = sg << 4;           // 16 rows
    const int rowBase = (b << 10) + sBase;
    const int tid = threadIdx.x;
    const int w = tid >> 6, l = tid & 63;
    const int m16 = l & 15, kq = l >> 4;
    const int l8 = l << 3;

    const int sgA = (b << 6) + sg;       // global rowgroup for A pack
    const short* AhB = wsAh + (size_t)sgA * (ASTEPS * 512) + l8;
    const short* AlB = wsAl + (size_t)sgA * (ASTEPS * 512) + l8;

    f32x4 accG[4], accL8[4];
#pragma unroll
    for (int ct = 0; ct < 4; ++ct) {
        accG[ct] = (f32x4){0.f, 0.f, 0.f, 0.f};
        accL8[ct] = (f32x4){0.f, 0.f, 0.f, 0.f};
    }

    // ---- scn k-steps (2): e' -> accG, s' -> accL, shared B loads ----
#pragma unroll
    for (int st = 0; st < 2; ++st) {
        const bf16x8 aeh = *(const bf16x8*)(AhB + (st << 9));
        const bf16x8 ael = *(const bf16x8*)(AlB + (st << 9));
        const bf16x8 ash = *(const bf16x8*)(AhB + ((2 + st) << 9));
        const bf16x8 asl = *(const bf16x8*)(AlB + ((2 + st) << 9));
#pragma unroll
        for (int ct = 0; ct < 4; ++ct) {
            const int mtile = (half << 5) + (w << 2) + ct;
            const size_t bo = (size_t)b * SCNP_B + (((size_t)mtile * 2 + st) << 9) + l8;
            const bf16x8 bh = *(const bf16x8*)(scnH + bo);
            const bf16x8 bl = *(const bf16x8*)(scnL + bo);
            accG[ct] = __builtin_amdgcn_mfma_f32_16x16x32_bf16(aeh, bh, accG[ct], 0, 0, 0);
            accG[ct] = __builtin_amdgcn_mfma_f32_16x16x32_bf16(aeh, bl, accG[ct], 0, 0, 0);
            accG[ct] = __builtin_amdgcn_mfma_f32_16x16x32_bf16(ael, bh, accG[ct], 0, 0, 0);
            accL8[ct] = __builtin_amdgcn_mfma_f32_16x16x32_bf16(ash, bh, accL8[ct], 0, 0, 0);
            accL8[ct] = __builtin_amdgcn_mfma_f32_16x16x32_bf16(ash, bl, accL8[ct], 0, 0, 0);
            accL8[ct] = __builtin_amdgcn_mfma_f32_16x16x32_bf16(asl, bh, accL8[ct], 0, 0, 0);
        }
    }
    // ---- msg k-steps (8): h' -> accG ----
#pragma unroll
    for (int st = 0; st < 8; ++st) {
        const bf16x8 ah = *(const bf16x8*)(AhB + ((4 + st) << 9));
        const bf16x8 al = *(const bf16x8*)(AlB + ((4 + st) << 9));
#pragma unroll
        for (int ct = 0; ct < 4; ++ct) {
            const int mtile = (half << 5) + (w << 2) + ct;
            const size_t bo = (size_t)b * MSGP_B + (((size_t)mtile * 8 + st) << 9) + l8;
            const bf16x8 bh = *(const bf16x8*)(msgH + bo);
            const bf16x8 bl = *(const bf16x8*)(msgL + bo);
            accG[ct] = __builtin_amdgcn_mfma_f32_16x16x32_bf16(ah, bh, accG[ct], 0, 0, 0);
            accG[ct] = __builtin_amdgcn_mfma_f32_16x16x32_bf16(ah, bl, accG[ct], 0, 0, 0);
            accG[ct] = __builtin_amdgcn_mfma_f32_16x16x32_bf16(al, bh, accG[ct], 0, 0, 0);
        }
    }

    // ---- tail: mask + mode; write zg + raw zl ----
    const int tBase = (half << 9) + (w << 6);
    const int mf = *maskFlag;
    const int4 mS4 = *(const int4*)(wsMode + rowBase + (kq << 2));   // this lane's 4 rows
    const int mSq[4] = {mS4.x, mS4.y, mS4.z, mS4.w};
#pragma unroll
    for (int ct = 0; ct < 4; ++ct) {
        const int t = tBase + (ct << 4) + m16;
        const int mdt = wsMode[(b << 10) + t];
#pragma unroll
        for (int q = 0; q < 4; ++q) {
            const int r = (kq << 2) + q;
            const int s_r = sBase + r;
            const size_t mb = (size_t)s_r * SEQ_ + t;
            int blk;
            if (mf == 1)      blk = ((const unsigned char*)maskP)[mb] != 0;
            else if (mf == 2) blk = ((const float*)maskP)[mb] != 0.f;
            else              blk = ((const int*)maskP)[mb] != 0;
            if (s_r == t) blk = 1;
            zgO[(size_t)(rowBase + r) * SEQ_ + t] = blk ? NEG_ : accG[ct][q];
            const int sm = (!blk) && (mdt == mSq[q]);
            zlO[(size_t)(rowBase + r) * SEQ_ + t] =
                blk ? BLKNEG_ : (sm ? accL8[ct][q] : 0.0f);
        }
    }
}

// Kernel B: 4 waves per block, wave owns one row (mirror-balanced).
// hasNb derived in-row from raw zl.  Sparse combined gather; dense rows
// deferred to cleanup via queue.
__global__ __launch_bounds__(256) void route4_kernel(
    const float* __restrict__ messages,
    const float* __restrict__ scn,
    const int* __restrict__ x_ids,
    const int* __restrict__ static_nb,
    const float* __restrict__ W_e1,
    const float* __restrict__ b_e1,
    const float* __restrict__ W_e2,
    const float* __restrict__ b_e2,
    const float* __restrict__ wsProbe,
    const float* __restrict__ wsGw,
    const float* __restrict__ zgA,
    const float* __restrict__ zlA,
    float* __restrict__ wq,          // [MAXQ][1024] dense weights
    int* __restrict__ qRows,
    int* __restrict__ qMeta,         // [0]=tail, [1]=consume
    float* __restrict__ out)
{
    __shared__ uint2 lst[4][256];
    __shared__ float ewLds[4][8];
    __shared__ int   mlist[4][64];

    const int jb = blockIdx.x;               // 0..1023
    const int tid = threadIdx.x;
    const int wid = tid >> 6, lane = tid & 63;
    const int base = jb << 1;
    const int row = (wid == 0) ? base
                  : (wid == 1) ? base + 1
                  : (wid == 2) ? 4094 - base
                               : 4095 - base;
    const int b = row >> 10, s_r = row & 1023;
    const float* msgB = messages + (size_t)b * SEQ_ * D_;
    const float* scnB = scn + (size_t)b * SEQ_ * NS_;
    const unsigned long long ltmask = (1ull << lane) - 1ull;
    const int d4 = lane << 2;

    float zrG[16], zrL[16];
    {
        const float4* zgp = (const float4*)(zgA + (size_t)row * SEQ_ + (lane << 4));
        const float4* zlp = (const float4*)(zlA + (size_t)row * SEQ_ + (lane << 4));
#pragma unroll
        for (int q = 0; q < 4; ++q) {
            const float4 g4 = zgp[q];
            zrG[q * 4 + 0] = g4.x; zrG[q * 4 + 1] = g4.y;
            zrG[q * 4 + 2] = g4.z; zrG[q * 4 + 3] = g4.w;
            const float4 l4 = zlp[q];
            zrL[q * 4 + 0] = l4.x; zrL[q * 4 + 1] = l4.y;
            zrL[q * 4 + 2] = l4.z; zrL[q * 4 + 3] = l4.w;
        }
    }

    // ----- static neighbor-vocab scan: ONE ballot per 64-block (kmask) -----
    const int q = x_ids[row];
    int nb[KNB_];
#pragma unroll
    for (int k = 0; k < KNB_; ++k) nb[k] = static_nb[(size_t)q * KNB_ + k];
    const float ss_l = scnB[(size_t)s_r * NS_ + lane];
    float simk[KNB_] = {};
    unsigned matchedMask = 0;
    int mcW = 0;
    const int* xb = x_ids + (b << 10);
    for (int pb = 0; pb <= s_r; pb += 64) {
        const int p = pb + lane;
        const int id = (p <= s_r) ? xb[p] : -2147483647;
        unsigned kmask = 0;
#pragma unroll
        for (int k = 0; k < KNB_; ++k) kmask |= (id == nb[k]) ? (1u << k) : 0u;
        unsigned long long mb = __ballot(kmask != 0u);
        while (mb) {
            const int src = __ffsll(mb) - 1; mb &= mb - 1;
            const unsigned kms = (unsigned)__shfl((int)kmask, src, 64);
            const int pp = pb + src;
            float pv = scnB[(size_t)pp * NS_ + lane] * ss_l;
            pv = waveSum(pv);
            matchedMask |= kms;
#pragma unroll
            for (int k = 0; k < KNB_; ++k) {
                if ((kms >> k) & 1u) {
                    simk[k] += pv;
                    if (mcW < 64) { if (lane == 0) mlist[wid][mcW] = (pp << 3) | k; ++mcW; }
                }
            }
        }
    }
    const int kk = lane >> 3, jjn = lane & 7;
    float sv = simk[0];
#pragma unroll
    for (int k = 1; k < KNB_; ++k) sv = (kk == k) ? simk[k] : sv;
    const float xx = sv * W_e1[jjn] + b_e1[jjn];
    float eo = 0.5f * xx * (1.f + erff(xx * 0.70710678118654752f)) * W_e2[jjn];
    eo += __shfl_xor(eo, 1, 64); eo += __shfl_xor(eo, 2, 64); eo += __shfl_xor(eo, 4, 64);
    eo += b_e2[0];
    float m2 = eo;
    m2 = fmaxf(m2, __shfl_xor(m2, 8, 64));
    m2 = fmaxf(m2, __shfl_xor(m2, 16, 64));
    m2 = fmaxf(m2, __shfl_xor(m2, 32, 64));
    const float exv = expf(eo - m2);
    float smv = exv;
    smv += __shfl_xor(smv, 8, 64); smv += __shfl_xor(smv, 16, 64); smv += __shfl_xor(smv, 32, 64);
    if ((lane & 7) == 0) ewLds[wid][kk] = exv / smv;

    const float cov = (float)__popc(matchedMask) * 0.125f;
    const float gw = wsGw[row];
    const float coefG = gw;
    const float coefL = (1.f - gw) * (1.f - cov);
    const float coefS = (1.f - gw) * cov;

    // ----- local hasNb derived from raw zl -----
    int fl = 0;
#pragma unroll
    for (int j = 0; j < 16; ++j) fl |= (zrL[j] != 0.0f && zrL[j] > -40000.f);
    const int hasNb = __any(fl);
    if (!hasNb) {
#pragma unroll
        for (int j = 0; j < 16; ++j) {
            const int t = (lane << 4) + j;
            zrL[j] = (zrL[j] <= -40000.f) ? BLKNEG_ : -0.05f * fabsf((float)(s_r - t));
        }
    }

    const float tauG = sparsemaxTauWave(zrG);
    int supG = 0;
#pragma unroll
    for (int j = 0; j < 16; ++j) supG += __popcll(__ballot(zrG[j] > tauG));
    const float tauL = sparsemaxTauWave(zrL);
    int supL = 0;
#pragma unroll
    for (int j = 0; j < 16; ++j) supL += __popcll(__ballot(zrL[j] > tauL));
    const bool gDense = supG > 96;
    const bool lDense = supL > 96;

    int cnt = 0;
    if (!gDense) {
#pragma unroll
        for (int j = 0; j < 16; ++j) {
            const float wv = zrG[j] - tauG;
            const bool take = wv > 0.f;
            const unsigned long long m = __ballot(take);
            if (take) {
                const int pos = cnt + __popcll(m & ltmask);
                lst[wid][pos] = make_uint2((unsigned)((lane << 4) + j),
                                           __float_as_uint(coefG * wv));
            }
            cnt += __popcll(m);
        }
    }
    if (!lDense) {
#pragma unroll
        for (int j = 0; j < 16; ++j) {
            const float wv = zrL[j] - tauL;
            const bool take = wv > 0.f;
            const unsigned long long m = __ballot(take);
            if (take) {
                const int pos = cnt + __popcll(m & ltmask);
                lst[wid][pos] = make_uint2((unsigned)((lane << 4) + j),
                                           __float_as_uint(coefL * wv));
            }
            cnt += __popcll(m);
        }
    }
    const int nm = (mcW < 64) ? mcW : 64;
    for (int i = lane; i < nm; i += 64) {
        const int ee = mlist[wid][i];
        lst[wid][cnt + i] = make_uint2((unsigned)(ee >> 3),
                                       __float_as_uint(coefS * ewLds[wid][ee & 7]));
    }
    cnt += nm;

    float ox = 0.f, oy = 0.f, oz2 = 0.f, ow = 0.f;
    int i = 0;
    for (; i + 4 <= cnt; i += 4) {
        const uint2 e0 = lst[wid][i + 0];
        const uint2 e1 = lst[wid][i + 1];
        const uint2 e2 = lst[wid][i + 2];
        const uint2 e3 = lst[wid][i + 3];
        const float4 m0 = *(const float4*)(msgB + (size_t)e0.x * D_ + d4);
        const float4 m1 = *(const float4*)(msgB + (size_t)e1.x * D_ + d4);
        const float4 m2b = *(const float4*)(msgB + (size_t)e2.x * D_ + d4);
        const float4 m3 = *(const float4*)(msgB + (size_t)e3.x * D_ + d4);
        const float w0 = __uint_as_float(e0.y), w1 = __uint_as_float(e1.y);
        const float w2 = __uint_as_float(e2.y), w3 = __uint_as_float(e3.y);
        ox = fmaf(w0, m0.x, fmaf(w1, m1.x, fmaf(w2, m2b.x, fmaf(w3, m3.x, ox))));
        oy = fmaf(w0, m0.y, fmaf(w1, m1.y, fmaf(w2, m2b.y, fmaf(w3, m3.y, oy))));
        oz2 = fmaf(w0, m0.z, fmaf(w1, m1.z, fmaf(w2, m2b.z, fmaf(w3, m3.z, oz2))));
        ow = fmaf(w0, m0.w, fmaf(w1, m1.w, fmaf(w2, m2b.w, fmaf(w3, m3.w, ow))));
    }
    for (; i < cnt; ++i) {
        const uint2 e0 = lst[wid][i];
        const float w0 = __uint_as_float(e0.y);
        const float4 m0 = *(const float4*)(msgB + (size_t)e0.x * D_ + d4);
        ox = fmaf(w0, m0.x, ox); oy = fmaf(w0, m0.y, oy);
        oz2 = fmaf(w0, m0.z, oz2); ow = fmaf(w0, m0.w, ow);
    }

    int slot = -1;
    if (gDense || lDense) {
        int s0 = 0;
        if (lane == 0) s0 = atomicAdd(&qMeta[0], 1);
        slot = __shfl(s0, 0, 64);
    }
    if (slot >= 0 && slot < MAXQ_) {
#pragma unroll
        for (int qd = 0; qd < 4; ++qd) {
            float4 w4;
            float* wv4 = &w4.x;
#pragma unroll
            for (int u = 0; u < 4; ++u) {
                const int j = qd * 4 + u;
                float w = 0.f;
                if (gDense) w += coefG * fmaxf(zrG[j] - tauG, 0.f);
                if (lDense) w += coefL * fmaxf(zrL[j] - tauL, 0.f);
                wv4[u] = w;
            }
            *(float4*)(wq + (size_t)slot * SEQ_ + (lane << 4) + qd * 4) = w4;
        }
        if (lane == 0) qRows[slot] = row;
        *(float4*)(out + (size_t)row * D_ + d4) = make_float4(ox, oy, oz2, ow);
        return;
    }
    if (slot >= MAXQ_) {
#pragma unroll
        for (int j = 0; j < 16; ++j) {
            float wv = 0.f;
            if (gDense) wv += coefG * fmaxf(zrG[j] - tauG, 0.f);
            if (lDense) wv += coefL * fmaxf(zrL[j] - tauL, 0.f);
            unsigned long long m = __ballot(wv > 0.f);
            while (m) {
                const int s0 = __ffsll(m) - 1; m &= m - 1;
                const float w0 = __shfl(wv, s0, 64);
                const float4 m4 = *(const float4*)(msgB + (size_t)((s0 << 4) + j) * D_ + d4);
                ox = fmaf(w0, m4.x, ox); oy = fmaf(w0, m4.y, oy);
                oz2 = fmaf(w0, m4.z, oz2); ow = fmaf(w0, m4.w, ow);
            }
        }
    }

    float ssq = ox * ox + oy * oy + oz2 * oz2 + ow * ow;
    ssq = waveSum(ssq);
    const float nrm = fmaxf(sqrtf(ssq), 1e-12f);
    const float4 pr = *(const float4*)(wsProbe + (size_t)row * D_ + d4);
    float dp = (ox * pr.x + oy * pr.y + oz2 * pr.z + ow * pr.w) / nrm;
    dp = waveSum(dp);
    const float rel = 1.f / (1.f + expf(-dp));
    *(float4*)(out + (size_t)row * D_ + d4) =
        make_float4(ox * rel, oy * rel, oz2 * rel, ow * rel);
}

// Kernel C: drain dense-row queue.
__global__ __launch_bounds__(256) void cleanup_kernel(
    const float* __restrict__ messages,
    const float* __restrict__ wsProbe,
    const float* __restrict__ wq,
    const int* __restrict__ qRows,
    int* __restrict__ qMeta,
    float* __restrict__ out)
{
    __shared__ float wsh[SEQ_];
    __shared__ float scr[4];
    __shared__ int idxSh;
    const int tid = threadIdx.x;
    const int nq = (qMeta[0] < MAXQ_) ? qMeta[0] : MAXQ_;
    for (;;) {
        __syncthreads();
        if (tid == 0) idxSh = atomicAdd(&qMeta[1], 1);
        __syncthreads();
        const int idx = idxSh;
        if (idx >= nq) break;
        const int row = qRows[idx];
        const int b = row >> 10;
        const float* msgB = messages + (size_t)b * SEQ_ * D_;
        for (int i = tid; i < SEQ_; i += 256)
            wsh[i] = wq[(size_t)idx * SEQ_ + i];
        __syncthreads();
        float acc = out[(size_t)row * D_ + tid];
        for (int t = 0; t < SEQ_; t += 4) {
            acc = fmaf(wsh[t + 0], msgB[(size_t)(t + 0) * D_ + tid],
                  fmaf(wsh[t + 1], msgB[(size_t)(t + 1) * D_ + tid],
                  fmaf(wsh[t + 2], msgB[(size_t)(t + 2) * D_ + tid],
                  fmaf(wsh[t + 3], msgB[(size_t)(t + 3) * D_ + tid], acc))));
        }
        const float ssq = blockSum(acc * acc, scr);
        const float nrm = fmaxf(sqrtf(ssq), 1e-12f);
        const float dp = blockSum((acc / nrm) * wsProbe[(size_t)row * D_ + tid], scr);
        const float rel = 1.f / (1.f + expf(-dp));
        out[(size_t)row * D_ + tid] = acc * rel;
    }
}

extern "C" void kernel_launch(void* const* d_in, const int* in_sizes, int n_in,
                              void* d_out, int out_size, void* d_ws, size_t ws_size,
                              hipStream_t stream) {
    const float* messages  = (const float*)d_in[0];
    const float* hidden    = (const float*)d_in[1];
    const int*   x_ids     = (const int*)d_in[2];
    const float* scn       = (const float*)d_in[3];
    const void*  mask      = d_in[4];
    const int*   static_nb = (const int*)d_in[5];
    const float* gvel      = (const float*)d_in[6];
    const float* ctx       = (const float*)d_in[7];
    const float* ent       = (const float*)d_in[8];
    const float* W_vel     = (const float*)d_in[9];
    const float* W_e1      = (const float*)d_in[10];
    const float* b_e1      = (const float*)d_in[11];
    const float* W_e2      = (const float*)d_in[12];
    const float* b_e2      = (const float*)d_in[13];
    const float* W_probe   = (const float*)d_in[14];
    const float* W_gate    = (const float*)d_in[15];
    const float* b_gate    = (const float*)d_in[16];
    float* out = (float*)d_out;
    (void)in_sizes; (void)n_in; (void)out_size; (void)ws_size;

    char* ws = (char*)d_ws;
    size_t o = 0;
    int* flag      = (int*)(ws + o);   o += 256;
    short* wsAh    = (short*)(ws + o); o += (size_t)B_ * SEQ_ * 384 * 2;   // 3.1 MB packed
    short* wsAl    = (short*)(ws + o); o += (size_t)B_ * SEQ_ * 384 * 2;
    float* wsProbe = (float*)(ws + o); o += (size_t)B_ * SEQ_ * D_ * 4;
    int* wsMode    = (int*)(ws + o);   o += (size_t)B_ * SEQ_ * 4;
    float* wsGw    = (float*)(ws + o); o += (size_t)B_ * SEQ_ * 4;
    short* msgH    = (short*)(ws + o); o += (size_t)B_ * MSGP_B * 2;       // 2 MB packed
    short* msgL    = (short*)(ws + o); o += (size_t)B_ * MSGP_B * 2;
    short* scnH    = (short*)(ws + o); o += (size_t)B_ * SCNP_B * 2;
    short* scnL    = (short*)(ws + o); o += (size_t)B_ * SCNP_B * 2;
    float* zgW     = (float*)(ws + o); o += (size_t)B_ * SEQ_ * SEQ_ * 4;
    float* zlW     = (float*)(ws + o); o += (size_t)B_ * SEQ_ * SEQ_ * 4;
    int* qMeta     = (int*)(ws + o);   o += 256;
    int* qRows     = (int*)(ws + o);   o += (size_t)MAXQ_ * 4;
    // dense-weight buffer overlays msgH+msgL (dead after sims): 4 MB
    float* wq      = (float*)msgH;

    setup_kernel<<<dim3(833), dim3(256), 0, stream>>>(
        messages, scn, hidden, gvel, ctx, ent, W_probe, W_vel, W_gate, b_gate,
        msgH, msgL, scnH, scnL, (const unsigned int*)mask, flag, qMeta,
        wsAh, wsAl, wsProbe, wsMode, wsGw);
    sims_kernel<<<dim3(512), dim3(512), 0, stream>>>(
        msgH, msgL, scnH, scnL, wsAh, wsAl, wsMode, mask, flag, zgW, zlW);
    route4_kernel<<<dim3(B_ * SEQ_ / 4), dim3(256), 0, stream>>>(
        messages, scn, x_ids, static_nb, W_e1, b_e1, W_e2, b_e2,
        wsProbe, wsGw, zgW, zlW, wq, qRows, qMeta, out);
    cleanup_kernel<<<dim3(64), dim3(256), 0, stream>>>(
        messages, wsProbe, wq, qRows, qMeta, out);
}

// Round 15
// 105.342 us; speedup vs baseline: 2.3374x; 1.0552x over previous
//
#include <hip/hip_runtime.h>
#include <math.h>

#define D_ 256
#define NS_ 64
#define KNB_ 8
#define SEQ_ 1024
#define B_ 4
#define MAXQ_ 1024
#define NEG_ (-10000.0f)
#define BLKNEG_ (-50000.0f)

// packed sizes (shorts)
#define MSGP_B 262144      // 64 tiles * 8 ksteps * 64 lanes * 8
#define SCNP_B 65536       // 64 tiles * 2 ksteps * 64 lanes * 8
#define ASTEPS 12          // e'(2) | s'(2) | h'(8)

typedef short bf16x8 __attribute__((ext_vector_type(8)));
typedef float f32x4 __attribute__((ext_vector_type(4)));

__device__ __forceinline__ float waveSum(float v) {
#pragma unroll
    for (int off = 32; off; off >>= 1) v += __shfl_xor(v, off, 64);
    return v;
}

__device__ __forceinline__ float blockSum(float v, float* scr) {
    const int tid = threadIdx.x;
    const int wid = tid >> 6, lane = tid & 63;
    v = waveSum(v);
    __syncthreads();
    if (lane == 0) scr[wid] = v;
    __syncthreads();
    return scr[0] + scr[1] + scr[2] + scr[3];
}

__device__ __forceinline__ void blockSum4(float v[4], float (*scr4)[4]) {
    const int tid = threadIdx.x;
    const int wid = tid >> 6, lane = tid & 63;
#pragma unroll
    for (int off = 32; off; off >>= 1) {
#pragma unroll
        for (int q = 0; q < 4; ++q) v[q] += __shfl_xor(v[q], off, 64);
    }
    __syncthreads();
    if (lane == 0) {
#pragma unroll
        for (int q = 0; q < 4; ++q) scr4[wid][q] = v[q];
    }
    __syncthreads();
#pragma unroll
    for (int q = 0; q < 4; ++q)
        v[q] = scr4[0][q] + scr4[1][q] + scr4[2][q] + scr4[3][q];
}

// split fp32 -> bf16 hi + bf16 lo (truncation; a ~= hi + lo, err ~2^-16 rel)
__device__ __forceinline__ void cvtSplit(float a, short& h, short& l) {
    const unsigned ab = __float_as_uint(a);
    h = (short)(ab >> 16);
    const float hf = __uint_as_float(ab & 0xFFFF0000u);
    l = (short)(__float_as_uint(a - hf) >> 16);
}

// A-pack index: ((sg*12 + st)*64 + kq*16 + m16)*8 + j
__device__ __forceinline__ size_t aIdx(int sg, int st, int kq, int m16, int j) {
    return ((((size_t)sg * ASTEPS + st) << 6) + (kq << 4) + m16) * 8 + j;
}

// Fused setup: fragment-major bf16-split packing + mask detect + prep.
// blocks [0,256): messages -> msgH/msgL packed (b=bid>>6, T=bid&63)
// [256,320): scn -> scnH/scnL packed (4 tiles per block)
// 320: mask detect + counter zero; [321,833): prep (8 rows each).
__global__ __launch_bounds__(256) void setup_kernel(
    const float* __restrict__ messages, const float* __restrict__ scn,
    const float* __restrict__ hidden, const float* __restrict__ gvel,
    const float* __restrict__ ctx, const float* __restrict__ ent,
    const float* __restrict__ W_probe, const float* __restrict__ W_vel,
    const float* __restrict__ W_gate, const float* __restrict__ b_gate,
    short* __restrict__ msgH, short* __restrict__ msgL,
    short* __restrict__ scnH, short* __restrict__ scnL,
    const unsigned int* __restrict__ maskW, int* __restrict__ flag,
    int* __restrict__ qMeta,
    short* __restrict__ wsAh, short* __restrict__ wsAl,
    float* __restrict__ wsProbe,
    int* __restrict__ wsMode, float* __restrict__ wsGw)
{
    const int bid = blockIdx.x;
    const int tid = threadIdx.x;

    if (bid < 256) {   // messages -> packed fragments
        const int b = bid >> 6, T = bid & 63;
        const float* src = messages + (size_t)b * SEQ_ * D_;
        short* dh = msgH + (size_t)b * MSGP_B;
        short* dl = msgL + (size_t)b * MSGP_B;
#pragma unroll
        for (int it = 0; it < 2; ++it) {
            const int g = (it << 8) + tid;         // 0..511
            const int st = g >> 6, kq = (g >> 4) & 3, m16 = g & 15;
            const int t = (T << 4) + m16;
            const int k0 = (st << 5) + (kq << 3);
            const float4 v0 = *(const float4*)(src + (size_t)t * D_ + k0);
            const float4 v1 = *(const float4*)(src + (size_t)t * D_ + k0 + 4);
            short h[8], l[8];
            cvtSplit(v0.x, h[0], l[0]); cvtSplit(v0.y, h[1], l[1]);
            cvtSplit(v0.z, h[2], l[2]); cvtSplit(v0.w, h[3], l[3]);
            cvtSplit(v1.x, h[4], l[4]); cvtSplit(v1.y, h[5], l[5]);
            cvtSplit(v1.z, h[6], l[6]); cvtSplit(v1.w, h[7], l[7]);
            const size_t o = (((size_t)T * 8 + st) << 9) + (size_t)((kq << 4) + m16) * 8;
            *(short4*)(dh + o) = make_short4(h[0], h[1], h[2], h[3]);
            *(short4*)(dh + o + 4) = make_short4(h[4], h[5], h[6], h[7]);
            *(short4*)(dl + o) = make_short4(l[0], l[1], l[2], l[3]);
            *(short4*)(dl + o + 4) = make_short4(l[4], l[5], l[6], l[7]);
        }
        return;
    }

    if (bid < 320) {   // scn -> packed fragments, 4 tiles per block
        const int i = bid - 256;
        const int b = i >> 4;
        const float* src = scn + (size_t)b * SEQ_ * NS_;
        short* dh = scnH + (size_t)b * SCNP_B;
        short* dl = scnL + (size_t)b * SCNP_B;
#pragma unroll
        for (int tt = 0; tt < 4; ++tt) {
            const int T = ((i & 15) << 2) + tt;
            if (tid < 128) {
                const int st = tid >> 6, kq = (tid >> 4) & 3, m16 = tid & 15;
                const int t = (T << 4) + m16;
                const int k0 = (st << 5) + (kq << 3);
                const float4 v0 = *(const float4*)(src + (size_t)t * NS_ + k0);
                const float4 v1 = *(const float4*)(src + (size_t)t * NS_ + k0 + 4);
                short h[8], l[8];
                cvtSplit(v0.x, h[0], l[0]); cvtSplit(v0.y, h[1], l[1]);
                cvtSplit(v0.z, h[2], l[2]); cvtSplit(v0.w, h[3], l[3]);
                cvtSplit(v1.x, h[4], l[4]); cvtSplit(v1.y, h[5], l[5]);
                cvtSplit(v1.z, h[6], l[6]); cvtSplit(v1.w, h[7], l[7]);
                const size_t o = (((size_t)T * 2 + st) << 9) + (size_t)((kq << 4) + m16) * 8;
                *(short4*)(dh + o) = make_short4(h[0], h[1], h[2], h[3]);
                *(short4*)(dh + o + 4) = make_short4(h[4], h[5], h[6], h[7]);
                *(short4*)(dl + o) = make_short4(l[0], l[1], l[2], l[3]);
                *(short4*)(dl + o + 4) = make_short4(l[4], l[5], l[6], l[7]);
            }
        }
        return;
    }

    if (bid == 320) {
        __shared__ int notI, notF;
        if (tid == 0) { notI = 0; notF = 0; qMeta[0] = 0; qMeta[1] = 0; }
        __syncthreads();
        int ni = 0, nf = 0;
        for (int i = tid; i < 1024; i += 256) {
            const unsigned int w = maskW[i];
            if (w != 0u && w != 1u) ni = 1;
            if (w != 0u && w != 0x3f800000u) nf = 1;
        }
        if (ni) atomicOr(&notI, 1);
        if (nf) atomicOr(&notF, 1);
        __syncthreads();
        if (tid == 0) *flag = (!notI) ? 0 : ((!notF) ? 2 : 1);
        return;
    }

    // ---- prep: 8 rows per block; A written in fragment-major pack ----
    __shared__ float scr4[4][4];
    const int rowBase = (bid - 321) << 3;
    const int wid = tid >> 6, lane = tid & 63;
    const float* h0 = hidden + (size_t)rowBase * D_;

    float vh[8] = {};
    for (int e = 0; e < NS_; e += 4) {
        const float4 wv4 = *(const float4*)(W_vel + (size_t)tid * NS_ + e);  // thread-own row
#pragma unroll
        for (int r = 0; r < 8; ++r) {
            const float4 g4 = *(const float4*)(gvel + (size_t)(rowBase + r) * NS_ + e); // uniform
            vh[r] = fmaf(g4.x, wv4.x, fmaf(g4.y, wv4.y, fmaf(g4.z, wv4.z, fmaf(g4.w, wv4.w, vh[r]))));
        }
    }
    float pr[8] = {};
    for (int e = 0; e < D_; e += 4) {
        const float4 wp4 = *(const float4*)(W_probe + (size_t)tid * D_ + e);  // thread-own row
#pragma unroll
        for (int r = 0; r < 8; ++r) {
            const float4 h4 = *(const float4*)(h0 + (size_t)r * D_ + e);      // uniform
            pr[r] = fmaf(h4.x, wp4.x, fmaf(h4.y, wp4.y, fmaf(h4.z, wp4.z, fmaf(h4.w, wp4.w, pr[r]))));
        }
    }

    // per-wave: wave w handles rows 2w, 2w+1 (endpoint e', s', argmax, gate)
#pragma unroll
    for (int rr = 0; rr < 2; ++rr) {
        const int r = (wid << 1) + rr, row = rowBase + r;
        const int sg = row >> 4, m16 = row & 15;
        const float sv = scn[(size_t)row * NS_ + lane];
        const float gv = gvel[(size_t)row * NS_ + lane];
        const float Hn = ent[row] / 10.373491191781864f;   // log(32000)+1e-8
        const float e = sv + 0.4f * gv;
        const float ss = waveSum(e * e);
        const int stE = lane >> 5, kqE = (lane & 31) >> 3, jE = lane & 7;
        short hh, ll;
        cvtSplit((e / fmaxf(sqrtf(ss), 1e-12f)) * 5.0f * Hn, hh, ll);
        wsAh[aIdx(sg, stE, kqE, m16, jE)] = hh;
        wsAl[aIdx(sg, stE, kqE, m16, jE)] = ll;
        cvtSplit(5.0f * sv, hh, ll);
        wsAh[aIdx(sg, 2 + stE, kqE, m16, jE)] = hh;
        wsAl[aIdx(sg, 2 + stE, kqE, m16, jE)] = ll;
        float v = sv; int idx = lane;
#pragma unroll
        for (int off = 1; off < 64; off <<= 1) {
            const float ov = __shfl_xor(v, off, 64);
            const int   oi = __shfl_xor(idx, off, 64);
            if (ov > v || (ov == v && oi < idx)) { v = ov; idx = oi; }
        }
        float gd = 0.f;
#pragma unroll
        for (int j = 0; j < 4; ++j) {
            const int d = lane + (j << 6);
            gd = fmaf(h0[(size_t)r * D_ + d], W_gate[d], gd);
        }
        gd = waveSum(gd);
        if (lane == 0) {
            wsMode[row] = idx;
            const float raw = 1.f / (1.f + expf(-(gd + b_gate[0])));
            wsGw[row] = raw * ctx[row];
        }
    }

    // block-wide norms; h' written packed
    const int stH = 4 + (tid >> 5), kqH = (tid & 31) >> 3, jH = tid & 7;
#pragma unroll
    for (int g = 0; g < 2; ++g) {
        float ha4[4], va[4], vp[4];
#pragma unroll
        for (int q = 0; q < 4; ++q) {
            const int r = (g << 2) + q;
            ha4[q] = h0[(size_t)r * D_ + tid] + 0.3f * vh[r];
            va[q] = ha4[q] * ha4[q];
            vp[q] = pr[(g << 2) + q] * pr[(g << 2) + q];
        }
        blockSum4(va, scr4);
        blockSum4(vp, scr4);
#pragma unroll
        for (int q = 0; q < 4; ++q) {
            const int r = (g << 2) + q;
            const int row = rowBase + r;
            const int sg = row >> 4, m16 = row & 15;
            short hh, ll;
            cvtSplit((ha4[q] / fmaxf(sqrtf(va[q]), 1e-12f)) * 2.5f, hh, ll);
            wsAh[aIdx(sg, stH, kqH, m16, jH)] = hh;
            wsAl[aIdx(sg, stH, kqH, m16, jH)] = ll;
            wsProbe[(size_t)row * D_ + tid] = pr[r] / fmaxf(sqrtf(vp[q]), 1e-12f);
        }
    }
}

// Kernel A: all-pairs sims via split-bf16 MFMA, fragment-packed operands.
// 512 blocks = b(4) x rowgroup32(32) x colquarter(4); 8 waves x 2 A-tiles x
// 2 col-tiles -> each B fragment pair feeds 6 MFMAs (msg steps).
__global__ __launch_bounds__(512) void sims_kernel(
    const short* __restrict__ msgH, const short* __restrict__ msgL,   // packed
    const short* __restrict__ scnH, const short* __restrict__ scnL,   // packed
    const short* __restrict__ wsAh, const short* __restrict__ wsAl,   // packed
    const int* __restrict__ wsMode,
    const void* __restrict__ maskP,
    const int* __restrict__ maskFlag,
    float* __restrict__ zgO,            // [4096][1024]
    float* __restrict__ zlO)            // [4096][1024]
{
    const int bid = blockIdx.x;          // 512 blocks
    const int b = bid >> 7;
    const int rem = bid & 127;
    const int rg = rem >> 2;             // 32-row group (0..31)
    const int qt = rem & 3;              // column quarter (256 cols)
    const int sBase = rg << 5;           // 32 rows
    const int rowBase = (b << 10) + sBase;
    const int tid = threadIdx.x;
    const int w = tid >> 6, l = tid & 63;
    const int m16 = l & 15, kq = l >> 4;
    const int l8 = l << 3;

    const int sgA = (b << 6) + (rg << 1);       // first 16-row group in A pack
    const short* Ah0 = wsAh + (size_t)sgA * (ASTEPS * 512) + l8;
    const short* Al0 = wsAl + (size_t)sgA * (ASTEPS * 512) + l8;
    const short* Ah1 = Ah0 + ASTEPS * 512;
    const short* Al1 = Al0 + ASTEPS * 512;

    f32x4 accG[2][2], accL8[2][2];
#pragma unroll
    for (int mA = 0; mA < 2; ++mA)
#pragma unroll
        for (int ct = 0; ct < 2; ++ct) {
            accG[mA][ct] = (f32x4){0.f, 0.f, 0.f, 0.f};
            accL8[mA][ct] = (f32x4){0.f, 0.f, 0.f, 0.f};
        }

    // ---- scn k-steps (2): e' -> accG, s' -> accL, shared B loads ----
#pragma unroll
    for (int st = 0; st < 2; ++st) {
        const bf16x8 aeh0 = *(const bf16x8*)(Ah0 + (st << 9));
        const bf16x8 ael0 = *(const bf16x8*)(Al0 + (st << 9));
        const bf16x8 ash0 = *(const bf16x8*)(Ah0 + ((2 + st) << 9));
        const bf16x8 asl0 = *(const bf16x8*)(Al0 + ((2 + st) << 9));
        const bf16x8 aeh1 = *(const bf16x8*)(Ah1 + (st << 9));
        const bf16x8 ael1 = *(const bf16x8*)(Al1 + (st << 9));
        const bf16x8 ash1 = *(const bf16x8*)(Ah1 + ((2 + st) << 9));
        const bf16x8 asl1 = *(const bf16x8*)(Al1 + ((2 + st) << 9));
#pragma unroll
        for (int ct = 0; ct < 2; ++ct) {
            const int mtile = (qt << 4) + (w << 1) + ct;
            const size_t bo = (size_t)b * SCNP_B + (((size_t)mtile * 2 + st) << 9) + l8;
            const bf16x8 bh = *(const bf16x8*)(scnH + bo);
            const bf16x8 bl = *(const bf16x8*)(scnL + bo);
            accG[0][ct] = __builtin_amdgcn_mfma_f32_16x16x32_bf16(aeh0, bh, accG[0][ct], 0, 0, 0);
            accG[0][ct] = __builtin_amdgcn_mfma_f32_16x16x32_bf16(aeh0, bl, accG[0][ct], 0, 0, 0);
            accG[0][ct] = __builtin_amdgcn_mfma_f32_16x16x32_bf16(ael0, bh, accG[0][ct], 0, 0, 0);
            accL8[0][ct] = __builtin_amdgcn_mfma_f32_16x16x32_bf16(ash0, bh, accL8[0][ct], 0, 0, 0);
            accL8[0][ct] = __builtin_amdgcn_mfma_f32_16x16x32_bf16(ash0, bl, accL8[0][ct], 0, 0, 0);
            accL8[0][ct] = __builtin_amdgcn_mfma_f32_16x16x32_bf16(asl0, bh, accL8[0][ct], 0, 0, 0);
            accG[1][ct] = __builtin_amdgcn_mfma_f32_16x16x32_bf16(aeh1, bh, accG[1][ct], 0, 0, 0);
            accG[1][ct] = __builtin_amdgcn_mfma_f32_16x16x32_bf16(aeh1, bl, accG[1][ct], 0, 0, 0);
            accG[1][ct] = __builtin_amdgcn_mfma_f32_16x16x32_bf16(ael1, bh, accG[1][ct], 0, 0, 0);
            accL8[1][ct] = __builtin_amdgcn_mfma_f32_16x16x32_bf16(ash1, bh, accL8[1][ct], 0, 0, 0);
            accL8[1][ct] = __builtin_amdgcn_mfma_f32_16x16x32_bf16(ash1, bl, accL8[1][ct], 0, 0, 0);
            accL8[1][ct] = __builtin_amdgcn_mfma_f32_16x16x32_bf16(asl1, bh, accL8[1][ct], 0, 0, 0);
        }
    }
    // ---- msg k-steps (8): h' -> accG ----
#pragma unroll
    for (int st = 0; st < 8; ++st) {
        const bf16x8 ah0 = *(const bf16x8*)(Ah0 + ((4 + st) << 9));
        const bf16x8 al0 = *(const bf16x8*)(Al0 + ((4 + st) << 9));
        const bf16x8 ah1 = *(const bf16x8*)(Ah1 + ((4 + st) << 9));
        const bf16x8 al1 = *(const bf16x8*)(Al1 + ((4 + st) << 9));
#pragma unroll
        for (int ct = 0; ct < 2; ++ct) {
            const int mtile = (qt << 4) + (w << 1) + ct;
            const size_t bo = (size_t)b * MSGP_B + (((size_t)mtile * 8 + st) << 9) + l8;
            const bf16x8 bh = *(const bf16x8*)(msgH + bo);
            const bf16x8 bl = *(const bf16x8*)(msgL + bo);
            accG[0][ct] = __builtin_amdgcn_mfma_f32_16x16x32_bf16(ah0, bh, accG[0][ct], 0, 0, 0);
            accG[0][ct] = __builtin_amdgcn_mfma_f32_16x16x32_bf16(ah0, bl, accG[0][ct], 0, 0, 0);
            accG[0][ct] = __builtin_amdgcn_mfma_f32_16x16x32_bf16(al0, bh, accG[0][ct], 0, 0, 0);
            accG[1][ct] = __builtin_amdgcn_mfma_f32_16x16x32_bf16(ah1, bh, accG[1][ct], 0, 0, 0);
            accG[1][ct] = __builtin_amdgcn_mfma_f32_16x16x32_bf16(ah1, bl, accG[1][ct], 0, 0, 0);
            accG[1][ct] = __builtin_amdgcn_mfma_f32_16x16x32_bf16(al1, bh, accG[1][ct], 0, 0, 0);
        }
    }

    // ---- tail: mask + mode; write zg + raw zl ----
    const int tBase = (qt << 8) + (w << 5);
    const int mf = *maskFlag;
#pragma unroll
    for (int mA = 0; mA < 2; ++mA) {
        const int4 mS4 = *(const int4*)(wsMode + rowBase + (mA << 4) + (kq << 2));
        const int mSq[4] = {mS4.x, mS4.y, mS4.z, mS4.w};
#pragma unroll
        for (int ct = 0; ct < 2; ++ct) {
            const int t = tBase + (ct << 4) + m16;
            const int mdt = wsMode[(b << 10) + t];
#pragma unroll
            for (int q = 0; q < 4; ++q) {
                const int r = (mA << 4) + (kq << 2) + q;
                const int s_r = sBase + r;
                const size_t mb = (size_t)s_r * SEQ_ + t;
                int blk;
                if (mf == 1)      blk = ((const unsigned char*)maskP)[mb] != 0;
                else if (mf == 2) blk = ((const float*)maskP)[mb] != 0.f;
                else              blk = ((const int*)maskP)[mb] != 0;
                if (s_r == t) blk = 1;
                zgO[(size_t)(rowBase + r) * SEQ_ + t] = blk ? NEG_ : accG[mA][ct][q];
                const int sm = (!blk) && (mdt == mSq[q]);
                zlO[(size_t)(rowBase + r) * SEQ_ + t] =
                    blk ? BLKNEG_ : (sm ? accL8[mA][ct][q] : 0.0f);
            }
        }
    }
}

// Kernel B: 4 waves per block, wave owns one row (mirror-balanced).
// hasNb derived in-row from raw zl; JOINT tau iteration for geo+local.
// Sparse combined gather; dense rows deferred to cleanup via queue.
__global__ __launch_bounds__(256) void route4_kernel(
    const float* __restrict__ messages,
    const float* __restrict__ scn,
    const int* __restrict__ x_ids,
    const int* __restrict__ static_nb,
    const float* __restrict__ W_e1,
    const float* __restrict__ b_e1,
    const float* __restrict__ W_e2,
    const float* __restrict__ b_e2,
    const float* __restrict__ wsProbe,
    const float* __restrict__ wsGw,
    const float* __restrict__ zgA,
    const float* __restrict__ zlA,
    float* __restrict__ wq,          // [MAXQ][1024] dense weights
    int* __restrict__ qRows,
    int* __restrict__ qMeta,         // [0]=tail, [1]=consume
    float* __restrict__ out)
{
    __shared__ uint2 lst[4][256];
    __shared__ float ewLds[4][8];
    __shared__ int   mlist[4][64];

    const int jb = blockIdx.x;               // 0..1023
    const int tid = threadIdx.x;
    const int wid = tid >> 6, lane = tid & 63;
    const int base = jb << 1;
    const int row = (wid == 0) ? base
                  : (wid == 1) ? base + 1
                  : (wid == 2) ? 4094 - base
                               : 4095 - base;
    const int b = row >> 10, s_r = row & 1023;
    const float* msgB = messages + (size_t)b * SEQ_ * D_;
    const float* scnB = scn + (size_t)b * SEQ_ * NS_;
    const unsigned long long ltmask = (1ull << lane) - 1ull;
    const int d4 = lane << 2;

    float zrG[16], zrL[16];
    {
        const float4* zgp = (const float4*)(zgA + (size_t)row * SEQ_ + (lane << 4));
        const float4* zlp = (const float4*)(zlA + (size_t)row * SEQ_ + (lane << 4));
#pragma unroll
        for (int q = 0; q < 4; ++q) {
            const float4 g4 = zgp[q];
            zrG[q * 4 + 0] = g4.x; zrG[q * 4 + 1] = g4.y;
            zrG[q * 4 + 2] = g4.z; zrG[q * 4 + 3] = g4.w;
            const float4 l4 = zlp[q];
            zrL[q * 4 + 0] = l4.x; zrL[q * 4 + 1] = l4.y;
            zrL[q * 4 + 2] = l4.z; zrL[q * 4 + 3] = l4.w;
        }
    }

    // ----- static neighbor-vocab scan: ONE ballot per 64-block (kmask) -----
    const int q = x_ids[row];
    int nb[KNB_];
#pragma unroll
    for (int k = 0; k < KNB_; ++k) nb[k] = static_nb[(size_t)q * KNB_ + k];
    const float ss_l = scnB[(size_t)s_r * NS_ + lane];
    float simk[KNB_] = {};
    unsigned matchedMask = 0;
    int mcW = 0;
    const int* xb = x_ids + (b << 10);
    for (int pb = 0; pb <= s_r; pb += 64) {
        const int p = pb + lane;
        const int id = (p <= s_r) ? xb[p] : -2147483647;
        unsigned kmask = 0;
#pragma unroll
        for (int k = 0; k < KNB_; ++k) kmask |= (id == nb[k]) ? (1u << k) : 0u;
        unsigned long long mb = __ballot(kmask != 0u);
        while (mb) {
            const int src = __ffsll(mb) - 1; mb &= mb - 1;
            const unsigned kms = (unsigned)__shfl((int)kmask, src, 64);
            const int pp = pb + src;
            float pv = scnB[(size_t)pp * NS_ + lane] * ss_l;
            pv = waveSum(pv);
            matchedMask |= kms;
#pragma unroll
            for (int k = 0; k < KNB_; ++k) {
                if ((kms >> k) & 1u) {
                    simk[k] += pv;
                    if (mcW < 64) { if (lane == 0) mlist[wid][mcW] = (pp << 3) | k; ++mcW; }
                }
            }
        }
    }
    const int kk = lane >> 3, jjn = lane & 7;
    float sv = simk[0];
#pragma unroll
    for (int k = 1; k < KNB_; ++k) sv = (kk == k) ? simk[k] : sv;
    const float xx = sv * W_e1[jjn] + b_e1[jjn];
    float eo = 0.5f * xx * (1.f + erff(xx * 0.70710678118654752f)) * W_e2[jjn];
    eo += __shfl_xor(eo, 1, 64); eo += __shfl_xor(eo, 2, 64); eo += __shfl_xor(eo, 4, 64);
    eo += b_e2[0];
    float m2 = eo;
    m2 = fmaxf(m2, __shfl_xor(m2, 8, 64));
    m2 = fmaxf(m2, __shfl_xor(m2, 16, 64));
    m2 = fmaxf(m2, __shfl_xor(m2, 32, 64));
    const float exv = expf(eo - m2);
    float smv = exv;
    smv += __shfl_xor(smv, 8, 64); smv += __shfl_xor(smv, 16, 64); smv += __shfl_xor(smv, 32, 64);
    if ((lane & 7) == 0) ewLds[wid][kk] = exv / smv;

    const float cov = (float)__popc(matchedMask) * 0.125f;
    const float gw = wsGw[row];
    const float coefG = gw;
    const float coefL = (1.f - gw) * (1.f - cov);
    const float coefS = (1.f - gw) * cov;

    // ----- local hasNb derived from raw zl -----
    int fl = 0;
#pragma unroll
    for (int j = 0; j < 16; ++j) fl |= (zrL[j] != 0.0f && zrL[j] > -40000.f);
    const int hasNb = __any(fl);
    if (!hasNb) {
#pragma unroll
        for (int j = 0; j < 16; ++j) {
            const int t = (lane << 4) + j;
            zrL[j] = (zrL[j] <= -40000.f) ? BLKNEG_ : -0.05f * fabsf((float)(s_r - t));
        }
    }

    // ----- JOINT sparsemax tau (geo + local lockstep, batched butterflies) -----
    float mxG = zrG[0], mxL = zrL[0];
#pragma unroll
    for (int j = 1; j < 16; ++j) { mxG = fmaxf(mxG, zrG[j]); mxL = fmaxf(mxL, zrL[j]); }
#pragma unroll
    for (int off = 32; off; off >>= 1) {
        mxG = fmaxf(mxG, __shfl_xor(mxG, off, 64));
        mxL = fmaxf(mxL, __shfl_xor(mxL, off, 64));
    }
    float tauG = mxG - 1.f, tauL = mxL - 1.f;
    for (int it = 0; it < 32; ++it) {
        float sG = 0.f, cG = 0.f, sL = 0.f, cL = 0.f;
#pragma unroll
        for (int j = 0; j < 16; ++j) {
            if (zrG[j] > tauG) { sG += zrG[j]; cG += 1.f; }
            if (zrL[j] > tauL) { sL += zrL[j]; cL += 1.f; }
        }
#pragma unroll
        for (int off = 32; off; off >>= 1) {
            sG += __shfl_xor(sG, off, 64); cG += __shfl_xor(cG, off, 64);
            sL += __shfl_xor(sL, off, 64); cL += __shfl_xor(cL, off, 64);
        }
        const float nG = (sG - 1.f) / fmaxf(cG, 1.f);
        const float nL = (sL - 1.f) / fmaxf(cL, 1.f);
        if (nG == tauG && nL == tauL) break;
        tauG = nG; tauL = nL;
    }

    int supG = 0, supL = 0;
#pragma unroll
    for (int j = 0; j < 16; ++j) {
        supG += __popcll(__ballot(zrG[j] > tauG));
        supL += __popcll(__ballot(zrL[j] > tauL));
    }
    const bool gDense = supG > 96;
    const bool lDense = supL > 96;

    int cnt = 0;
    if (!gDense) {
#pragma unroll
        for (int j = 0; j < 16; ++j) {
            const float wv = zrG[j] - tauG;
            const bool take = wv > 0.f;
            const unsigned long long m = __ballot(take);
            if (take) {
                const int pos = cnt + __popcll(m & ltmask);
                lst[wid][pos] = make_uint2((unsigned)((lane << 4) + j),
                                           __float_as_uint(coefG * wv));
            }
            cnt += __popcll(m);
        }
    }
    if (!lDense) {
#pragma unroll
        for (int j = 0; j < 16; ++j) {
            const float wv = zrL[j] - tauL;
            const bool take = wv > 0.f;
            const unsigned long long m = __ballot(take);
            if (take) {
                const int pos = cnt + __popcll(m & ltmask);
                lst[wid][pos] = make_uint2((unsigned)((lane << 4) + j),
                                           __float_as_uint(coefL * wv));
            }
            cnt += __popcll(m);
        }
    }
    const int nm = (mcW < 64) ? mcW : 64;
    for (int i = lane; i < nm; i += 64) {
        const int ee = mlist[wid][i];
        lst[wid][cnt + i] = make_uint2((unsigned)(ee >> 3),
                                       __float_as_uint(coefS * ewLds[wid][ee & 7]));
    }
    cnt += nm;

    float ox = 0.f, oy = 0.f, oz2 = 0.f, ow = 0.f;
    int i = 0;
    for (; i + 4 <= cnt; i += 4) {
        const uint2 e0 = lst[wid][i + 0];
        const uint2 e1 = lst[wid][i + 1];
        const uint2 e2 = lst[wid][i + 2];
        const uint2 e3 = lst[wid][i + 3];
        const float4 m0 = *(const float4*)(msgB + (size_t)e0.x * D_ + d4);
        const float4 m1 = *(const float4*)(msgB + (size_t)e1.x * D_ + d4);
        const float4 m2b = *(const float4*)(msgB + (size_t)e2.x * D_ + d4);
        const float4 m3 = *(const float4*)(msgB + (size_t)e3.x * D_ + d4);
        const float w0 = __uint_as_float(e0.y), w1 = __uint_as_float(e1.y);
        const float w2 = __uint_as_float(e2.y), w3 = __uint_as_float(e3.y);
        ox = fmaf(w0, m0.x, fmaf(w1, m1.x, fmaf(w2, m2b.x, fmaf(w3, m3.x, ox))));
        oy = fmaf(w0, m0.y, fmaf(w1, m1.y, fmaf(w2, m2b.y, fmaf(w3, m3.y, oy))));
        oz2 = fmaf(w0, m0.z, fmaf(w1, m1.z, fmaf(w2, m2b.z, fmaf(w3, m3.z, oz2))));
        ow = fmaf(w0, m0.w, fmaf(w1, m1.w, fmaf(w2, m2b.w, fmaf(w3, m3.w, ow))));
    }
    for (; i < cnt; ++i) {
        const uint2 e0 = lst[wid][i];
        const float w0 = __uint_as_float(e0.y);
        const float4 m0 = *(const float4*)(msgB + (size_t)e0.x * D_ + d4);
        ox = fmaf(w0, m0.x, ox); oy = fmaf(w0, m0.y, oy);
        oz2 = fmaf(w0, m0.z, oz2); ow = fmaf(w0, m0.w, ow);
    }

    int slot = -1;
    if (gDense || lDense) {
        int s0 = 0;
        if (lane == 0) s0 = atomicAdd(&qMeta[0], 1);
        slot = __shfl(s0, 0, 64);
    }
    if (slot >= 0 && slot < MAXQ_) {
#pragma unroll
        for (int qd = 0; qd < 4; ++qd) {
            float4 w4;
            float* wv4 = &w4.x;
#pragma unroll
            for (int u = 0; u < 4; ++u) {
                const int j = qd * 4 + u;
                float w = 0.f;
                if (gDense) w += coefG * fmaxf(zrG[j] - tauG, 0.f);
                if (lDense) w += coefL * fmaxf(zrL[j] - tauL, 0.f);
                wv4[u] = w;
            }
            *(float4*)(wq + (size_t)slot * SEQ_ + (lane << 4) + qd * 4) = w4;
        }
        if (lane == 0) qRows[slot] = row;
        *(float4*)(out + (size_t)row * D_ + d4) = make_float4(ox, oy, oz2, ow);
        return;
    }
    if (slot >= MAXQ_) {
#pragma unroll
        for (int j = 0; j < 16; ++j) {
            float wv = 0.f;
            if (gDense) wv += coefG * fmaxf(zrG[j] - tauG, 0.f);
            if (lDense) wv += coefL * fmaxf(zrL[j] - tauL, 0.f);
            unsigned long long m = __ballot(wv > 0.f);
            while (m) {
                const int s0 = __ffsll(m) - 1; m &= m - 1;
                const float w0 = __shfl(wv, s0, 64);
                const float4 m4 = *(const float4*)(msgB + (size_t)((s0 << 4) + j) * D_ + d4);
                ox = fmaf(w0, m4.x, ox); oy = fmaf(w0, m4.y, oy);
                oz2 = fmaf(w0, m4.z, oz2); ow = fmaf(w0, m4.w, ow);
            }
        }
    }

    float ssq = ox * ox + oy * oy + oz2 * oz2 + ow * ow;
    ssq = waveSum(ssq);
    const float nrm = fmaxf(sqrtf(ssq), 1e-12f);
    const float4 pr = *(const float4*)(wsProbe + (size_t)row * D_ + d4);
    float dp = (ox * pr.x + oy * pr.y + oz2 * pr.z + ow * pr.w) / nrm;
    dp = waveSum(dp);
    const float rel = 1.f / (1.f + expf(-dp));
    *(float4*)(out + (size_t)row * D_ + d4) =
        make_float4(ox * rel, oy * rel, oz2 * rel, ow * rel);
}

// Kernel C: drain dense-row queue.
__global__ __launch_bounds__(256) void cleanup_kernel(
    const float* __restrict__ messages,
    const float* __restrict__ wsProbe,
    const float* __restrict__ wq,
    const int* __restrict__ qRows,
    int* __restrict__ qMeta,
    float* __restrict__ out)
{
    __shared__ float wsh[SEQ_];
    __shared__ float scr[4];
    __shared__ int idxSh;
    const int tid = threadIdx.x;
    const int nq = (qMeta[0] < MAXQ_) ? qMeta[0] : MAXQ_;
    for (;;) {
        __syncthreads();
        if (tid == 0) idxSh = atomicAdd(&qMeta[1], 1);
        __syncthreads();
        const int idx = idxSh;
        if (idx >= nq) break;
        const int row = qRows[idx];
        const int b = row >> 10;
        const float* msgB = messages + (size_t)b * SEQ_ * D_;
        for (int i = tid; i < SEQ_; i += 256)
            wsh[i] = wq[(size_t)idx * SEQ_ + i];
        __syncthreads();
        float acc = out[(size_t)row * D_ + tid];
        for (int t = 0; t < SEQ_; t += 4) {
            acc = fmaf(wsh[t + 0], msgB[(size_t)(t + 0) * D_ + tid],
                  fmaf(wsh[t + 1], msgB[(size_t)(t + 1) * D_ + tid],
                  fmaf(wsh[t + 2], msgB[(size_t)(t + 2) * D_ + tid],
                  fmaf(wsh[t + 3], msgB[(size_t)(t + 3) * D_ + tid], acc))));
        }
        const float ssq = blockSum(acc * acc, scr);
        const float nrm = fmaxf(sqrtf(ssq), 1e-12f);
        const float dp = blockSum((acc / nrm) * wsProbe[(size_t)row * D_ + tid], scr);
        const float rel = 1.f / (1.f + expf(-dp));
        out[(size_t)row * D_ + tid] = acc * rel;
    }
}

extern "C" void kernel_launch(void* const* d_in, const int* in_sizes, int n_in,
                              void* d_out, int out_size, void* d_ws, size_t ws_size,
                              hipStream_t stream) {
    const float* messages  = (const float*)d_in[0];
    const float* hidden    = (const float*)d_in[1];
    const int*   x_ids     = (const int*)d_in[2];
    const float* scn       = (const float*)d_in[3];
    const void*  mask      = d_in[4];
    const int*   static_nb = (const int*)d_in[5];
    const float* gvel      = (const float*)d_in[6];
    const float* ctx       = (const float*)d_in[7];
    const float* ent       = (const float*)d_in[8];
    const float* W_vel     = (const float*)d_in[9];
    const float* W_e1      = (const float*)d_in[10];
    const float* b_e1      = (const float*)d_in[11];
    const float* W_e2      = (const float*)d_in[12];
    const float* b_e2      = (const float*)d_in[13];
    const float* W_probe   = (const float*)d_in[14];
    const float* W_gate    = (const float*)d_in[15];
    const float* b_gate    = (const float*)d_in[16];
    float* out = (float*)d_out;
    (void)in_sizes; (void)n_in; (void)out_size; (void)ws_size;

    char* ws = (char*)d_ws;
    size_t o = 0;
    int* flag      = (int*)(ws + o);   o += 256;
    short* wsAh    = (short*)(ws + o); o += (size_t)B_ * SEQ_ * 384 * 2;   // 3.1 MB packed
    short* wsAl    = (short*)(ws + o); o += (size_t)B_ * SEQ_ * 384 * 2;
    float* wsProbe = (float*)(ws + o); o += (size_t)B_ * SEQ_ * D_ * 4;
    int* wsMode    = (int*)(ws + o);   o += (size_t)B_ * SEQ_ * 4;
    float* wsGw    = (float*)(ws + o); o += (size_t)B_ * SEQ_ * 4;
    short* msgH    = (short*)(ws + o); o += (size_t)B_ * MSGP_B * 2;       // 2 MB packed
    short* msgL    = (short*)(ws + o); o += (size_t)B_ * MSGP_B * 2;
    short* scnH    = (short*)(ws + o); o += (size_t)B_ * SCNP_B * 2;
    short* scnL    = (short*)(ws + o); o += (size_t)B_ * SCNP_B * 2;
    float* zgW     = (float*)(ws + o); o += (size_t)B_ * SEQ_ * SEQ_ * 4;
    float* zlW     = (float*)(ws + o); o += (size_t)B_ * SEQ_ * SEQ_ * 4;
    int* qMeta     = (int*)(ws + o);   o += 256;
    int* qRows     = (int*)(ws + o);   o += (size_t)MAXQ_ * 4;
    // dense-weight buffer overlays msgH+msgL (dead after sims): 4 MB
    float* wq      = (float*)msgH;

    setup_kernel<<<dim3(833), dim3(256), 0, stream>>>(
        messages, scn, hidden, gvel, ctx, ent, W_probe, W_vel, W_gate, b_gate,
        msgH, msgL, scnH, scnL, (const unsigned int*)mask, flag, qMeta,
        wsAh, wsAl, wsProbe, wsMode, wsGw);
    sims_kernel<<<dim3(512), dim3(512), 0, stream>>>(
        msgH, msgL, scnH, scnL, wsAh, wsAl, wsMode, mask, flag, zgW, zlW);
    route4_kernel<<<dim3(B_ * SEQ_ / 4), dim3(256), 0, stream>>>(
        messages, scn, x_ids, static_nb, W_e1, b_e1, W_e2, b_e2,
        wsProbe, wsGw, zgW, zlW, wq, qRows, qMeta, out);
    cleanup_kernel<<<dim3(64), dim3(256), 0, stream>>>(
        messages, wsProbe, wq, qRows, qMeta, out);
}

// Round 16
// 105.282 us; speedup vs baseline: 2.3388x; 1.0006x over previous
//
#include <hip/hip_runtime.h>
#include <math.h>

#define D_ 256
#define NS_ 64
#define KNB_ 8
#define SEQ_ 1024
#define B_ 4
#define MAXQ_ 1024
#define NEG_ (-10000.0f)
#define BLKNEG_ (-50000.0f)

// packed sizes (shorts)
#define MSGP_B 262144      // 64 tiles * 8 ksteps * 64 lanes * 8
#define SCNP_B 65536       // 64 tiles * 2 ksteps * 64 lanes * 8
#define ASTEPS 12          // e'(2) | s'(2) | h'(8)

typedef short bf16x8 __attribute__((ext_vector_type(8)));
typedef float f32x4 __attribute__((ext_vector_type(4)));

__device__ __forceinline__ float waveSum(float v) {
#pragma unroll
    for (int off = 32; off; off >>= 1) v += __shfl_xor(v, off, 64);
    return v;
}

__device__ __forceinline__ float blockSum(float v, float* scr) {
    const int tid = threadIdx.x;
    const int wid = tid >> 6, lane = tid & 63;
    v = waveSum(v);
    __syncthreads();
    if (lane == 0) scr[wid] = v;
    __syncthreads();
    return scr[0] + scr[1] + scr[2] + scr[3];
}

__device__ __forceinline__ void blockSum4(float v[4], float (*scr4)[4]) {
    const int tid = threadIdx.x;
    const int wid = tid >> 6, lane = tid & 63;
#pragma unroll
    for (int off = 32; off; off >>= 1) {
#pragma unroll
        for (int q = 0; q < 4; ++q) v[q] += __shfl_xor(v[q], off, 64);
    }
    __syncthreads();
    if (lane == 0) {
#pragma unroll
        for (int q = 0; q < 4; ++q) scr4[wid][q] = v[q];
    }
    __syncthreads();
#pragma unroll
    for (int q = 0; q < 4; ++q)
        v[q] = scr4[0][q] + scr4[1][q] + scr4[2][q] + scr4[3][q];
}

// split fp32 -> bf16 hi + bf16 lo (truncation; a ~= hi + lo, err ~2^-16 rel)
__device__ __forceinline__ void cvtSplit(float a, short& h, short& l) {
    const unsigned ab = __float_as_uint(a);
    h = (short)(ab >> 16);
    const float hf = __uint_as_float(ab & 0xFFFF0000u);
    l = (short)(__float_as_uint(a - hf) >> 16);
}

// A-pack index: ((sg*12 + st)*64 + kq*16 + m16)*8 + j
__device__ __forceinline__ size_t aIdx(int sg, int st, int kq, int m16, int j) {
    return ((((size_t)sg * ASTEPS + st) << 6) + (kq << 4) + m16) * 8 + j;
}

// Fused setup: fragment-major bf16-split packing + mask detect + prep.
// blocks [0,256): messages -> msgH/msgL packed (b=bid>>6, T=bid&63)
// [256,320): scn -> scnH/scnL packed (4 tiles per block)
// 320: mask detect + counter zero; [321,833): prep (8 rows each).
__global__ __launch_bounds__(256) void setup_kernel(
    const float* __restrict__ messages, const float* __restrict__ scn,
    const float* __restrict__ hidden, const float* __restrict__ gvel,
    const float* __restrict__ ctx, const float* __restrict__ ent,
    const float* __restrict__ W_probe, const float* __restrict__ W_vel,
    const float* __restrict__ W_gate, const float* __restrict__ b_gate,
    short* __restrict__ msgH, short* __restrict__ msgL,
    short* __restrict__ scnH, short* __restrict__ scnL,
    const unsigned int* __restrict__ maskW, int* __restrict__ flag,
    int* __restrict__ qMeta,
    short* __restrict__ wsAh, short* __restrict__ wsAl,
    float* __restrict__ wsProbe,
    int* __restrict__ wsMode, float* __restrict__ wsGw)
{
    const int bid = blockIdx.x;
    const int tid = threadIdx.x;

    if (bid < 256) {   // messages -> packed fragments
        const int b = bid >> 6, T = bid & 63;
        const float* src = messages + (size_t)b * SEQ_ * D_;
        short* dh = msgH + (size_t)b * MSGP_B;
        short* dl = msgL + (size_t)b * MSGP_B;
#pragma unroll
        for (int it = 0; it < 2; ++it) {
            const int g = (it << 8) + tid;         // 0..511
            const int st = g >> 6, kq = (g >> 4) & 3, m16 = g & 15;
            const int t = (T << 4) + m16;
            const int k0 = (st << 5) + (kq << 3);
            const float4 v0 = *(const float4*)(src + (size_t)t * D_ + k0);
            const float4 v1 = *(const float4*)(src + (size_t)t * D_ + k0 + 4);
            short h[8], l[8];
            cvtSplit(v0.x, h[0], l[0]); cvtSplit(v0.y, h[1], l[1]);
            cvtSplit(v0.z, h[2], l[2]); cvtSplit(v0.w, h[3], l[3]);
            cvtSplit(v1.x, h[4], l[4]); cvtSplit(v1.y, h[5], l[5]);
            cvtSplit(v1.z, h[6], l[6]); cvtSplit(v1.w, h[7], l[7]);
            const size_t o = (((size_t)T * 8 + st) << 9) + (size_t)((kq << 4) + m16) * 8;
            *(short4*)(dh + o) = make_short4(h[0], h[1], h[2], h[3]);
            *(short4*)(dh + o + 4) = make_short4(h[4], h[5], h[6], h[7]);
            *(short4*)(dl + o) = make_short4(l[0], l[1], l[2], l[3]);
            *(short4*)(dl + o + 4) = make_short4(l[4], l[5], l[6], l[7]);
        }
        return;
    }

    if (bid < 320) {   // scn -> packed fragments, 4 tiles per block
        const int i = bid - 256;
        const int b = i >> 4;
        const float* src = scn + (size_t)b * SEQ_ * NS_;
        short* dh = scnH + (size_t)b * SCNP_B;
        short* dl = scnL + (size_t)b * SCNP_B;
#pragma unroll
        for (int tt = 0; tt < 4; ++tt) {
            const int T = ((i & 15) << 2) + tt;
            if (tid < 128) {
                const int st = tid >> 6, kq = (tid >> 4) & 3, m16 = tid & 15;
                const int t = (T << 4) + m16;
                const int k0 = (st << 5) + (kq << 3);
                const float4 v0 = *(const float4*)(src + (size_t)t * NS_ + k0);
                const float4 v1 = *(const float4*)(src + (size_t)t * NS_ + k0 + 4);
                short h[8], l[8];
                cvtSplit(v0.x, h[0], l[0]); cvtSplit(v0.y, h[1], l[1]);
                cvtSplit(v0.z, h[2], l[2]); cvtSplit(v0.w, h[3], l[3]);
                cvtSplit(v1.x, h[4], l[4]); cvtSplit(v1.y, h[5], l[5]);
                cvtSplit(v1.z, h[6], l[6]); cvtSplit(v1.w, h[7], l[7]);
                const size_t o = (((size_t)T * 2 + st) << 9) + (size_t)((kq << 4) + m16) * 8;
                *(short4*)(dh + o) = make_short4(h[0], h[1], h[2], h[3]);
                *(short4*)(dh + o + 4) = make_short4(h[4], h[5], h[6], h[7]);
                *(short4*)(dl + o) = make_short4(l[0], l[1], l[2], l[3]);
                *(short4*)(dl + o + 4) = make_short4(l[4], l[5], l[6], l[7]);
            }
        }
        return;
    }

    if (bid == 320) {
        __shared__ int notI, notF;
        if (tid == 0) { notI = 0; notF = 0; qMeta[0] = 0; qMeta[1] = 0; }
        __syncthreads();
        int ni = 0, nf = 0;
        for (int i = tid; i < 1024; i += 256) {
            const unsigned int w = maskW[i];
            if (w != 0u && w != 1u) ni = 1;
            if (w != 0u && w != 0x3f800000u) nf = 1;
        }
        if (ni) atomicOr(&notI, 1);
        if (nf) atomicOr(&notF, 1);
        __syncthreads();
        if (tid == 0) *flag = (!notI) ? 0 : ((!notF) ? 2 : 1);
        return;
    }

    // ---- prep: 8 rows per block; A written in fragment-major pack ----
    __shared__ float scr4[4][4];
    const int rowBase = (bid - 321) << 3;
    const int wid = tid >> 6, lane = tid & 63;
    const float* h0 = hidden + (size_t)rowBase * D_;

    float vh[8] = {};
    for (int e = 0; e < NS_; e += 4) {
        const float4 wv4 = *(const float4*)(W_vel + (size_t)tid * NS_ + e);  // thread-own row
#pragma unroll
        for (int r = 0; r < 8; ++r) {
            const float4 g4 = *(const float4*)(gvel + (size_t)(rowBase + r) * NS_ + e); // uniform
            vh[r] = fmaf(g4.x, wv4.x, fmaf(g4.y, wv4.y, fmaf(g4.z, wv4.z, fmaf(g4.w, wv4.w, vh[r]))));
        }
    }
    float pr[8] = {};
    for (int e = 0; e < D_; e += 4) {
        const float4 wp4 = *(const float4*)(W_probe + (size_t)tid * D_ + e);  // thread-own row
#pragma unroll
        for (int r = 0; r < 8; ++r) {
            const float4 h4 = *(const float4*)(h0 + (size_t)r * D_ + e);      // uniform
            pr[r] = fmaf(h4.x, wp4.x, fmaf(h4.y, wp4.y, fmaf(h4.z, wp4.z, fmaf(h4.w, wp4.w, pr[r]))));
        }
    }

    // per-wave: wave w handles rows 2w, 2w+1 (endpoint e', s', argmax, gate)
#pragma unroll
    for (int rr = 0; rr < 2; ++rr) {
        const int r = (wid << 1) + rr, row = rowBase + r;
        const int sg = row >> 4, m16 = row & 15;
        const float sv = scn[(size_t)row * NS_ + lane];
        const float gv = gvel[(size_t)row * NS_ + lane];
        const float Hn = ent[row] / 10.373491191781864f;   // log(32000)+1e-8
        const float e = sv + 0.4f * gv;
        const float ss = waveSum(e * e);
        const int stE = lane >> 5, kqE = (lane & 31) >> 3, jE = lane & 7;
        short hh, ll;
        cvtSplit((e / fmaxf(sqrtf(ss), 1e-12f)) * 5.0f * Hn, hh, ll);
        wsAh[aIdx(sg, stE, kqE, m16, jE)] = hh;
        wsAl[aIdx(sg, stE, kqE, m16, jE)] = ll;
        cvtSplit(5.0f * sv, hh, ll);
        wsAh[aIdx(sg, 2 + stE, kqE, m16, jE)] = hh;
        wsAl[aIdx(sg, 2 + stE, kqE, m16, jE)] = ll;
        float v = sv; int idx = lane;
#pragma unroll
        for (int off = 1; off < 64; off <<= 1) {
            const float ov = __shfl_xor(v, off, 64);
            const int   oi = __shfl_xor(idx, off, 64);
            if (ov > v || (ov == v && oi < idx)) { v = ov; idx = oi; }
        }
        float gd = 0.f;
#pragma unroll
        for (int j = 0; j < 4; ++j) {
            const int d = lane + (j << 6);
            gd = fmaf(h0[(size_t)r * D_ + d], W_gate[d], gd);
        }
        gd = waveSum(gd);
        if (lane == 0) {
            wsMode[row] = idx;
            const float raw = 1.f / (1.f + expf(-(gd + b_gate[0])));
            wsGw[row] = raw * ctx[row];
        }
    }

    // block-wide norms; h' written packed
    const int stH = 4 + (tid >> 5), kqH = (tid & 31) >> 3, jH = tid & 7;
#pragma unroll
    for (int g = 0; g < 2; ++g) {
        float ha4[4], va[4], vp[4];
#pragma unroll
        for (int q = 0; q < 4; ++q) {
            const int r = (g << 2) + q;
            ha4[q] = h0[(size_t)r * D_ + tid] + 0.3f * vh[r];
            va[q] = ha4[q] * ha4[q];
            vp[q] = pr[(g << 2) + q] * pr[(g << 2) + q];
        }
        blockSum4(va, scr4);
        blockSum4(vp, scr4);
#pragma unroll
        for (int q = 0; q < 4; ++q) {
            const int r = (g << 2) + q;
            const int row = rowBase + r;
            const int sg = row >> 4, m16 = row & 15;
            short hh, ll;
            cvtSplit((ha4[q] / fmaxf(sqrtf(va[q]), 1e-12f)) * 2.5f, hh, ll);
            wsAh[aIdx(sg, stH, kqH, m16, jH)] = hh;
            wsAl[aIdx(sg, stH, kqH, m16, jH)] = ll;
            wsProbe[(size_t)row * D_ + tid] = pr[r] / fmaxf(sqrtf(vp[q]), 1e-12f);
        }
    }
}

// Kernel A: all-pairs sims via split-bf16 MFMA, fragment-packed operands.
// 512 blocks = b(4) x rowgroup32(32) x colquarter(4); 8 waves x 2 A-tiles x
// 2 col-tiles.  A fragments (48 KB, shared by all 8 waves) staged in LDS:
// vmem A-traffic 384 KB/block -> 48 KB + DS reads (parallel pipe).
__global__ __launch_bounds__(512) void sims_kernel(
    const short* __restrict__ msgH, const short* __restrict__ msgL,   // packed
    const short* __restrict__ scnH, const short* __restrict__ scnL,   // packed
    const short* __restrict__ wsAh, const short* __restrict__ wsAl,   // packed
    const int* __restrict__ wsMode,
    const void* __restrict__ maskP,
    const int* __restrict__ maskFlag,
    float* __restrict__ zgO,            // [4096][1024]
    float* __restrict__ zlO)            // [4096][1024]
{
    __shared__ short shAh[2][ASTEPS][512];   // 24 KB: [tile][step][lane*8]
    __shared__ short shAl[2][ASTEPS][512];   // 24 KB
    const int bid = blockIdx.x;          // 512 blocks
    const int b = bid >> 7;
    const int rem = bid & 127;
    const int rg = rem >> 2;             // 32-row group (0..31)
    const int qt = rem & 3;              // column quarter (256 cols)
    const int sBase = rg << 5;           // 32 rows
    const int rowBase = (b << 10) + sBase;
    const int tid = threadIdx.x;
    const int w = tid >> 6, l = tid & 63;
    const int m16 = l & 15, kq = l >> 4;
    const int l8 = l << 3;

    const int sgA = (b << 6) + (rg << 1);       // first 16-row group in A pack
    {   // cooperative stage of both A tiles (hi+lo), 16B coalesced
        const short* srcH = wsAh + (size_t)sgA * (ASTEPS * 512);
        const short* srcL = wsAl + (size_t)sgA * (ASTEPS * 512);
        short* dH = &shAh[0][0][0];
        short* dL = &shAl[0][0][0];
#pragma unroll
        for (int i = 0; i < 3; ++i) {
            const int c = (i << 9) + tid;        // 0..1535 chunks of 8 shorts
            *(bf16x8*)(dH + c * 8) = *(const bf16x8*)(srcH + c * 8);
            *(bf16x8*)(dL + c * 8) = *(const bf16x8*)(srcL + c * 8);
        }
    }
    __syncthreads();

    f32x4 accG[2][2], accL8[2][2];
#pragma unroll
    for (int mA = 0; mA < 2; ++mA)
#pragma unroll
        for (int ct = 0; ct < 2; ++ct) {
            accG[mA][ct] = (f32x4){0.f, 0.f, 0.f, 0.f};
            accL8[mA][ct] = (f32x4){0.f, 0.f, 0.f, 0.f};
        }

    // ---- scn k-steps (2): e' -> accG, s' -> accL, shared B loads ----
#pragma unroll
    for (int st = 0; st < 2; ++st) {
        const bf16x8 aeh0 = *(const bf16x8*)(&shAh[0][st][l8]);
        const bf16x8 ael0 = *(const bf16x8*)(&shAl[0][st][l8]);
        const bf16x8 ash0 = *(const bf16x8*)(&shAh[0][2 + st][l8]);
        const bf16x8 asl0 = *(const bf16x8*)(&shAl[0][2 + st][l8]);
        const bf16x8 aeh1 = *(const bf16x8*)(&shAh[1][st][l8]);
        const bf16x8 ael1 = *(const bf16x8*)(&shAl[1][st][l8]);
        const bf16x8 ash1 = *(const bf16x8*)(&shAh[1][2 + st][l8]);
        const bf16x8 asl1 = *(const bf16x8*)(&shAl[1][2 + st][l8]);
#pragma unroll
        for (int ct = 0; ct < 2; ++ct) {
            const int mtile = (qt << 4) + (w << 1) + ct;
            const size_t bo = (size_t)b * SCNP_B + (((size_t)mtile * 2 + st) << 9) + l8;
            const bf16x8 bh = *(const bf16x8*)(scnH + bo);
            const bf16x8 bl = *(const bf16x8*)(scnL + bo);
            accG[0][ct] = __builtin_amdgcn_mfma_f32_16x16x32_bf16(aeh0, bh, accG[0][ct], 0, 0, 0);
            accG[0][ct] = __builtin_amdgcn_mfma_f32_16x16x32_bf16(aeh0, bl, accG[0][ct], 0, 0, 0);
            accG[0][ct] = __builtin_amdgcn_mfma_f32_16x16x32_bf16(ael0, bh, accG[0][ct], 0, 0, 0);
            accL8[0][ct] = __builtin_amdgcn_mfma_f32_16x16x32_bf16(ash0, bh, accL8[0][ct], 0, 0, 0);
            accL8[0][ct] = __builtin_amdgcn_mfma_f32_16x16x32_bf16(ash0, bl, accL8[0][ct], 0, 0, 0);
            accL8[0][ct] = __builtin_amdgcn_mfma_f32_16x16x32_bf16(asl0, bh, accL8[0][ct], 0, 0, 0);
            accG[1][ct] = __builtin_amdgcn_mfma_f32_16x16x32_bf16(aeh1, bh, accG[1][ct], 0, 0, 0);
            accG[1][ct] = __builtin_amdgcn_mfma_f32_16x16x32_bf16(aeh1, bl, accG[1][ct], 0, 0, 0);
            accG[1][ct] = __builtin_amdgcn_mfma_f32_16x16x32_bf16(ael1, bh, accG[1][ct], 0, 0, 0);
            accL8[1][ct] = __builtin_amdgcn_mfma_f32_16x16x32_bf16(ash1, bh, accL8[1][ct], 0, 0, 0);
            accL8[1][ct] = __builtin_amdgcn_mfma_f32_16x16x32_bf16(ash1, bl, accL8[1][ct], 0, 0, 0);
            accL8[1][ct] = __builtin_amdgcn_mfma_f32_16x16x32_bf16(asl1, bh, accL8[1][ct], 0, 0, 0);
        }
    }
    // ---- msg k-steps (8): h' -> accG ----
#pragma unroll
    for (int st = 0; st < 8; ++st) {
        const bf16x8 ah0 = *(const bf16x8*)(&shAh[0][4 + st][l8]);
        const bf16x8 al0 = *(const bf16x8*)(&shAl[0][4 + st][l8]);
        const bf16x8 ah1 = *(const bf16x8*)(&shAh[1][4 + st][l8]);
        const bf16x8 al1 = *(const bf16x8*)(&shAl[1][4 + st][l8]);
#pragma unroll
        for (int ct = 0; ct < 2; ++ct) {
            const int mtile = (qt << 4) + (w << 1) + ct;
            const size_t bo = (size_t)b * MSGP_B + (((size_t)mtile * 8 + st) << 9) + l8;
            const bf16x8 bh = *(const bf16x8*)(msgH + bo);
            const bf16x8 bl = *(const bf16x8*)(msgL + bo);
            accG[0][ct] = __builtin_amdgcn_mfma_f32_16x16x32_bf16(ah0, bh, accG[0][ct], 0, 0, 0);
            accG[0][ct] = __builtin_amdgcn_mfma_f32_16x16x32_bf16(ah0, bl, accG[0][ct], 0, 0, 0);
            accG[0][ct] = __builtin_amdgcn_mfma_f32_16x16x32_bf16(al0, bh, accG[0][ct], 0, 0, 0);
            accG[1][ct] = __builtin_amdgcn_mfma_f32_16x16x32_bf16(ah1, bh, accG[1][ct], 0, 0, 0);
            accG[1][ct] = __builtin_amdgcn_mfma_f32_16x16x32_bf16(ah1, bl, accG[1][ct], 0, 0, 0);
            accG[1][ct] = __builtin_amdgcn_mfma_f32_16x16x32_bf16(al1, bh, accG[1][ct], 0, 0, 0);
        }
    }

    // ---- tail: mask + mode; write zg + raw zl ----
    const int tBase = (qt << 8) + (w << 5);
    const int mf = *maskFlag;
#pragma unroll
    for (int mA = 0; mA < 2; ++mA) {
        const int4 mS4 = *(const int4*)(wsMode + rowBase + (mA << 4) + (kq << 2));
        const int mSq[4] = {mS4.x, mS4.y, mS4.z, mS4.w};
#pragma unroll
        for (int ct = 0; ct < 2; ++ct) {
            const int t = tBase + (ct << 4) + m16;
            const int mdt = wsMode[(b << 10) + t];
#pragma unroll
            for (int q = 0; q < 4; ++q) {
                const int r = (mA << 4) + (kq << 2) + q;
                const int s_r = sBase + r;
                const size_t mb = (size_t)s_r * SEQ_ + t;
                int blk;
                if (mf == 1)      blk = ((const unsigned char*)maskP)[mb] != 0;
                else if (mf == 2) blk = ((const float*)maskP)[mb] != 0.f;
                else              blk = ((const int*)maskP)[mb] != 0;
                if (s_r == t) blk = 1;
                zgO[(size_t)(rowBase + r) * SEQ_ + t] = blk ? NEG_ : accG[mA][ct][q];
                const int sm = (!blk) && (mdt == mSq[q]);
                zlO[(size_t)(rowBase + r) * SEQ_ + t] =
                    blk ? BLKNEG_ : (sm ? accL8[mA][ct][q] : 0.0f);
            }
        }
    }
}

// Kernel B: 4 waves per block, wave owns one row (mirror-balanced).
// hasNb derived in-row from raw zl; JOINT tau iteration for geo+local.
// Sparse combined gather; dense rows deferred to cleanup via queue.
__global__ __launch_bounds__(256) void route4_kernel(
    const float* __restrict__ messages,
    const float* __restrict__ scn,
    const int* __restrict__ x_ids,
    const int* __restrict__ static_nb,
    const float* __restrict__ W_e1,
    const float* __restrict__ b_e1,
    const float* __restrict__ W_e2,
    const float* __restrict__ b_e2,
    const float* __restrict__ wsProbe,
    const float* __restrict__ wsGw,
    const float* __restrict__ zgA,
    const float* __restrict__ zlA,
    float* __restrict__ wq,          // [MAXQ][1024] dense weights
    int* __restrict__ qRows,
    int* __restrict__ qMeta,         // [0]=tail, [1]=consume
    float* __restrict__ out)
{
    __shared__ uint2 lst[4][256];
    __shared__ float ewLds[4][8];
    __shared__ int   mlist[4][64];

    const int jb = blockIdx.x;               // 0..1023
    const int tid = threadIdx.x;
    const int wid = tid >> 6, lane = tid & 63;
    const int base = jb << 1;
    const int row = (wid == 0) ? base
                  : (wid == 1) ? base + 1
                  : (wid == 2) ? 4094 - base
                               : 4095 - base;
    const int b = row >> 10, s_r = row & 1023;
    const float* msgB = messages + (size_t)b * SEQ_ * D_;
    const float* scnB = scn + (size_t)b * SEQ_ * NS_;
    const unsigned long long ltmask = (1ull << lane) - 1ull;
    const int d4 = lane << 2;

    float zrG[16], zrL[16];
    {
        const float4* zgp = (const float4*)(zgA + (size_t)row * SEQ_ + (lane << 4));
        const float4* zlp = (const float4*)(zlA + (size_t)row * SEQ_ + (lane << 4));
#pragma unroll
        for (int q = 0; q < 4; ++q) {
            const float4 g4 = zgp[q];
            zrG[q * 4 + 0] = g4.x; zrG[q * 4 + 1] = g4.y;
            zrG[q * 4 + 2] = g4.z; zrG[q * 4 + 3] = g4.w;
            const float4 l4 = zlp[q];
            zrL[q * 4 + 0] = l4.x; zrL[q * 4 + 1] = l4.y;
            zrL[q * 4 + 2] = l4.z; zrL[q * 4 + 3] = l4.w;
        }
    }

    // ----- static neighbor-vocab scan: ONE ballot per 64-block (kmask) -----
    const int q = x_ids[row];
    int nb[KNB_];
#pragma unroll
    for (int k = 0; k < KNB_; ++k) nb[k] = static_nb[(size_t)q * KNB_ + k];
    const float ss_l = scnB[(size_t)s_r * NS_ + lane];
    float simk[KNB_] = {};
    unsigned matchedMask = 0;
    int mcW = 0;
    const int* xb = x_ids + (b << 10);
    for (int pb = 0; pb <= s_r; pb += 64) {
        const int p = pb + lane;
        const int id = (p <= s_r) ? xb[p] : -2147483647;
        unsigned kmask = 0;
#pragma unroll
        for (int k = 0; k < KNB_; ++k) kmask |= (id == nb[k]) ? (1u << k) : 0u;
        unsigned long long mb = __ballot(kmask != 0u);
        while (mb) {
            const int src = __ffsll(mb) - 1; mb &= mb - 1;
            const unsigned kms = (unsigned)__shfl((int)kmask, src, 64);
            const int pp = pb + src;
            float pv = scnB[(size_t)pp * NS_ + lane] * ss_l;
            pv = waveSum(pv);
            matchedMask |= kms;
#pragma unroll
            for (int k = 0; k < KNB_; ++k) {
                if ((kms >> k) & 1u) {
                    simk[k] += pv;
                    if (mcW < 64) { if (lane == 0) mlist[wid][mcW] = (pp << 3) | k; ++mcW; }
                }
            }
        }
    }
    const int kk = lane >> 3, jjn = lane & 7;
    float sv = simk[0];
#pragma unroll
    for (int k = 1; k < KNB_; ++k) sv = (kk == k) ? simk[k] : sv;
    const float xx = sv * W_e1[jjn] + b_e1[jjn];
    float eo = 0.5f * xx * (1.f + erff(xx * 0.70710678118654752f)) * W_e2[jjn];
    eo += __shfl_xor(eo, 1, 64); eo += __shfl_xor(eo, 2, 64); eo += __shfl_xor(eo, 4, 64);
    eo += b_e2[0];
    float m2 = eo;
    m2 = fmaxf(m2, __shfl_xor(m2, 8, 64));
    m2 = fmaxf(m2, __shfl_xor(m2, 16, 64));
    m2 = fmaxf(m2, __shfl_xor(m2, 32, 64));
    const float exv = expf(eo - m2);
    float smv = exv;
    smv += __shfl_xor(smv, 8, 64); smv += __shfl_xor(smv, 16, 64); smv += __shfl_xor(smv, 32, 64);
    if ((lane & 7) == 0) ewLds[wid][kk] = exv / smv;

    const float cov = (float)__popc(matchedMask) * 0.125f;
    const float gw = wsGw[row];
    const float coefG = gw;
    const float coefL = (1.f - gw) * (1.f - cov);
    const float coefS = (1.f - gw) * cov;

    // ----- local hasNb derived from raw zl -----
    int fl = 0;
#pragma unroll
    for (int j = 0; j < 16; ++j) fl |= (zrL[j] != 0.0f && zrL[j] > -40000.f);
    const int hasNb = __any(fl);
    if (!hasNb) {
#pragma unroll
        for (int j = 0; j < 16; ++j) {
            const int t = (lane << 4) + j;
            zrL[j] = (zrL[j] <= -40000.f) ? BLKNEG_ : -0.05f * fabsf((float)(s_r - t));
        }
    }

    // ----- JOINT sparsemax tau (geo + local lockstep, batched butterflies) -----
    float mxG = zrG[0], mxL = zrL[0];
#pragma unroll
    for (int j = 1; j < 16; ++j) { mxG = fmaxf(mxG, zrG[j]); mxL = fmaxf(mxL, zrL[j]); }
#pragma unroll
    for (int off = 32; off; off >>= 1) {
        mxG = fmaxf(mxG, __shfl_xor(mxG, off, 64));
        mxL = fmaxf(mxL, __shfl_xor(mxL, off, 64));
    }
    float tauG = mxG - 1.f, tauL = mxL - 1.f;
    for (int it = 0; it < 32; ++it) {
        float sG = 0.f, cG = 0.f, sL = 0.f, cL = 0.f;
#pragma unroll
        for (int j = 0; j < 16; ++j) {
            if (zrG[j] > tauG) { sG += zrG[j]; cG += 1.f; }
            if (zrL[j] > tauL) { sL += zrL[j]; cL += 1.f; }
        }
#pragma unroll
        for (int off = 32; off; off >>= 1) {
            sG += __shfl_xor(sG, off, 64); cG += __shfl_xor(cG, off, 64);
            sL += __shfl_xor(sL, off, 64); cL += __shfl_xor(cL, off, 64);
        }
        const float nG = (sG - 1.f) / fmaxf(cG, 1.f);
        const float nL = (sL - 1.f) / fmaxf(cL, 1.f);
        if (nG == tauG && nL == tauL) break;
        tauG = nG; tauL = nL;
    }

    int supG = 0, supL = 0;
#pragma unroll
    for (int j = 0; j < 16; ++j) {
        supG += __popcll(__ballot(zrG[j] > tauG));
        supL += __popcll(__ballot(zrL[j] > tauL));
    }
    const bool gDense = supG > 96;
    const bool lDense = supL > 96;

    int cnt = 0;
    if (!gDense) {
#pragma unroll
        for (int j = 0; j < 16; ++j) {
            const float wv = zrG[j] - tauG;
            const bool take = wv > 0.f;
            const unsigned long long m = __ballot(take);
            if (take) {
                const int pos = cnt + __popcll(m & ltmask);
                lst[wid][pos] = make_uint2((unsigned)((lane << 4) + j),
                                           __float_as_uint(coefG * wv));
            }
            cnt += __popcll(m);
        }
    }
    if (!lDense) {
#pragma unroll
        for (int j = 0; j < 16; ++j) {
            const float wv = zrL[j] - tauL;
            const bool take = wv > 0.f;
            const unsigned long long m = __ballot(take);
            if (take) {
                const int pos = cnt + __popcll(m & ltmask);
                lst[wid][pos] = make_uint2((unsigned)((lane << 4) + j),
                                           __float_as_uint(coefL * wv));
            }
            cnt += __popcll(m);
        }
    }
    const int nm = (mcW < 64) ? mcW : 64;
    for (int i = lane; i < nm; i += 64) {
        const int ee = mlist[wid][i];
        lst[wid][cnt + i] = make_uint2((unsigned)(ee >> 3),
                                       __float_as_uint(coefS * ewLds[wid][ee & 7]));
    }
    cnt += nm;

    float ox = 0.f, oy = 0.f, oz2 = 0.f, ow = 0.f;
    int i = 0;
    for (; i + 4 <= cnt; i += 4) {
        const uint2 e0 = lst[wid][i + 0];
        const uint2 e1 = lst[wid][i + 1];
        const uint2 e2 = lst[wid][i + 2];
        const uint2 e3 = lst[wid][i + 3];
        const float4 m0 = *(const float4*)(msgB + (size_t)e0.x * D_ + d4);
        const float4 m1 = *(const float4*)(msgB + (size_t)e1.x * D_ + d4);
        const float4 m2b = *(const float4*)(msgB + (size_t)e2.x * D_ + d4);
        const float4 m3 = *(const float4*)(msgB + (size_t)e3.x * D_ + d4);
        const float w0 = __uint_as_float(e0.y), w1 = __uint_as_float(e1.y);
        const float w2 = __uint_as_float(e2.y), w3 = __uint_as_float(e3.y);
        ox = fmaf(w0, m0.x, fmaf(w1, m1.x, fmaf(w2, m2b.x, fmaf(w3, m3.x, ox))));
        oy = fmaf(w0, m0.y, fmaf(w1, m1.y, fmaf(w2, m2b.y, fmaf(w3, m3.y, oy))));
        oz2 = fmaf(w0, m0.z, fmaf(w1, m1.z, fmaf(w2, m2b.z, fmaf(w3, m3.z, oz2))));
        ow = fmaf(w0, m0.w, fmaf(w1, m1.w, fmaf(w2, m2b.w, fmaf(w3, m3.w, ow))));
    }
    for (; i < cnt; ++i) {
        const uint2 e0 = lst[wid][i];
        const float w0 = __uint_as_float(e0.y);
        const float4 m0 = *(const float4*)(msgB + (size_t)e0.x * D_ + d4);
        ox = fmaf(w0, m0.x, ox); oy = fmaf(w0, m0.y, oy);
        oz2 = fmaf(w0, m0.z, oz2); ow = fmaf(w0, m0.w, ow);
    }

    int slot = -1;
    if (gDense || lDense) {
        int s0 = 0;
        if (lane == 0) s0 = atomicAdd(&qMeta[0], 1);
        slot = __shfl(s0, 0, 64);
    }
    if (slot >= 0 && slot < MAXQ_) {
#pragma unroll
        for (int qd = 0; qd < 4; ++qd) {
            float4 w4;
            float* wv4 = &w4.x;
#pragma unroll
            for (int u = 0; u < 4; ++u) {
                const int j = qd * 4 + u;
                float w = 0.f;
                if (gDense) w += coefG * fmaxf(zrG[j] - tauG, 0.f);
                if (lDense) w += coefL * fmaxf(zrL[j] - tauL, 0.f);
                wv4[u] = w;
            }
            *(float4*)(wq + (size_t)slot * SEQ_ + (lane << 4) + qd * 4) = w4;
        }
        if (lane == 0) qRows[slot] = row;
        *(float4*)(out + (size_t)row * D_ + d4) = make_float4(ox, oy, oz2, ow);
        return;
    }
    if (slot >= MAXQ_) {
#pragma unroll
        for (int j = 0; j < 16; ++j) {
            float wv = 0.f;
            if (gDense) wv += coefG * fmaxf(zrG[j] - tauG, 0.f);
            if (lDense) wv += coefL * fmaxf(zrL[j] - tauL, 0.f);
            unsigned long long m = __ballot(wv > 0.f);
            while (m) {
                const int s0 = __ffsll(m) - 1; m &= m - 1;
                const float w0 = __shfl(wv, s0, 64);
                const float4 m4 = *(const float4*)(msgB + (size_t)((s0 << 4) + j) * D_ + d4);
                ox = fmaf(w0, m4.x, ox); oy = fmaf(w0, m4.y, oy);
                oz2 = fmaf(w0, m4.z, oz2); ow = fmaf(w0, m4.w, ow);
            }
        }
    }

    float ssq = ox * ox + oy * oy + oz2 * oz2 + ow * ow;
    ssq = waveSum(ssq);
    const float nrm = fmaxf(sqrtf(ssq), 1e-12f);
    const float4 pr = *(const float4*)(wsProbe + (size_t)row * D_ + d4);
    float dp = (ox * pr.x + oy * pr.y + oz2 * pr.z + ow * pr.w) / nrm;
    dp = waveSum(dp);
    const float rel = 1.f / (1.f + expf(-dp));
    *(float4*)(out + (size_t)row * D_ + d4) =
        make_float4(ox * rel, oy * rel, oz2 * rel, ow * rel);
}

// Kernel C: drain dense-row queue.
__global__ __launch_bounds__(256) void cleanup_kernel(
    const float* __restrict__ messages,
    const float* __restrict__ wsProbe,
    const float* __restrict__ wq,
    const int* __restrict__ qRows,
    int* __restrict__ qMeta,
    float* __restrict__ out)
{
    __shared__ float wsh[SEQ_];
    __shared__ float scr[4];
    __shared__ int idxSh;
    const int tid = threadIdx.x;
    const int nq = (qMeta[0] < MAXQ_) ? qMeta[0] : MAXQ_;
    for (;;) {
        __syncthreads();
        if (tid == 0) idxSh = atomicAdd(&qMeta[1], 1);
        __syncthreads();
        const int idx = idxSh;
        if (idx >= nq) break;
        const int row = qRows[idx];
        const int b = row >> 10;
        const float* msgB = messages + (size_t)b * SEQ_ * D_;
        for (int i = tid; i < SEQ_; i += 256)
            wsh[i] = wq[(size_t)idx * SEQ_ + i];
        __syncthreads();
        float acc = out[(size_t)row * D_ + tid];
        for (int t = 0; t < SEQ_; t += 4) {
            acc = fmaf(wsh[t + 0], msgB[(size_t)(t + 0) * D_ + tid],
                  fmaf(wsh[t + 1], msgB[(size_t)(t + 1) * D_ + tid],
                  fmaf(wsh[t + 2], msgB[(size_t)(t + 2) * D_ + tid],
                  fmaf(wsh[t + 3], msgB[(size_t)(t + 3) * D_ + tid], acc))));
        }
        const float ssq = blockSum(acc * acc, scr);
        const float nrm = fmaxf(sqrtf(ssq), 1e-12f);
        const float dp = blockSum((acc / nrm) * wsProbe[(size_t)row * D_ + tid], scr);
        const float rel = 1.f / (1.f + expf(-dp));
        out[(size_t)row * D_ + tid] = acc * rel;
    }
}

extern "C" void kernel_launch(void* const* d_in, const int* in_sizes, int n_in,
                              void* d_out, int out_size, void* d_ws, size_t ws_size,
                              hipStream_t stream) {
    const float* messages  = (const float*)d_in[0];
    const float* hidden    = (const float*)d_in[1];
    const int*   x_ids     = (const int*)d_in[2];
    const float* scn       = (const float*)d_in[3];
    const void*  mask      = d_in[4];
    const int*   static_nb = (const int*)d_in[5];
    const float* gvel      = (const float*)d_in[6];
    const float* ctx       = (const float*)d_in[7];
    const float* ent       = (const float*)d_in[8];
    const float* W_vel     = (const float*)d_in[9];
    const float* W_e1      = (const float*)d_in[10];
    const float* b_e1      = (const float*)d_in[11];
    const float* W_e2      = (const float*)d_in[12];
    const float* b_e2      = (const float*)d_in[13];
    const float* W_probe   = (const float*)d_in[14];
    const float* W_gate    = (const float*)d_in[15];
    const float* b_gate    = (const float*)d_in[16];
    float* out = (float*)d_out;
    (void)in_sizes; (void)n_in; (void)out_size; (void)ws_size;

    char* ws = (char*)d_ws;
    size_t o = 0;
    int* flag      = (int*)(ws + o);   o += 256;
    short* wsAh    = (short*)(ws + o); o += (size_t)B_ * SEQ_ * 384 * 2;   // 3.1 MB packed
    short* wsAl    = (short*)(ws + o); o += (size_t)B_ * SEQ_ * 384 * 2;
    float* wsProbe = (float*)(ws + o); o += (size_t)B_ * SEQ_ * D_ * 4;
    int* wsMode    = (int*)(ws + o);   o += (size_t)B_ * SEQ_ * 4;
    float* wsGw    = (float*)(ws + o); o += (size_t)B_ * SEQ_ * 4;
    short* msgH    = (short*)(ws + o); o += (size_t)B_ * MSGP_B * 2;       // 2 MB packed
    short* msgL    = (short*)(ws + o); o += (size_t)B_ * MSGP_B * 2;
    short* scnH    = (short*)(ws + o); o += (size_t)B_ * SCNP_B * 2;
    short* scnL    = (short*)(ws + o); o += (size_t)B_ * SCNP_B * 2;
    float* zgW     = (float*)(ws + o); o += (size_t)B_ * SEQ_ * SEQ_ * 4;
    float* zlW     = (float*)(ws + o); o += (size_t)B_ * SEQ_ * SEQ_ * 4;
    int* qMeta     = (int*)(ws + o);   o += 256;
    int* qRows     = (int*)(ws + o);   o += (size_t)MAXQ_ * 4;
    // dense-weight buffer overlays msgH+msgL (dead after sims): 4 MB
    float* wq      = (float*)msgH;

    setup_kernel<<<dim3(833), dim3(256), 0, stream>>>(
        messages, scn, hidden, gvel, ctx, ent, W_probe, W_vel, W_gate, b_gate,
        msgH, msgL, scnH, scnL, (const unsigned int*)mask, flag, qMeta,
        wsAh, wsAl, wsProbe, wsMode, wsGw);
    sims_kernel<<<dim3(512), dim3(512), 0, stream>>>(
        msgH, msgL, scnH, scnL, wsAh, wsAl, wsMode, mask, flag, zgW, zlW);
    route4_kernel<<<dim3(B_ * SEQ_ / 4), dim3(256), 0, stream>>>(
        messages, scn, x_ids, static_nb, W_e1, b_e1, W_e2, b_e2,
        wsProbe, wsGw, zgW, zlW, wq, qRows, qMeta, out);
    cleanup_kernel<<<dim3(64), dim3(256), 0, stream>>>(
        messages, wsProbe, wq, qRows, qMeta, out);
}